// Round 8
// baseline (1038.899 us; speedup 1.0000x reference)
//
#include <hip/hip_runtime.h>
#include <hip/hip_bf16.h>
#include <cstddef>

#define DEV __device__ __forceinline__

constexpr int Bb  = 4;
constexpr int Nn  = 2048;
constexpr int MK  = 256;
constexpr int Dd  = 512;
constexpr int Hh  = 8;
constexpr int DH  = 64;
constexpr int QLD = 1536;   // qkv row stride (3*512)
constexpr int MLPD = 2048;
constexpr int NTOK = Bb * Nn + Bb * MK + Bb;   // 9220 concatenated rows
constexpr int KXOFF = Bb * Nn;                 // 8192: first kx row
constexpr int CLOFF = Bb * Nn + Bb * MK;       // 9216: first cls row
constexpr float SCALE = 0.125f;   // 64^-0.5
constexpr float NEGV  = -1e9f;

typedef __attribute__((ext_vector_type(8))) short short8;
typedef __attribute__((ext_vector_type(4))) float f32x4;

DEV float4 ldf4(const float* p) { return *reinterpret_cast<const float4*>(p); }

// async global->LDS, 16B per lane, linear LDS dest
DEV void gload16(const short* g, short* l) {
  __builtin_amdgcn_global_load_lds(
      (const __attribute__((address_space(1))) void*)g,
      (__attribute__((address_space(3))) void*)l, 16, 0, 0);
}

DEV float waveMax(float v) {
#pragma unroll
  for (int o = 32; o; o >>= 1) v = fmaxf(v, __shfl_xor(v, o));
  return v;
}
DEV float waveSum(float v) {
#pragma unroll
  for (int o = 32; o; o >>= 1) v += __shfl_xor(v, o);
  return v;
}
DEV float blockMax256(float v, float* red) {
  v = waveMax(v);
  __syncthreads();
  if ((threadIdx.x & 63) == 0) red[threadIdx.x >> 6] = v;
  __syncthreads();
  return fmaxf(fmaxf(red[0], red[1]), fmaxf(red[2], red[3]));
}
DEV float blockSum256(float v, float* red) {
  v = waveSum(v);
  __syncthreads();
  if ((threadIdx.x & 63) == 0) red[threadIdx.x >> 6] = v;
  __syncthreads();
  return red[0] + red[1] + red[2] + red[3];
}
DEV float gelu_f(float x) { return 0.5f * x * (1.f + erff(x * 0.70710678118654752f)); }

// ---------------- LayerNorm: one wave per 512-float row, dual f32+bf16 out ----------------
__global__ __launch_bounds__(64)
void ln_kernel(const float* __restrict__ in, const float* __restrict__ gw,
               const float* __restrict__ bw, float* __restrict__ out,
               __hip_bfloat16* __restrict__ outb) {
  const int row = blockIdx.x;
  const int t = threadIdx.x;
  const float* p = in + (size_t)row * Dd + t * 8;
  float4 v0 = ldf4(p), v1 = ldf4(p + 4);
  float s = v0.x + v0.y + v0.z + v0.w + v1.x + v1.y + v1.z + v1.w;
  float q = v0.x*v0.x + v0.y*v0.y + v0.z*v0.z + v0.w*v0.w
          + v1.x*v1.x + v1.y*v1.y + v1.z*v1.z + v1.w*v1.w;
  s = waveSum(s); q = waveSum(q);
  const float mu = s * (1.f / Dd);
  const float rstd = rsqrtf(fmaxf(q * (1.f / Dd) - mu * mu, 0.f) + 1e-5f);
  float4 g0 = ldf4(gw + t * 8), g1 = ldf4(gw + t * 8 + 4);
  float4 b0 = ldf4(bw + t * 8), b1 = ldf4(bw + t * 8 + 4);
  float o[8];
  o[0] = (v0.x - mu) * rstd * g0.x + b0.x;
  o[1] = (v0.y - mu) * rstd * g0.y + b0.y;
  o[2] = (v0.z - mu) * rstd * g0.z + b0.z;
  o[3] = (v0.w - mu) * rstd * g0.w + b0.w;
  o[4] = (v1.x - mu) * rstd * g1.x + b1.x;
  o[5] = (v1.y - mu) * rstd * g1.y + b1.y;
  o[6] = (v1.z - mu) * rstd * g1.z + b1.z;
  o[7] = (v1.w - mu) * rstd * g1.w + b1.w;
  float* op = out + (size_t)row * Dd + t * 8;
  *reinterpret_cast<float4*>(op)     = make_float4(o[0], o[1], o[2], o[3]);
  *reinterpret_cast<float4*>(op + 4) = make_float4(o[4], o[5], o[6], o[7]);
  __hip_bfloat16* ob = outb + (size_t)row * Dd + t * 8;
#pragma unroll
  for (int e = 0; e < 8; ++e) ob[e] = __float2bfloat16(o[e]);
}

// ---------------- bf16 MFMA GEMM (global_load_lds staging, XCD swizzle) ----------------
// EPI: 0 = f32 write; 1 = mask+scale f32 (scores); 2 = +bias +res f32;
//      3 = +bias, gelu, bf16 write; 4 = bf16 write.
struct GArgs {
  const short* A;  long asb; int lda;
  const short* Bt; long bsb; int ldb;
  float* C; __hip_bfloat16* Cb;
  long czo, czi; int ldc;
  const float* bias;
  const float* res; int ldr;
  const float* rowm; int rms;
  const float* colm; int cms;
  int z0, M, N, K;
};

template<int BM, int BN, int EPI>
__global__ __launch_bounds__(256)
void mgemm(GArgs g) {
  constexpr int WMW = (BN >= 128) ? 2 : 4;
  constexpr int WNW = 4 / WMW;
  constexpr int WM = BM / WMW, WN = BN / WNW;
  constexpr int FM = WM / 16, FN = WN / 16;
  __shared__ __align__(16) short As[BM * 64];
  __shared__ __align__(16) short Bs[BN * 64];
  const int tid = threadIdx.x, l = tid & 63, w = tid >> 6;
  const int wm = (WNW == 2) ? (w >> 1) : w;
  const int wn = (WNW == 2) ? (w & 1) : 0;
  int bx = blockIdx.x, by = blockIdx.y;
  {  // bijective XCD swizzle (m204) over the 2D plane
    const int gx = gridDim.x, nwg = gx * gridDim.y;
    const int orig = by * gx + bx;
    const int xcd = orig & 7, pos = orig >> 3;
    const int q = nwg >> 3, rmd = nwg & 7;
    const int s = (xcd < rmd ? xcd * (q + 1) : rmd * (q + 1) + (xcd - rmd) * q) + pos;
    bx = s % gx; by = s / gx;
  }
  const int z = blockIdx.z;
  const short* Ab = g.A + (size_t)z * g.asb;
  const short* Bb_ = g.Bt + (size_t)z * g.bsb;
  f32x4 acc[FM][FN] = {};
  const int lr = l & 15, lg = l >> 4;

  for (int k0 = 0; k0 < g.K; k0 += 64) {
    __syncthreads();
#pragma unroll
    for (int it = 0; it < BM / 32; ++it) {
      int idx = tid + it * 256, r = idx >> 3, c8 = (idx & 7) * 8;
      int gm = by * BM + r;
      if (gm >= g.M) gm = g.M - 1;   // clamp; rows independent in MFMA, masked at write
      gload16(Ab + (size_t)gm * g.lda + k0 + c8, As + idx * 8);
    }
#pragma unroll
    for (int it = 0; it < BN / 32; ++it) {
      int idx = tid + it * 256, r = idx >> 3, c8 = (idx & 7) * 8;
      int gn = bx * BN + r;
      gload16(Bb_ + (size_t)gn * g.ldb + k0 + c8, Bs + idx * 8);
    }
    __syncthreads();
#pragma unroll
    for (int ks = 0; ks < 2; ++ks) {
      const int kb = ks * 32 + lg * 8;
      short8 a[FM], b[FN];
#pragma unroll
      for (int fm = 0; fm < FM; ++fm) {
        int r = wm * WM + fm * 16 + lr;
        a[fm] = *reinterpret_cast<const short8*>(As + r * 64 + kb);
      }
#pragma unroll
      for (int fn = 0; fn < FN; ++fn) {
        int r = wn * WN + fn * 16 + lr;
        b[fn] = *reinterpret_cast<const short8*>(Bs + r * 64 + kb);
      }
#pragma unroll
      for (int fm = 0; fm < FM; ++fm)
#pragma unroll
        for (int fn = 0; fn < FN; ++fn)
          acc[fm][fn] = __builtin_amdgcn_mfma_f32_16x16x32_bf16(a[fm], b[fn], acc[fm][fn], 0, 0, 0);
    }
  }

  const int bg = (g.z0 + z) >> 3;                        // global (for masks)
  const size_t zoff = (size_t)(z >> 3) * g.czo + (size_t)(z & 7) * g.czi;  // local (buffers)
#pragma unroll
  for (int fm = 0; fm < FM; ++fm) {
#pragma unroll
    for (int fn = 0; fn < FN; ++fn) {
#pragma unroll
      for (int r = 0; r < 4; ++r) {
        int m = by * BM + wm * WM + fm * 16 + lg * 4 + r;
        int n = bx * BN + wn * WN + fn * 16 + lr;
        if (m >= g.M) continue;
        float v = acc[fm][fn][r];
        size_t coff = zoff + (size_t)m * g.ldc + n;
        if (EPI == 0) {
          g.C[coff] = v;
        } else if (EPI == 1) {
          float rm = g.rowm[(size_t)bg * g.rms + m];
          float cm = g.colm[(size_t)bg * g.cms + n];
          g.C[coff] = (rm * cm < 0.5f) ? NEGV : v * SCALE;
        } else if (EPI == 2) {
          v += g.bias[n] + g.res[(size_t)m * g.ldr + n];
          g.C[coff] = v;
        } else if (EPI == 3) {
          v = gelu_f(v + g.bias[n]);
          g.Cb[coff] = __float2bfloat16(v);
        } else {
          g.Cb[coff] = __float2bfloat16(v);
        }
      }
    }
  }
}

template<int BM, int BN, int EPI>
static void launch_mgemm(const GArgs& g, int zdim, hipStream_t s) {
  dim3 grid((g.N + BN - 1) / BN, (g.M + BM - 1) / BM, zdim);
  mgemm<BM, BN, EPI><<<grid, 256, 0, s>>>(g);
}

// ---------------- fused x-path score GEMM + dual softmax ----------------
// grid (Nn/128, 16). BM=128, BN=256 (full j-row per block). K=128 (hi|lo).
// Q/Km are BASE pointers; kernel offsets by global bh = z0 + blockIdx.y.
__global__ __launch_bounds__(256)
void score_sx_kernel(const short* __restrict__ Q, const short* __restrict__ Km,
                     const float* __restrict__ mask, const float* __restrict__ kmask,
                     const float* __restrict__ rdT,
                     __hip_bfloat16* __restrict__ P1, __hip_bfloat16* __restrict__ E24,
                     int z0) {
  __shared__ __align__(16) short As[128 * 64];
  __shared__ __align__(16) short Bs[256 * 64];
  __shared__ float red[128 * 2];
  __shared__ float red2[128 * 4];
  const int tid = threadIdx.x, l = tid & 63, w = tid >> 6;
  const int wm = w >> 1, wn = w & 1;
  const int by = blockIdx.x, z = blockIdx.y;
  const int bh = z0 + z, b = bh >> 3;
  const short* Ab = Q + (size_t)bh * Nn * 128;
  const short* Bb = Km + (size_t)bh * MK * 128;
  const int lr = l & 15, lg = l >> 4;
  f32x4 acc[4][8] = {};

  for (int k0 = 0; k0 < 128; k0 += 64) {
    __syncthreads();
#pragma unroll
    for (int it = 0; it < 4; ++it) {
      int idx = tid + it * 256, r = idx >> 3, c8 = (idx & 7) * 8;
      gload16(Ab + (size_t)(by * 128 + r) * 128 + k0 + c8, As + idx * 8);
    }
#pragma unroll
    for (int it = 0; it < 8; ++it) {
      int idx = tid + it * 256, r = idx >> 3, c8 = (idx & 7) * 8;
      gload16(Bb + (size_t)r * 128 + k0 + c8, Bs + idx * 8);
    }
    __syncthreads();
#pragma unroll
    for (int ks = 0; ks < 2; ++ks) {
      const int kb = ks * 32 + lg * 8;
      short8 a[4], bv[8];
#pragma unroll
      for (int fm = 0; fm < 4; ++fm)
        a[fm] = *reinterpret_cast<const short8*>(As + (wm * 64 + fm * 16 + lr) * 64 + kb);
#pragma unroll
      for (int fn = 0; fn < 8; ++fn)
        bv[fn] = *reinterpret_cast<const short8*>(Bs + (wn * 128 + fn * 16 + lr) * 64 + kb);
#pragma unroll
      for (int fm = 0; fm < 4; ++fm)
#pragma unroll
        for (int fn = 0; fn < 8; ++fn)
          acc[fm][fn] = __builtin_amdgcn_mfma_f32_16x16x32_bf16(a[fm], bv[fn], acc[fm][fn], 0, 0, 0);
    }
  }
  // mask + scale in place
  {
    float colm[8];
#pragma unroll
    for (int fn = 0; fn < 8; ++fn)
      colm[fn] = kmask[b * MK + wn * 128 + fn * 16 + lr];
#pragma unroll
    for (int fm = 0; fm < 4; ++fm)
#pragma unroll
      for (int r = 0; r < 4; ++r) {
        float rm = mask[(size_t)b * Nn + by * 128 + wm * 64 + fm * 16 + lg * 4 + r];
#pragma unroll
        for (int fn = 0; fn < 8; ++fn)
          acc[fm][fn][r] = (rm * colm[fn] < 0.5f) ? NEGV : acc[fm][fn][r] * SCALE;
      }
  }
  // row max: local frags -> 16-lane shfl -> cross-wave via LDS
  float mx[4][4];
#pragma unroll
  for (int fm = 0; fm < 4; ++fm)
#pragma unroll
    for (int r = 0; r < 4; ++r) {
      float m = -3.4e38f;
#pragma unroll
      for (int fn = 0; fn < 8; ++fn) m = fmaxf(m, acc[fm][fn][r]);
#pragma unroll
      for (int o = 8; o; o >>= 1) m = fmaxf(m, __shfl_xor(m, o));
      mx[fm][r] = m;
    }
  __syncthreads();
  if (lr == 0) {
#pragma unroll
    for (int fm = 0; fm < 4; ++fm)
#pragma unroll
      for (int r = 0; r < 4; ++r)
        red[(wm * 64 + fm * 16 + lg * 4 + r) * 2 + wn] = mx[fm][r];
  }
  __syncthreads();
#pragma unroll
  for (int fm = 0; fm < 4; ++fm)
#pragma unroll
    for (int r = 0; r < 4; ++r) {
      int row = wm * 64 + fm * 16 + lg * 4 + r;
      mx[fm][r] = fmaxf(red[row * 2], red[row * 2 + 1]);
    }
  // row sums (e1 & e24)
  float s1[4][4], s24[4][4];
#pragma unroll
  for (int fm = 0; fm < 4; ++fm)
#pragma unroll
    for (int r = 0; r < 4; ++r) {
      float a1 = 0.f, a24 = 0.f;
#pragma unroll
      for (int fn = 0; fn < 8; ++fn) {
        float d = acc[fm][fn][r] - mx[fm][r];
        a1 += __expf(d);
        a24 += __expf(24.f * d);
      }
#pragma unroll
      for (int o = 8; o; o >>= 1) { a1 += __shfl_xor(a1, o); a24 += __shfl_xor(a24, o); }
      s1[fm][r] = a1; s24[fm][r] = a24;
    }
  __syncthreads();
  if (lr == 0) {
#pragma unroll
    for (int fm = 0; fm < 4; ++fm)
#pragma unroll
      for (int r = 0; r < 4; ++r) {
        int row = wm * 64 + fm * 16 + lg * 4 + r;
        red2[row * 4 + wn * 2]     = s1[fm][r];
        red2[row * 4 + wn * 2 + 1] = s24[fm][r];
      }
  }
  __syncthreads();
#pragma unroll
  for (int fm = 0; fm < 4; ++fm)
#pragma unroll
    for (int r = 0; r < 4; ++r) {
      int row = wm * 64 + fm * 16 + lg * 4 + r;
      s1[fm][r]  = 1.f / (red2[row * 4] + red2[row * 4 + 2]);
      s24[fm][r] = 1.f / (red2[row * 4 + 1] + red2[row * 4 + 3]);
    }
  // normalized writes (chunk-local buffers)
#pragma unroll
  for (int fm = 0; fm < 4; ++fm) {
#pragma unroll
    for (int r = 0; r < 4; ++r) {
      int m = by * 128 + wm * 64 + fm * 16 + lg * 4 + r;
      const float* rp = rdT + ((size_t)b * Nn + m) * MK;
      size_t obase = ((size_t)z * Nn + m) * MK;
#pragma unroll
      for (int fn = 0; fn < 8; ++fn) {
        int n = wn * 128 + fn * 16 + lr;
        float d = acc[fm][fn][r] - mx[fm][r];
        float rv = rp[n];
        P1[obase + n]  = __float2bfloat16(__expf(d) * s1[fm][r] * rv);
        E24[obase + n] = __float2bfloat16(__expf(24.f * d) * s24[fm][r] * rv);
      }
    }
  }
}

// ---------------- atten transpose: E24 bf16 [z][i][j] -> f32 [bh][j][i] ----------------
__global__ __launch_bounds__(256)
void at_tr_kernel(const __hip_bfloat16* __restrict__ E, float* __restrict__ atten, int z0) {
  __shared__ __hip_bfloat16 t[64][72];
  const int z = blockIdx.x, bh = z0 + z;
  const int i0 = blockIdx.y * 64, j0 = blockIdx.z * 64;
  const int tid = threadIdx.x;
#pragma unroll
  for (int it = 0; it < 2; ++it) {
    int idx = tid + it * 256, r = idx >> 3, c8 = (idx & 7) * 8;
    short8 v = *reinterpret_cast<const short8*>(
        (const short*)E + ((size_t)z * Nn + i0 + r) * MK + j0 + c8);
#pragma unroll
    for (int e = 0; e < 8; ++e)
      *reinterpret_cast<short*>(&t[r][c8 + e]) = v[e];
  }
  __syncthreads();
#pragma unroll
  for (int it = 0; it < 4; ++it) {
    int idx = tid + it * 256, jr = idx >> 4, c4 = (idx & 15) * 4;
    float4 o;
    o.x = __bfloat162float(t[c4 + 0][jr]);
    o.y = __bfloat162float(t[c4 + 1][jr]);
    o.z = __bfloat162float(t[c4 + 2][jr]);
    o.w = __bfloat162float(t[c4 + 3][jr]);
    *reinterpret_cast<float4*>(
        atten + ((size_t)bh * MK + j0 + jr) * Nn + i0 + c4) = o;
  }
}

// ---------------- rd transpose: [b][j][i] -> rdT [b][i][j] (runs once) ----------------
__global__ __launch_bounds__(256)
void rd_tr_kernel(const float* __restrict__ rd, float* __restrict__ rdT) {
  __shared__ float tb[64][65];
  const int b = blockIdx.x;
  const int i0 = blockIdx.y * 64, j0 = blockIdx.z * 64;
  const int tid = threadIdx.x;
#pragma unroll
  for (int it = 0; it < 4; ++it) {
    int idx = tid + it * 256, r = idx >> 4, c4 = (idx & 15) * 4;   // r: j-local
    float4 v = ldf4(rd + ((size_t)(b * MK + j0 + r)) * Nn + i0 + c4);
    tb[r][c4 + 0] = v.x; tb[r][c4 + 1] = v.y; tb[r][c4 + 2] = v.z; tb[r][c4 + 3] = v.w;
  }
  __syncthreads();
#pragma unroll
  for (int it = 0; it < 4; ++it) {
    int idx = tid + it * 256, r = idx >> 4, c4 = (idx & 15) * 4;   // r: i-local
    float4 o = make_float4(tb[c4 + 0][r], tb[c4 + 1][r], tb[c4 + 2][r], tb[c4 + 3][r]);
    *reinterpret_cast<float4*>(rdT + ((size_t)(b * Nn + i0 + r)) * MK + j0 + c4) = o;
  }
}

// ---------------- weight transpose: f32 [K][N] -> bf16 [N][K] ----------------
__global__ __launch_bounds__(256)
void wtrans_kernel(const float* __restrict__ W, __hip_bfloat16* __restrict__ WT,
                   int K, int N) {
  __shared__ float t[64][65];
  const int n0 = blockIdx.x * 64, k0 = blockIdx.y * 64;
  const int tid = threadIdx.x;
#pragma unroll
  for (int it = 0; it < 4; ++it) {
    int idx = tid + it * 256, r = idx >> 4, f = idx & 15;
    float4 v = ldf4(W + (size_t)(k0 + r) * N + n0 + f * 4);
    t[r][f * 4 + 0] = v.x; t[r][f * 4 + 1] = v.y;
    t[r][f * 4 + 2] = v.z; t[r][f * 4 + 3] = v.w;
  }
  __syncthreads();
#pragma unroll
  for (int it = 0; it < 4; ++it) {
    int idx = tid + it * 256, r = idx >> 4, c4 = (idx & 15) * 4;
    __hip_bfloat16* op = WT + (size_t)(n0 + r) * K + k0 + c4;
#pragma unroll
    for (int e = 0; e < 4; ++e) op[e] = __float2bfloat16(t[c4 + e][r]);
  }
}

// ---------------- qkv split: hi/lo bf16 operand prep ----------------
template<bool Q_SPLIT>
__global__ __launch_bounds__(256)
void split_kernel(const float* __restrict__ qkv, __hip_bfloat16* __restrict__ qout,
                  __hip_bfloat16* __restrict__ kout, int T) {
  const int idx = blockIdx.x * 256 + threadIdx.x;
  const int token = idx >> 7, c8 = (idx & 127) * 8;
  const int b = token / T, i = token - b * T;
  const float* p = qkv + (size_t)token * QLD + c8;
  float v[8];
  float4 a = ldf4(p), c = ldf4(p + 4);
  v[0]=a.x; v[1]=a.y; v[2]=a.z; v[3]=a.w; v[4]=c.x; v[5]=c.y; v[6]=c.z; v[7]=c.w;
  if (c8 < 512) {
    int h = c8 >> 6, d = c8 & 63;
    if (Q_SPLIT) {
      __hip_bfloat16* q = qout + ((size_t)((b * 8 + h) * T + i)) * 128 + d;
#pragma unroll
      for (int e = 0; e < 8; ++e) {
        __hip_bfloat16 hi = __float2bfloat16(v[e]);
        q[e] = hi;
        q[64 + e] = __float2bfloat16(v[e] - __bfloat162float(hi));
      }
    } else {
      __hip_bfloat16* q = qout + ((size_t)((b * 8 + h) * T + i)) * 64 + d;
#pragma unroll
      for (int e = 0; e < 8; ++e) q[e] = __float2bfloat16(v[e]);
    }
  } else {
    int cc = c8 - 512, h = cc >> 6, d = cc & 63;
    if (Q_SPLIT) {
      __hip_bfloat16* k = kout + ((size_t)((b * 8 + h) * T + i)) * 64 + d;
#pragma unroll
      for (int e = 0; e < 8; ++e) k[e] = __float2bfloat16(v[e]);
    } else {
      __hip_bfloat16* k = kout + ((size_t)((b * 8 + h) * T + i)) * 128 + d;
#pragma unroll
      for (int e = 0; e < 8; ++e) {
        __hip_bfloat16 hi = __float2bfloat16(v[e]);
        k[e] = hi;
        k[64 + e] = __float2bfloat16(v[e] - __bfloat162float(hi));
      }
    }
  }
}

// ---------------- v transpose: qkv v-part -> bf16 [bh][d][token] ----------------
__global__ __launch_bounds__(256)
void vtrans_kernel(const float* __restrict__ qkv, __hip_bfloat16* __restrict__ vT, int T) {
  __shared__ float t[64][65];
  const int bh = blockIdx.x, b = bh >> 3, h = bh & 7;
  const int i0 = blockIdx.y * 64;
  const int tid = threadIdx.x;
#pragma unroll
  for (int it = 0; it < 4; ++it) {
    int idx = tid + it * 256, r = idx >> 4, f = idx & 15;
    float4 v = ldf4(qkv + (size_t)(b * T + i0 + r) * QLD + 2 * Dd + h * 64 + f * 4);
    t[r][f * 4 + 0] = v.x; t[r][f * 4 + 1] = v.y;
    t[r][f * 4 + 2] = v.z; t[r][f * 4 + 3] = v.w;
  }
  __syncthreads();
#pragma unroll
  for (int it = 0; it < 4; ++it) {
    int idx = tid + it * 256, d = idx >> 4, c4 = (idx & 15) * 4;
    __hip_bfloat16* op = vT + (size_t)(bh * 64 + d) * T + i0 + c4;
#pragma unroll
    for (int e = 0; e < 4; ++e) op[e] = __float2bfloat16(t[c4 + e][d]);
  }
}

// ---------------- k-path softmax + rd (P2 chunk-local) ----------------
__global__ __launch_bounds__(256)
void softmax_k_kernel(const float* __restrict__ S, const float* __restrict__ rd,
                      __hip_bfloat16* __restrict__ P2, int z0) {
  __shared__ float red8[8];
  const int tid = threadIdx.x;
  const int j = blockIdx.x, zloc = blockIdx.y, b = (z0 + zloc) >> 3;
  const float* row = S + ((size_t)zloc * MK + j) * Nn;
  float d[8];
  float lm = -3.4e38f;
#pragma unroll
  for (int c = 0; c < 8; ++c) { d[c] = row[c * 256 + tid]; lm = fmaxf(lm, d[c]); }
  const float mx = blockMax256(lm, red8);
  float ls = 0.f;
#pragma unroll
  for (int c = 0; c < 8; ++c) { d[c] = __expf(d[c] - mx); ls += d[c]; }
  const float s = blockSum256(ls, red8);
  const float inv = 1.f / s;
  const float* rp = rd + (size_t)(b * MK + j) * Nn;
  __hip_bfloat16* pp = P2 + ((size_t)zloc * MK + j) * Nn;
#pragma unroll
  for (int c = 0; c < 8; ++c)
    pp[c * 256 + tid] = __float2bfloat16(d[c] * inv * rp[c * 256 + tid]);
}

// ------------- cls-token attention: grid B*H, block 256, bf16 out -------------
__global__ __launch_bounds__(256)
void attn_c_kernel(const float* __restrict__ cqkv, const float* __restrict__ kqkv,
                   const float* __restrict__ mask, const float* __restrict__ kmask,
                   __hip_bfloat16* __restrict__ c_pre) {
  __shared__ __align__(16) float kv_s[MK][DH];
  __shared__ __align__(16) float q_s[DH];
  __shared__ float pbuf[MK];
  __shared__ float red8[8];
  __shared__ float redpv[4][DH];
  const int tid = threadIdx.x;
  const int bh = blockIdx.x, b = bh >> 3, h = bh & 7;
  const float* vp = kqkv + ((size_t)(b * MK + tid)) * QLD + 2 * Dd + h * DH;
#pragma unroll
  for (int q4 = 0; q4 < 16; ++q4)
    *reinterpret_cast<float4*>(&kv_s[tid][q4 * 4]) = ldf4(vp + q4 * 4);
  if (tid < DH) q_s[tid] = cqkv[(size_t)b * QLD + h * DH + tid];
  __syncthreads();
  const float* kp = kqkv + ((size_t)(b * MK + tid)) * QLD + Dd + h * DH;
  float dot = 0.f;
#pragma unroll
  for (int q4 = 0; q4 < 16; ++q4) {
    float4 kv4 = ldf4(kp + q4 * 4);
    float4 qv = ldf4(&q_s[q4 * 4]);
    dot = fmaf(qv.x, kv4.x, dot);
    dot = fmaf(qv.y, kv4.y, dot);
    dot = fmaf(qv.z, kv4.z, dot);
    dot = fmaf(qv.w, kv4.w, dot);
  }
  const float dm = (mask[(size_t)b * Nn] * kmask[b * MK + tid] < 0.5f) ? NEGV : dot * SCALE;
  const float mx = blockMax256(dm, red8);
  const float e = __expf(dm - mx);
  const float s = blockSum256(e, red8);
  pbuf[tid] = e / s;
  __syncthreads();
  const int d = tid & 63, g = tid >> 6;
  float acc = 0.f;
#pragma unroll 8
  for (int jj = 0; jj < 64; ++jj)
    acc = fmaf(pbuf[g * 64 + jj], kv_s[g * 64 + jj][d], acc);
  redpv[g][d] = acc;
  __syncthreads();
  if (tid < DH)
    c_pre[(size_t)b * Dd + h * DH + tid] = __float2bfloat16(
        redpv[0][tid] + redpv[1][tid] + redpv[2][tid] + redpv[3][tid]);
}

// ------------- output writers (float32 outputs) -------------
__global__ void kreps_kernel(const float* __restrict__ kx, const float* __restrict__ kmask,
                             float* __restrict__ o) {
  const int idx = blockIdx.x * 256 + threadIdx.x;
  const int bj = idx >> 9;
  const float keep = (kmask[bj] >= 0.5f) ? 1.f : 0.f;
  o[idx] = kx[idx] * keep;
}
__global__ void cout_kernel(const float* __restrict__ c_s, float* __restrict__ o) {
  const int idx = blockIdx.x * 256 + threadIdx.x;
  o[idx] = c_s[idx];
}

static GArgs ga_base() { GArgs g = {}; return g; }

extern "C" void kernel_launch(void* const* d_in, const int* in_sizes, int n_in,
                              void* d_out, int out_size, void* d_ws, size_t ws_size,
                              hipStream_t stream) {
  (void)in_sizes; (void)n_in; (void)out_size; (void)ws_size;
  const float* x_in  = (const float*)d_in[0];
  const float* kx_in = (const float*)d_in[1];
  const float* rd    = (const float*)d_in[2];
  const float* c_in  = (const float*)d_in[3];
  const float* mask  = (const float*)d_in[4];
  const float* kmask = (const float*)d_in[5];
  const float* ln1g  = (const float*)d_in[6];
  const float* ln1b  = (const float*)d_in[7];
  const float* Wqkv  = (const float*)d_in[8];
  const float* Woutw = (const float*)d_in[9];
  const float* boutw = (const float*)d_in[10];
  const float* ln2g  = (const float*)d_in[11];
  const float* ln2b  = (const float*)d_in[12];
  const float* W1    = (const float*)d_in[13];
  const float* b1    = (const float*)d_in[14];
  const float* W2    = (const float*)d_in[15];
  const float* b2    = (const float*)d_in[16];
  float* out = (float*)d_out;

  float* ws = (float*)d_ws;
  size_t off = 0;
  auto alloc = [&](size_t n) { float* p = ws + off; off += (n + 15) & ~(size_t)15; return p; };
  float* xcat_s   = alloc((size_t)NTOK * Dd);       // residual state (all tokens)
  float* xcat_n   = alloc((size_t)NTOK * Dd);       // LN output f32
  float* xcat_nb_f = alloc((size_t)NTOK * Dd / 2);  // LN output bf16
  float* pre_cat_f = alloc((size_t)NTOK * Dd / 2);  // attention out bf16
  float* qkv      = alloc((size_t)NTOK * QLD);      // hosts P1/E24/P2, then hid
  float* S        = alloc((size_t)16 * MK * Nn);    // k-path scores (per chunk)
  float* tq_s_f   = alloc((size_t)32 * Nn * 128 / 2);
  float* kk_s_f   = alloc((size_t)32 * MK * 128 / 2);
  float* tk_hi_f  = alloc((size_t)32 * Nn * 64 / 2);
  float* kq_hi_f  = alloc((size_t)32 * MK * 64 / 2);
  float* tvT_f    = alloc((size_t)32 * 64 * Nn / 2);
  float* kvT_f    = alloc((size_t)32 * 64 * MK / 2);
  float* rdT      = alloc((size_t)Bb * Nn * MK);
  float* WqkvT_f  = alloc((size_t)QLD * Dd / 2);
  float* WoutT_f  = alloc((size_t)Dd * Dd / 2);
  float* W1T_f    = alloc((size_t)MLPD * Dd / 2);
  float* W2T_f    = alloc((size_t)Dd * MLPD / 2);

  __hip_bfloat16* xcat_nb = (__hip_bfloat16*)xcat_nb_f;
  __hip_bfloat16* pre_cat = (__hip_bfloat16*)pre_cat_f;
  __hip_bfloat16* tq_s    = (__hip_bfloat16*)tq_s_f;
  __hip_bfloat16* kk_s    = (__hip_bfloat16*)kk_s_f;
  __hip_bfloat16* tk_hi   = (__hip_bfloat16*)tk_hi_f;
  __hip_bfloat16* kq_hi   = (__hip_bfloat16*)kq_hi_f;
  __hip_bfloat16* tvT     = (__hip_bfloat16*)tvT_f;
  __hip_bfloat16* kvT     = (__hip_bfloat16*)kvT_f;
  __hip_bfloat16* WqkvT   = (__hip_bfloat16*)WqkvT_f;
  __hip_bfloat16* WoutT   = (__hip_bfloat16*)WoutT_f;
  __hip_bfloat16* W1T     = (__hip_bfloat16*)W1T_f;
  __hip_bfloat16* W2T     = (__hip_bfloat16*)W2T_f;
  // overlays inside qkv: P1+E24+P2 fill exactly the x-token region (12.58M f32)
  __hip_bfloat16* P1b  = (__hip_bfloat16*)qkv;
  __hip_bfloat16* E24b = (__hip_bfloat16*)(qkv + (size_t)16 * Nn * MK / 2);
  __hip_bfloat16* P2b  = (__hip_bfloat16*)(qkv + (size_t)16 * Nn * MK);
  __hip_bfloat16* hid  = (__hip_bfloat16*)qkv;      // FF hidden, after attention

  const size_t CL_OFF = (size_t)2 * Bb * MK * Dd;
  const size_t AT_OFF = CL_OFF + (size_t)Bb * Dd;

  rd_tr_kernel<<<dim3(Bb, Nn / 64, MK / 64), 256, 0, stream>>>(rd, rdT);

  for (int l = 0; l < 2; ++l) {
    const float* g1 = ln1g + l * Dd; const float* bb1 = ln1b + l * Dd;
    ln_kernel<<<Bb * Nn, 64, 0, stream>>>(l ? xcat_s : x_in, g1, bb1, xcat_n, xcat_nb);
    ln_kernel<<<Bb * MK, 64, 0, stream>>>(l ? xcat_s + (size_t)KXOFF * Dd : kx_in, g1, bb1,
                                          xcat_n + (size_t)KXOFF * Dd,
                                          xcat_nb + (size_t)KXOFF * Dd);
    ln_kernel<<<Bb, 64, 0, stream>>>(l ? xcat_s + (size_t)CLOFF * Dd : c_in, g1, bb1,
                                     xcat_n + (size_t)CLOFF * Dd,
                                     xcat_nb + (size_t)CLOFF * Dd);

    const float* Wq = Wqkv + (size_t)l * Dd * QLD;
    const float* Wo = Woutw + (size_t)l * Dd * Dd;
    const float* bo = boutw + (size_t)l * Dd;
    const float* W1l = W1 + (size_t)l * Dd * MLPD;
    const float* b1l = b1 + (size_t)l * MLPD;
    const float* W2l = W2 + (size_t)l * MLPD * Dd;
    const float* b2l = b2 + (size_t)l * Dd;
    wtrans_kernel<<<dim3(QLD / 64, Dd / 64), 256, 0, stream>>>(Wq, WqkvT, Dd, QLD);
    wtrans_kernel<<<dim3(Dd / 64, Dd / 64), 256, 0, stream>>>(Wo, WoutT, Dd, Dd);
    wtrans_kernel<<<dim3(MLPD / 64, Dd / 64), 256, 0, stream>>>(W1l, W1T, Dd, MLPD);
    wtrans_kernel<<<dim3(Dd / 64, MLPD / 64), 256, 0, stream>>>(W2l, W2T, MLPD, Dd);

    // QKV: one GEMM over all 9220 rows
    {
      GArgs g = ga_base();
      g.A = (const short*)xcat_nb; g.lda = Dd;
      g.Bt = (const short*)WqkvT; g.ldb = Dd;
      g.C = qkv; g.ldc = QLD;
      g.M = NTOK; g.N = QLD; g.K = Dd;
      launch_mgemm<128, 128, 0>(g, 1, stream);
    }

    split_kernel<true><<<(Bb * Nn * 128) / 256, 256, 0, stream>>>(qkv, tq_s, tk_hi, Nn);
    split_kernel<false><<<(Bb * MK * 128) / 256, 256, 0, stream>>>(
        qkv + (size_t)KXOFF * QLD, kq_hi, kk_s, MK);
    vtrans_kernel<<<dim3(32, Nn / 64), 256, 0, stream>>>(qkv, tvT, Nn);
    vtrans_kernel<<<dim3(32, MK / 64), 256, 0, stream>>>(qkv + (size_t)KXOFF * QLD, kvT, MK);

    attn_c_kernel<<<Bb * Hh, 256, 0, stream>>>(qkv + (size_t)CLOFF * QLD,
                                               qkv + (size_t)KXOFF * QLD, mask, kmask,
                                               pre_cat + (size_t)CLOFF * Dd);

    for (int ch = 0; ch < 2; ++ch) {
      // ---- x-path: fused score+softmax, atten transpose, PV ----
      // NOTE: pass BASE pointers — kernel offsets by global bh = z0 + z.
      score_sx_kernel<<<dim3(Nn / 128, 16), 256, 0, stream>>>(
          (const short*)tq_s, (const short*)kk_s,
          mask, kmask, rdT, P1b, E24b, ch * 16);
      at_tr_kernel<<<dim3(16, Nn / 64, MK / 64), 256, 0, stream>>>(
          E24b, out + AT_OFF + (size_t)l * 32 * MK * Nn, ch * 16);
      {
        GArgs g = ga_base();
        g.A = (const short*)P1b; g.asb = (long)Nn * MK; g.lda = MK;
        g.Bt = (const short*)(kvT + (size_t)ch * 16 * 64 * MK); g.bsb = (long)64 * MK; g.ldb = MK;
        g.Cb = pre_cat + (size_t)(2 * ch) * Nn * Dd; g.czo = (long)Nn * Dd; g.czi = 64; g.ldc = Dd;
        g.M = Nn; g.N = 64; g.K = MK;
        launch_mgemm<128, 64, 4>(g, 16, stream);
      }
      // ---- k-path: score GEMM -> softmax -> PV ----
      {
        GArgs g = ga_base();
        g.A = (const short*)(kq_hi + (size_t)ch * 16 * MK * 64); g.asb = (long)MK * 64; g.lda = 64;
        g.Bt = (const short*)(tk_hi + (size_t)ch * 16 * Nn * 64); g.bsb = (long)Nn * 64; g.ldb = 64;
        g.C = S; g.czi = (long)MK * Nn; g.czo = 8L * MK * Nn; g.ldc = Nn;
        g.rowm = kmask; g.rms = MK; g.colm = mask; g.cms = Nn;
        g.z0 = ch * 16; g.M = MK; g.N = Nn; g.K = 64;
        launch_mgemm<128, 128, 1>(g, 16, stream);
      }
      softmax_k_kernel<<<dim3(MK, 16), 256, 0, stream>>>(S, rd, P2b, ch * 16);
      {
        GArgs g = ga_base();
        g.A = (const short*)P2b; g.asb = (long)MK * Nn; g.lda = Nn;
        g.Bt = (const short*)(tvT + (size_t)ch * 16 * 64 * Nn); g.bsb = (long)64 * Nn; g.ldb = Nn;
        g.Cb = pre_cat + (size_t)KXOFF * Dd + (size_t)(2 * ch) * MK * Dd;
        g.czo = (long)MK * Dd; g.czi = 64; g.ldc = Dd;
        g.M = MK; g.N = 64; g.K = Nn;
        launch_mgemm<64, 64, 4>(g, 16, stream);
      }
    }

    // ---- Wout + residual over all rows ----
    {
      GArgs g = ga_base();
      g.A = (const short*)pre_cat; g.lda = Dd;
      g.Bt = (const short*)WoutT; g.ldb = Dd;
      g.C = xcat_s; g.ldc = Dd; g.bias = bo; g.res = xcat_n; g.ldr = Dd;
      g.M = NTOK; g.N = Dd; g.K = Dd;
      launch_mgemm<128, 64, 2>(g, 1, stream);
    }

    // ---- FF over all rows ----
    ln_kernel<<<NTOK, 64, 0, stream>>>(xcat_s, ln2g + l * Dd, ln2b + l * Dd, xcat_n, xcat_nb);
    {
      GArgs g = ga_base();
      g.A = (const short*)xcat_nb; g.lda = Dd;
      g.Bt = (const short*)W1T; g.ldb = Dd;
      g.Cb = hid; g.ldc = MLPD; g.bias = b1l;
      g.M = NTOK; g.N = MLPD; g.K = Dd;
      launch_mgemm<128, 128, 3>(g, 1, stream);
      GArgs h = ga_base();
      h.A = (const short*)hid; h.lda = MLPD;
      h.Bt = (const short*)W2T; h.ldb = MLPD;
      h.C = xcat_s; h.ldc = Dd; h.bias = b2l; h.res = xcat_s; h.ldr = Dd;
      h.M = NTOK; h.N = Dd; h.K = MLPD;
      launch_mgemm<128, 64, 2>(h, 1, stream);
    }

    kreps_kernel<<<(Bb * MK * Dd) / 256, 256, 0, stream>>>(
        xcat_s + (size_t)KXOFF * Dd, kmask, out + (size_t)l * Bb * MK * Dd);
  }
  cout_kernel<<<(Bb * Dd) / 256, 256, 0, stream>>>(xcat_s + (size_t)CLOFF * Dd, out + CL_OFF);
}

// Round 9
// 953.645 us; speedup vs baseline: 1.0894x; 1.0894x over previous
//
#include <hip/hip_runtime.h>
#include <hip/hip_bf16.h>
#include <cstddef>

#define DEV __device__ __forceinline__

constexpr int Bb  = 4;
constexpr int Nn  = 2048;
constexpr int MK  = 256;
constexpr int Dd  = 512;
constexpr int Hh  = 8;
constexpr int DH  = 64;
constexpr int QLD = 1536;   // qkv row stride (3*512)
constexpr int MLPD = 2048;
constexpr int NTOK = Bb * Nn + Bb * MK + Bb;   // 9220 concatenated rows
constexpr int KXOFF = Bb * Nn;                 // 8192: first kx row
constexpr int CLOFF = Bb * Nn + Bb * MK;       // 9216: first cls row
constexpr float SCALE = 0.125f;   // 64^-0.5
constexpr float NEGV  = -1e9f;

typedef __attribute__((ext_vector_type(8))) short short8;
typedef __attribute__((ext_vector_type(4))) float f32x4;

DEV float4 ldf4(const float* p) { return *reinterpret_cast<const float4*>(p); }

// async global->LDS, 16B per lane, linear LDS dest
DEV void gload16(const short* g, short* l) {
  __builtin_amdgcn_global_load_lds(
      (const __attribute__((address_space(1))) void*)g,
      (__attribute__((address_space(3))) void*)l, 16, 0, 0);
}
DEV void drain_vm() { asm volatile("s_waitcnt vmcnt(0)" ::: "memory"); }
DEV void sbar() { __builtin_amdgcn_s_barrier(); }
DEV void schedbar() { __builtin_amdgcn_sched_barrier(0); }

DEV float waveMax(float v) {
#pragma unroll
  for (int o = 32; o; o >>= 1) v = fmaxf(v, __shfl_xor(v, o));
  return v;
}
DEV float waveSum(float v) {
#pragma unroll
  for (int o = 32; o; o >>= 1) v += __shfl_xor(v, o);
  return v;
}
DEV float blockMax256(float v, float* red) {
  v = waveMax(v);
  __syncthreads();
  if ((threadIdx.x & 63) == 0) red[threadIdx.x >> 6] = v;
  __syncthreads();
  return fmaxf(fmaxf(red[0], red[1]), fmaxf(red[2], red[3]));
}
DEV float blockSum256(float v, float* red) {
  v = waveSum(v);
  __syncthreads();
  if ((threadIdx.x & 63) == 0) red[threadIdx.x >> 6] = v;
  __syncthreads();
  return red[0] + red[1] + red[2] + red[3];
}
DEV float gelu_f(float x) { return 0.5f * x * (1.f + erff(x * 0.70710678118654752f)); }

// ---------------- LayerNorm: one wave per 512-float row, dual f32+bf16 out ----------------
__global__ __launch_bounds__(64)
void ln_kernel(const float* __restrict__ in, const float* __restrict__ gw,
               const float* __restrict__ bw, float* __restrict__ out,
               __hip_bfloat16* __restrict__ outb) {
  const int row = blockIdx.x;
  const int t = threadIdx.x;
  const float* p = in + (size_t)row * Dd + t * 8;
  float4 v0 = ldf4(p), v1 = ldf4(p + 4);
  float s = v0.x + v0.y + v0.z + v0.w + v1.x + v1.y + v1.z + v1.w;
  float q = v0.x*v0.x + v0.y*v0.y + v0.z*v0.z + v0.w*v0.w
          + v1.x*v1.x + v1.y*v1.y + v1.z*v1.z + v1.w*v1.w;
  s = waveSum(s); q = waveSum(q);
  const float mu = s * (1.f / Dd);
  const float rstd = rsqrtf(fmaxf(q * (1.f / Dd) - mu * mu, 0.f) + 1e-5f);
  float4 g0 = ldf4(gw + t * 8), g1 = ldf4(gw + t * 8 + 4);
  float4 b0 = ldf4(bw + t * 8), b1 = ldf4(bw + t * 8 + 4);
  float o[8];
  o[0] = (v0.x - mu) * rstd * g0.x + b0.x;
  o[1] = (v0.y - mu) * rstd * g0.y + b0.y;
  o[2] = (v0.z - mu) * rstd * g0.z + b0.z;
  o[3] = (v0.w - mu) * rstd * g0.w + b0.w;
  o[4] = (v1.x - mu) * rstd * g1.x + b1.x;
  o[5] = (v1.y - mu) * rstd * g1.y + b1.y;
  o[6] = (v1.z - mu) * rstd * g1.z + b1.z;
  o[7] = (v1.w - mu) * rstd * g1.w + b1.w;
  float* op = out + (size_t)row * Dd + t * 8;
  *reinterpret_cast<float4*>(op)     = make_float4(o[0], o[1], o[2], o[3]);
  *reinterpret_cast<float4*>(op + 4) = make_float4(o[4], o[5], o[6], o[7]);
  __hip_bfloat16* ob = outb + (size_t)row * Dd + t * 8;
#pragma unroll
  for (int e = 0; e < 8; ++e) ob[e] = __float2bfloat16(o[e]);
}

// ---------------- bf16 MFMA GEMM ----------------
// Double-buffered LDS + counted-vmcnt pipeline (T3 minimal 2-phase) +
// source-pre-swizzled staging for conflict-free ds_read_b128 (ERRATA#21:
// linear gload_lds dest + XOR'd global source + same XOR on read).
// EPI: 0 = f32 write; 1 = mask+scale f32 (scores); 2 = +bias +res f32;
//      3 = +bias, gelu, bf16 write; 4 = bf16 write.
struct GArgs {
  const short* A;  long asb; int lda;
  const short* Bt; long bsb; int ldb;
  float* C; __hip_bfloat16* Cb;
  long czo, czi; int ldc;
  const float* bias;
  const float* res; int ldr;
  const float* rowm; int rms;
  const float* colm; int cms;
  int z0, M, N, K;
};

template<int BM, int BN, int EPI>
__global__ __launch_bounds__(256)
void mgemm(GArgs g) {
  constexpr int WMW = (BN >= 128) ? 2 : 4;
  constexpr int WNW = 4 / WMW;
  constexpr int WM = BM / WMW, WN = BN / WNW;
  constexpr int FM = WM / 16, FN = WN / 16;
  __shared__ __align__(16) short As[2][BM * 64];
  __shared__ __align__(16) short Bs[2][BN * 64];
  const int tid = threadIdx.x, l = tid & 63, w = tid >> 6;
  const int wm = (WNW == 2) ? (w >> 1) : w;
  const int wn = (WNW == 2) ? (w & 1) : 0;
  int bx = blockIdx.x, by = blockIdx.y;
  {  // bijective XCD swizzle (m204): contiguous tile chunk per XCD
    const int gx = gridDim.x, nwg = gx * gridDim.y;
    const int orig = by * gx + bx;
    const int xcd = orig & 7, pos = orig >> 3;
    const int q = nwg >> 3, rmd = nwg & 7;
    const int s = (xcd < rmd ? xcd * (q + 1) : rmd * (q + 1) + (xcd - rmd) * q) + pos;
    bx = s % gx; by = s / gx;
  }
  const int z = blockIdx.z;
  const short* Ab = g.A + (size_t)z * g.asb;
  const short* Bb_ = g.Bt + (size_t)z * g.bsb;
  f32x4 acc[FM][FN] = {};
  const int lr = l & 15, lg = l >> 4;

  // stage tile (k0) into buffer buf; global source chunk XOR'd so that a
  // plain XOR'd read is conflict-free while LDS dest stays linear.
  auto stage = [&](int k0, int buf) {
#pragma unroll
    for (int it = 0; it < BM / 32; ++it) {
      int idx = tid + it * 256, r = idx >> 3, c = idx & 7;
      int gm = by * BM + r;
      if (gm >= g.M) gm = g.M - 1;   // clamp; rows independent, masked at write
      gload16(Ab + (size_t)gm * g.lda + k0 + ((c ^ (r & 7)) * 8), &As[buf][idx * 8]);
    }
#pragma unroll
    for (int it = 0; it < BN / 32; ++it) {
      int idx = tid + it * 256, r = idx >> 3, c = idx & 7;
      int gn = bx * BN + r;
      gload16(Bb_ + (size_t)gn * g.ldb + k0 + ((c ^ (r & 7)) * 8), &Bs[buf][idx * 8]);
    }
  };

  const int NT = g.K >> 6;
  stage(0, 0);
  drain_vm();
  sbar();
  schedbar();
  int cur = 0;
  for (int t = 0; t < NT; ++t) {
    if (t + 1 < NT) stage((t + 1) << 6, cur ^ 1);   // issue BEFORE compute
    schedbar();
#pragma unroll
    for (int ks = 0; ks < 2; ++ks) {
      short8 a[FM], b[FN];
#pragma unroll
      for (int fm = 0; fm < FM; ++fm) {
        int rr = wm * WM + fm * 16 + lr;
        int ch = (ks * 4 + lg) ^ (rr & 7);
        a[fm] = *reinterpret_cast<const short8*>(&As[cur][rr * 64 + ch * 8]);
      }
#pragma unroll
      for (int fn = 0; fn < FN; ++fn) {
        int rn = wn * WN + fn * 16 + lr;
        int ch = (ks * 4 + lg) ^ (rn & 7);
        b[fn] = *reinterpret_cast<const short8*>(&Bs[cur][rn * 64 + ch * 8]);
      }
#pragma unroll
      for (int fm = 0; fm < FM; ++fm)
#pragma unroll
        for (int fn = 0; fn < FN; ++fn)
          acc[fm][fn] = __builtin_amdgcn_mfma_f32_16x16x32_bf16(a[fm], b[fn], acc[fm][fn], 0, 0, 0);
    }
    schedbar();
    drain_vm();       // next-tile stage writes landed (overlapped with MFMA above)
    schedbar();
    sbar();           // all waves done reading cur + all stage writes visible
    schedbar();
    cur ^= 1;
  }

  const int bg = (g.z0 + z) >> 3;                        // global (for masks)
  const size_t zoff = (size_t)(z >> 3) * g.czo + (size_t)(z & 7) * g.czi;  // local
#pragma unroll
  for (int fm = 0; fm < FM; ++fm) {
#pragma unroll
    for (int fn = 0; fn < FN; ++fn) {
#pragma unroll
      for (int r = 0; r < 4; ++r) {
        int m = by * BM + wm * WM + fm * 16 + lg * 4 + r;
        int n = bx * BN + wn * WN + fn * 16 + lr;
        if (m >= g.M) continue;
        float v = acc[fm][fn][r];
        size_t coff = zoff + (size_t)m * g.ldc + n;
        if (EPI == 0) {
          g.C[coff] = v;
        } else if (EPI == 1) {
          float rm = g.rowm[(size_t)bg * g.rms + m];
          float cm = g.colm[(size_t)bg * g.cms + n];
          g.C[coff] = (rm * cm < 0.5f) ? NEGV : v * SCALE;
        } else if (EPI == 2) {
          v += g.bias[n] + g.res[(size_t)m * g.ldr + n];
          g.C[coff] = v;
        } else if (EPI == 3) {
          v = gelu_f(v + g.bias[n]);
          g.Cb[coff] = __float2bfloat16(v);
        } else {
          g.Cb[coff] = __float2bfloat16(v);
        }
      }
    }
  }
}

template<int BM, int BN, int EPI>
static void launch_mgemm(const GArgs& g, int zdim, hipStream_t s) {
  dim3 grid((g.N + BN - 1) / BN, (g.M + BM - 1) / BM, zdim);
  mgemm<BM, BN, EPI><<<grid, 256, 0, s>>>(g);
}

// ---------------- fused x-path score GEMM + dual softmax ----------------
// grid (Nn/128, 16). BM=128, BN=256 (full j-row per block). K=128 (hi|lo).
// Q/Km are BASE pointers; kernel offsets by global bh = z0 + blockIdx.y.
__global__ __launch_bounds__(256)
void score_sx_kernel(const short* __restrict__ Q, const short* __restrict__ Km,
                     const float* __restrict__ mask, const float* __restrict__ kmask,
                     const float* __restrict__ rdT,
                     __hip_bfloat16* __restrict__ P1, __hip_bfloat16* __restrict__ E24,
                     int z0) {
  __shared__ __align__(16) short As[128 * 64];
  __shared__ __align__(16) short Bs[256 * 64];
  __shared__ float red[128 * 2];
  __shared__ float red2[128 * 4];
  const int tid = threadIdx.x, l = tid & 63, w = tid >> 6;
  const int wm = w >> 1, wn = w & 1;
  const int by = blockIdx.x, z = blockIdx.y;
  const int bh = z0 + z, b = bh >> 3;
  const short* Ab = Q + (size_t)bh * Nn * 128;
  const short* Bb = Km + (size_t)bh * MK * 128;
  const int lr = l & 15, lg = l >> 4;
  f32x4 acc[4][8] = {};

  for (int k0 = 0; k0 < 128; k0 += 64) {
    __syncthreads();
#pragma unroll
    for (int it = 0; it < 4; ++it) {
      int idx = tid + it * 256, r = idx >> 3, c = idx & 7;
      gload16(Ab + (size_t)(by * 128 + r) * 128 + k0 + ((c ^ (r & 7)) * 8), As + idx * 8);
    }
#pragma unroll
    for (int it = 0; it < 8; ++it) {
      int idx = tid + it * 256, r = idx >> 3, c = idx & 7;
      gload16(Bb + (size_t)r * 128 + k0 + ((c ^ (r & 7)) * 8), Bs + idx * 8);
    }
    __syncthreads();
#pragma unroll
    for (int ks = 0; ks < 2; ++ks) {
      short8 a[4], bv[8];
#pragma unroll
      for (int fm = 0; fm < 4; ++fm) {
        int rr = wm * 64 + fm * 16 + lr;
        int ch = (ks * 4 + lg) ^ (rr & 7);
        a[fm] = *reinterpret_cast<const short8*>(As + rr * 64 + ch * 8);
      }
#pragma unroll
      for (int fn = 0; fn < 8; ++fn) {
        int rn = wn * 128 + fn * 16 + lr;
        int ch = (ks * 4 + lg) ^ (rn & 7);
        bv[fn] = *reinterpret_cast<const short8*>(Bs + rn * 64 + ch * 8);
      }
#pragma unroll
      for (int fm = 0; fm < 4; ++fm)
#pragma unroll
        for (int fn = 0; fn < 8; ++fn)
          acc[fm][fn] = __builtin_amdgcn_mfma_f32_16x16x32_bf16(a[fm], bv[fn], acc[fm][fn], 0, 0, 0);
    }
  }
  // mask + scale in place
  {
    float colm[8];
#pragma unroll
    for (int fn = 0; fn < 8; ++fn)
      colm[fn] = kmask[b * MK + wn * 128 + fn * 16 + lr];
#pragma unroll
    for (int fm = 0; fm < 4; ++fm)
#pragma unroll
      for (int r = 0; r < 4; ++r) {
        float rm = mask[(size_t)b * Nn + by * 128 + wm * 64 + fm * 16 + lg * 4 + r];
#pragma unroll
        for (int fn = 0; fn < 8; ++fn)
          acc[fm][fn][r] = (rm * colm[fn] < 0.5f) ? NEGV : acc[fm][fn][r] * SCALE;
      }
  }
  // row max: local frags -> 16-lane shfl -> cross-wave via LDS
  float mx[4][4];
#pragma unroll
  for (int fm = 0; fm < 4; ++fm)
#pragma unroll
    for (int r = 0; r < 4; ++r) {
      float m = -3.4e38f;
#pragma unroll
      for (int fn = 0; fn < 8; ++fn) m = fmaxf(m, acc[fm][fn][r]);
#pragma unroll
      for (int o = 8; o; o >>= 1) m = fmaxf(m, __shfl_xor(m, o));
      mx[fm][r] = m;
    }
  __syncthreads();
  if (lr == 0) {
#pragma unroll
    for (int fm = 0; fm < 4; ++fm)
#pragma unroll
      for (int r = 0; r < 4; ++r)
        red[(wm * 64 + fm * 16 + lg * 4 + r) * 2 + wn] = mx[fm][r];
  }
  __syncthreads();
#pragma unroll
  for (int fm = 0; fm < 4; ++fm)
#pragma unroll
    for (int r = 0; r < 4; ++r) {
      int row = wm * 64 + fm * 16 + lg * 4 + r;
      mx[fm][r] = fmaxf(red[row * 2], red[row * 2 + 1]);
    }
  // row sums (e1 & e24)
  float s1[4][4], s24[4][4];
#pragma unroll
  for (int fm = 0; fm < 4; ++fm)
#pragma unroll
    for (int r = 0; r < 4; ++r) {
      float a1 = 0.f, a24 = 0.f;
#pragma unroll
      for (int fn = 0; fn < 8; ++fn) {
        float d = acc[fm][fn][r] - mx[fm][r];
        a1 += __expf(d);
        a24 += __expf(24.f * d);
      }
#pragma unroll
      for (int o = 8; o; o >>= 1) { a1 += __shfl_xor(a1, o); a24 += __shfl_xor(a24, o); }
      s1[fm][r] = a1; s24[fm][r] = a24;
    }
  __syncthreads();
  if (lr == 0) {
#pragma unroll
    for (int fm = 0; fm < 4; ++fm)
#pragma unroll
      for (int r = 0; r < 4; ++r) {
        int row = wm * 64 + fm * 16 + lg * 4 + r;
        red2[row * 4 + wn * 2]     = s1[fm][r];
        red2[row * 4 + wn * 2 + 1] = s24[fm][r];
      }
  }
  __syncthreads();
#pragma unroll
  for (int fm = 0; fm < 4; ++fm)
#pragma unroll
    for (int r = 0; r < 4; ++r) {
      int row = wm * 64 + fm * 16 + lg * 4 + r;
      s1[fm][r]  = 1.f / (red2[row * 4] + red2[row * 4 + 2]);
      s24[fm][r] = 1.f / (red2[row * 4 + 1] + red2[row * 4 + 3]);
    }
  // normalized writes (chunk-local buffers)
#pragma unroll
  for (int fm = 0; fm < 4; ++fm) {
#pragma unroll
    for (int r = 0; r < 4; ++r) {
      int m = by * 128 + wm * 64 + fm * 16 + lg * 4 + r;
      const float* rp = rdT + ((size_t)b * Nn + m) * MK;
      size_t obase = ((size_t)z * Nn + m) * MK;
#pragma unroll
      for (int fn = 0; fn < 8; ++fn) {
        int n = wn * 128 + fn * 16 + lr;
        float d = acc[fm][fn][r] - mx[fm][r];
        float rv = rp[n];
        P1[obase + n]  = __float2bfloat16(__expf(d) * s1[fm][r] * rv);
        E24[obase + n] = __float2bfloat16(__expf(24.f * d) * s24[fm][r] * rv);
      }
    }
  }
}

// ---------------- atten transpose: E24 bf16 [z][i][j] -> f32 [bh][j][i] ----------------
__global__ __launch_bounds__(256)
void at_tr_kernel(const __hip_bfloat16* __restrict__ E, float* __restrict__ atten, int z0) {
  __shared__ __hip_bfloat16 t[64][72];
  const int z = blockIdx.x, bh = z0 + z;
  const int i0 = blockIdx.y * 64, j0 = blockIdx.z * 64;
  const int tid = threadIdx.x;
#pragma unroll
  for (int it = 0; it < 2; ++it) {
    int idx = tid + it * 256, r = idx >> 3, c8 = (idx & 7) * 8;
    short8 v = *reinterpret_cast<const short8*>(
        (const short*)E + ((size_t)z * Nn + i0 + r) * MK + j0 + c8);
#pragma unroll
    for (int e = 0; e < 8; ++e)
      *reinterpret_cast<short*>(&t[r][c8 + e]) = v[e];
  }
  __syncthreads();
#pragma unroll
  for (int it = 0; it < 4; ++it) {
    int idx = tid + it * 256, jr = idx >> 4, c4 = (idx & 15) * 4;
    float4 o;
    o.x = __bfloat162float(t[c4 + 0][jr]);
    o.y = __bfloat162float(t[c4 + 1][jr]);
    o.z = __bfloat162float(t[c4 + 2][jr]);
    o.w = __bfloat162float(t[c4 + 3][jr]);
    *reinterpret_cast<float4*>(
        atten + ((size_t)bh * MK + j0 + jr) * Nn + i0 + c4) = o;
  }
}

// ---------------- rd transpose: [b][j][i] -> rdT [b][i][j] (runs once) ----------------
__global__ __launch_bounds__(256)
void rd_tr_kernel(const float* __restrict__ rd, float* __restrict__ rdT) {
  __shared__ float tb[64][65];
  const int b = blockIdx.x;
  const int i0 = blockIdx.y * 64, j0 = blockIdx.z * 64;
  const int tid = threadIdx.x;
#pragma unroll
  for (int it = 0; it < 4; ++it) {
    int idx = tid + it * 256, r = idx >> 4, c4 = (idx & 15) * 4;   // r: j-local
    float4 v = ldf4(rd + ((size_t)(b * MK + j0 + r)) * Nn + i0 + c4);
    tb[r][c4 + 0] = v.x; tb[r][c4 + 1] = v.y; tb[r][c4 + 2] = v.z; tb[r][c4 + 3] = v.w;
  }
  __syncthreads();
#pragma unroll
  for (int it = 0; it < 4; ++it) {
    int idx = tid + it * 256, r = idx >> 4, c4 = (idx & 15) * 4;   // r: i-local
    float4 o = make_float4(tb[c4 + 0][r], tb[c4 + 1][r], tb[c4 + 2][r], tb[c4 + 3][r]);
    *reinterpret_cast<float4*>(rdT + ((size_t)(b * Nn + i0 + r)) * MK + j0 + c4) = o;
  }
}

// ---------------- weight transpose: f32 [K][N] -> bf16 [N][K] ----------------
__global__ __launch_bounds__(256)
void wtrans_kernel(const float* __restrict__ W, __hip_bfloat16* __restrict__ WT,
                   int K, int N) {
  __shared__ float t[64][65];
  const int n0 = blockIdx.x * 64, k0 = blockIdx.y * 64;
  const int tid = threadIdx.x;
#pragma unroll
  for (int it = 0; it < 4; ++it) {
    int idx = tid + it * 256, r = idx >> 4, f = idx & 15;
    float4 v = ldf4(W + (size_t)(k0 + r) * N + n0 + f * 4);
    t[r][f * 4 + 0] = v.x; t[r][f * 4 + 1] = v.y;
    t[r][f * 4 + 2] = v.z; t[r][f * 4 + 3] = v.w;
  }
  __syncthreads();
#pragma unroll
  for (int it = 0; it < 4; ++it) {
    int idx = tid + it * 256, r = idx >> 4, c4 = (idx & 15) * 4;
    __hip_bfloat16* op = WT + (size_t)(n0 + r) * K + k0 + c4;
#pragma unroll
    for (int e = 0; e < 4; ++e) op[e] = __float2bfloat16(t[c4 + e][r]);
  }
}

// ---------------- qkv split: hi/lo bf16 operand prep ----------------
template<bool Q_SPLIT>
__global__ __launch_bounds__(256)
void split_kernel(const float* __restrict__ qkv, __hip_bfloat16* __restrict__ qout,
                  __hip_bfloat16* __restrict__ kout, int T) {
  const int idx = blockIdx.x * 256 + threadIdx.x;
  const int token = idx >> 7, c8 = (idx & 127) * 8;
  const int b = token / T, i = token - b * T;
  const float* p = qkv + (size_t)token * QLD + c8;
  float v[8];
  float4 a = ldf4(p), c = ldf4(p + 4);
  v[0]=a.x; v[1]=a.y; v[2]=a.z; v[3]=a.w; v[4]=c.x; v[5]=c.y; v[6]=c.z; v[7]=c.w;
  if (c8 < 512) {
    int h = c8 >> 6, d = c8 & 63;
    if (Q_SPLIT) {
      __hip_bfloat16* q = qout + ((size_t)((b * 8 + h) * T + i)) * 128 + d;
#pragma unroll
      for (int e = 0; e < 8; ++e) {
        __hip_bfloat16 hi = __float2bfloat16(v[e]);
        q[e] = hi;
        q[64 + e] = __float2bfloat16(v[e] - __bfloat162float(hi));
      }
    } else {
      __hip_bfloat16* q = qout + ((size_t)((b * 8 + h) * T + i)) * 64 + d;
#pragma unroll
      for (int e = 0; e < 8; ++e) q[e] = __float2bfloat16(v[e]);
    }
  } else {
    int cc = c8 - 512, h = cc >> 6, d = cc & 63;
    if (Q_SPLIT) {
      __hip_bfloat16* k = kout + ((size_t)((b * 8 + h) * T + i)) * 64 + d;
#pragma unroll
      for (int e = 0; e < 8; ++e) k[e] = __float2bfloat16(v[e]);
    } else {
      __hip_bfloat16* k = kout + ((size_t)((b * 8 + h) * T + i)) * 128 + d;
#pragma unroll
      for (int e = 0; e < 8; ++e) {
        __hip_bfloat16 hi = __float2bfloat16(v[e]);
        k[e] = hi;
        k[64 + e] = __float2bfloat16(v[e] - __bfloat162float(hi));
      }
    }
  }
}

// ---------------- v transpose: qkv v-part -> bf16 [bh][d][token] ----------------
__global__ __launch_bounds__(256)
void vtrans_kernel(const float* __restrict__ qkv, __hip_bfloat16* __restrict__ vT, int T) {
  __shared__ float t[64][65];
  const int bh = blockIdx.x, b = bh >> 3, h = bh & 7;
  const int i0 = blockIdx.y * 64;
  const int tid = threadIdx.x;
#pragma unroll
  for (int it = 0; it < 4; ++it) {
    int idx = tid + it * 256, r = idx >> 4, f = idx & 15;
    float4 v = ldf4(qkv + (size_t)(b * T + i0 + r) * QLD + 2 * Dd + h * 64 + f * 4);
    t[r][f * 4 + 0] = v.x; t[r][f * 4 + 1] = v.y;
    t[r][f * 4 + 2] = v.z; t[r][f * 4 + 3] = v.w;
  }
  __syncthreads();
#pragma unroll
  for (int it = 0; it < 4; ++it) {
    int idx = tid + it * 256, d = idx >> 4, c4 = (idx & 15) * 4;
    __hip_bfloat16* op = vT + (size_t)(bh * 64 + d) * T + i0 + c4;
#pragma unroll
    for (int e = 0; e < 4; ++e) op[e] = __float2bfloat16(t[c4 + e][d]);
  }
}

// ---------------- k-path softmax + rd (P2 chunk-local) ----------------
__global__ __launch_bounds__(256)
void softmax_k_kernel(const float* __restrict__ S, const float* __restrict__ rd,
                      __hip_bfloat16* __restrict__ P2, int z0) {
  __shared__ float red8[8];
  const int tid = threadIdx.x;
  const int j = blockIdx.x, zloc = blockIdx.y, b = (z0 + zloc) >> 3;
  const float* row = S + ((size_t)zloc * MK + j) * Nn;
  float d[8];
  float lm = -3.4e38f;
#pragma unroll
  for (int c = 0; c < 8; ++c) { d[c] = row[c * 256 + tid]; lm = fmaxf(lm, d[c]); }
  const float mx = blockMax256(lm, red8);
  float ls = 0.f;
#pragma unroll
  for (int c = 0; c < 8; ++c) { d[c] = __expf(d[c] - mx); ls += d[c]; }
  const float s = blockSum256(ls, red8);
  const float inv = 1.f / s;
  const float* rp = rd + (size_t)(b * MK + j) * Nn;
  __hip_bfloat16* pp = P2 + ((size_t)zloc * MK + j) * Nn;
#pragma unroll
  for (int c = 0; c < 8; ++c)
    pp[c * 256 + tid] = __float2bfloat16(d[c] * inv * rp[c * 256 + tid]);
}

// ------------- cls-token attention: grid B*H, block 256, bf16 out -------------
__global__ __launch_bounds__(256)
void attn_c_kernel(const float* __restrict__ cqkv, const float* __restrict__ kqkv,
                   const float* __restrict__ mask, const float* __restrict__ kmask,
                   __hip_bfloat16* __restrict__ c_pre) {
  __shared__ __align__(16) float kv_s[MK][DH];
  __shared__ __align__(16) float q_s[DH];
  __shared__ float pbuf[MK];
  __shared__ float red8[8];
  __shared__ float redpv[4][DH];
  const int tid = threadIdx.x;
  const int bh = blockIdx.x, b = bh >> 3, h = bh & 7;
  const float* vp = kqkv + ((size_t)(b * MK + tid)) * QLD + 2 * Dd + h * DH;
#pragma unroll
  for (int q4 = 0; q4 < 16; ++q4)
    *reinterpret_cast<float4*>(&kv_s[tid][q4 * 4]) = ldf4(vp + q4 * 4);
  if (tid < DH) q_s[tid] = cqkv[(size_t)b * QLD + h * DH + tid];
  __syncthreads();
  const float* kp = kqkv + ((size_t)(b * MK + tid)) * QLD + Dd + h * DH;
  float dot = 0.f;
#pragma unroll
  for (int q4 = 0; q4 < 16; ++q4) {
    float4 kv4 = ldf4(kp + q4 * 4);
    float4 qv = ldf4(&q_s[q4 * 4]);
    dot = fmaf(qv.x, kv4.x, dot);
    dot = fmaf(qv.y, kv4.y, dot);
    dot = fmaf(qv.z, kv4.z, dot);
    dot = fmaf(qv.w, kv4.w, dot);
  }
  const float dm = (mask[(size_t)b * Nn] * kmask[b * MK + tid] < 0.5f) ? NEGV : dot * SCALE;
  const float mx = blockMax256(dm, red8);
  const float e = __expf(dm - mx);
  const float s = blockSum256(e, red8);
  pbuf[tid] = e / s;
  __syncthreads();
  const int d = tid & 63, g = tid >> 6;
  float acc = 0.f;
#pragma unroll 8
  for (int jj = 0; jj < 64; ++jj)
    acc = fmaf(pbuf[g * 64 + jj], kv_s[g * 64 + jj][d], acc);
  redpv[g][d] = acc;
  __syncthreads();
  if (tid < DH)
    c_pre[(size_t)b * Dd + h * DH + tid] = __float2bfloat16(
        redpv[0][tid] + redpv[1][tid] + redpv[2][tid] + redpv[3][tid]);
}

// ------------- output writers (float32 outputs) -------------
__global__ void kreps_kernel(const float* __restrict__ kx, const float* __restrict__ kmask,
                             float* __restrict__ o) {
  const int idx = blockIdx.x * 256 + threadIdx.x;
  const int bj = idx >> 9;
  const float keep = (kmask[bj] >= 0.5f) ? 1.f : 0.f;
  o[idx] = kx[idx] * keep;
}
__global__ void cout_kernel(const float* __restrict__ c_s, float* __restrict__ o) {
  const int idx = blockIdx.x * 256 + threadIdx.x;
  o[idx] = c_s[idx];
}

static GArgs ga_base() { GArgs g = {}; return g; }

extern "C" void kernel_launch(void* const* d_in, const int* in_sizes, int n_in,
                              void* d_out, int out_size, void* d_ws, size_t ws_size,
                              hipStream_t stream) {
  (void)in_sizes; (void)n_in; (void)out_size; (void)ws_size;
  const float* x_in  = (const float*)d_in[0];
  const float* kx_in = (const float*)d_in[1];
  const float* rd    = (const float*)d_in[2];
  const float* c_in  = (const float*)d_in[3];
  const float* mask  = (const float*)d_in[4];
  const float* kmask = (const float*)d_in[5];
  const float* ln1g  = (const float*)d_in[6];
  const float* ln1b  = (const float*)d_in[7];
  const float* Wqkv  = (const float*)d_in[8];
  const float* Woutw = (const float*)d_in[9];
  const float* boutw = (const float*)d_in[10];
  const float* ln2g  = (const float*)d_in[11];
  const float* ln2b  = (const float*)d_in[12];
  const float* W1    = (const float*)d_in[13];
  const float* b1    = (const float*)d_in[14];
  const float* W2    = (const float*)d_in[15];
  const float* b2    = (const float*)d_in[16];
  float* out = (float*)d_out;

  float* ws = (float*)d_ws;
  size_t off = 0;
  auto alloc = [&](size_t n) { float* p = ws + off; off += (n + 15) & ~(size_t)15; return p; };
  float* xcat_s   = alloc((size_t)NTOK * Dd);       // residual state (all tokens)
  float* xcat_n   = alloc((size_t)NTOK * Dd);       // LN output f32
  float* xcat_nb_f = alloc((size_t)NTOK * Dd / 2);  // LN output bf16
  float* pre_cat_f = alloc((size_t)NTOK * Dd / 2);  // attention out bf16
  float* qkv      = alloc((size_t)NTOK * QLD);      // hosts P1/E24/P2, then hid
  float* S        = alloc((size_t)16 * MK * Nn);    // k-path scores (per chunk)
  float* tq_s_f   = alloc((size_t)32 * Nn * 128 / 2);
  float* kk_s_f   = alloc((size_t)32 * MK * 128 / 2);
  float* tk_hi_f  = alloc((size_t)32 * Nn * 64 / 2);
  float* kq_hi_f  = alloc((size_t)32 * MK * 64 / 2);
  float* tvT_f    = alloc((size_t)32 * 64 * Nn / 2);
  float* kvT_f    = alloc((size_t)32 * 64 * MK / 2);
  float* rdT      = alloc((size_t)Bb * Nn * MK);
  float* WqkvT_f  = alloc((size_t)QLD * Dd / 2);
  float* WoutT_f  = alloc((size_t)Dd * Dd / 2);
  float* W1T_f    = alloc((size_t)MLPD * Dd / 2);
  float* W2T_f    = alloc((size_t)Dd * MLPD / 2);

  __hip_bfloat16* xcat_nb = (__hip_bfloat16*)xcat_nb_f;
  __hip_bfloat16* pre_cat = (__hip_bfloat16*)pre_cat_f;
  __hip_bfloat16* tq_s    = (__hip_bfloat16*)tq_s_f;
  __hip_bfloat16* kk_s    = (__hip_bfloat16*)kk_s_f;
  __hip_bfloat16* tk_hi   = (__hip_bfloat16*)tk_hi_f;
  __hip_bfloat16* kq_hi   = (__hip_bfloat16*)kq_hi_f;
  __hip_bfloat16* tvT     = (__hip_bfloat16*)tvT_f;
  __hip_bfloat16* kvT     = (__hip_bfloat16*)kvT_f;
  __hip_bfloat16* WqkvT   = (__hip_bfloat16*)WqkvT_f;
  __hip_bfloat16* WoutT   = (__hip_bfloat16*)WoutT_f;
  __hip_bfloat16* W1T     = (__hip_bfloat16*)W1T_f;
  __hip_bfloat16* W2T     = (__hip_bfloat16*)W2T_f;
  // overlays inside qkv: P1+E24+P2 fill exactly the x-token region (12.58M f32)
  __hip_bfloat16* P1b  = (__hip_bfloat16*)qkv;
  __hip_bfloat16* E24b = (__hip_bfloat16*)(qkv + (size_t)16 * Nn * MK / 2);
  __hip_bfloat16* P2b  = (__hip_bfloat16*)(qkv + (size_t)16 * Nn * MK);
  __hip_bfloat16* hid  = (__hip_bfloat16*)qkv;      // FF hidden, after attention

  const size_t CL_OFF = (size_t)2 * Bb * MK * Dd;
  const size_t AT_OFF = CL_OFF + (size_t)Bb * Dd;

  rd_tr_kernel<<<dim3(Bb, Nn / 64, MK / 64), 256, 0, stream>>>(rd, rdT);

  for (int l = 0; l < 2; ++l) {
    const float* g1 = ln1g + l * Dd; const float* bb1 = ln1b + l * Dd;
    ln_kernel<<<Bb * Nn, 64, 0, stream>>>(l ? xcat_s : x_in, g1, bb1, xcat_n, xcat_nb);
    ln_kernel<<<Bb * MK, 64, 0, stream>>>(l ? xcat_s + (size_t)KXOFF * Dd : kx_in, g1, bb1,
                                          xcat_n + (size_t)KXOFF * Dd,
                                          xcat_nb + (size_t)KXOFF * Dd);
    ln_kernel<<<Bb, 64, 0, stream>>>(l ? xcat_s + (size_t)CLOFF * Dd : c_in, g1, bb1,
                                     xcat_n + (size_t)CLOFF * Dd,
                                     xcat_nb + (size_t)CLOFF * Dd);

    const float* Wq = Wqkv + (size_t)l * Dd * QLD;
    const float* Wo = Woutw + (size_t)l * Dd * Dd;
    const float* bo = boutw + (size_t)l * Dd;
    const float* W1l = W1 + (size_t)l * Dd * MLPD;
    const float* b1l = b1 + (size_t)l * MLPD;
    const float* W2l = W2 + (size_t)l * MLPD * Dd;
    const float* b2l = b2 + (size_t)l * Dd;
    wtrans_kernel<<<dim3(QLD / 64, Dd / 64), 256, 0, stream>>>(Wq, WqkvT, Dd, QLD);
    wtrans_kernel<<<dim3(Dd / 64, Dd / 64), 256, 0, stream>>>(Wo, WoutT, Dd, Dd);
    wtrans_kernel<<<dim3(MLPD / 64, Dd / 64), 256, 0, stream>>>(W1l, W1T, Dd, MLPD);
    wtrans_kernel<<<dim3(Dd / 64, MLPD / 64), 256, 0, stream>>>(W2l, W2T, MLPD, Dd);

    // QKV: one GEMM over all 9220 rows
    {
      GArgs g = ga_base();
      g.A = (const short*)xcat_nb; g.lda = Dd;
      g.Bt = (const short*)WqkvT; g.ldb = Dd;
      g.C = qkv; g.ldc = QLD;
      g.M = NTOK; g.N = QLD; g.K = Dd;
      launch_mgemm<128, 128, 0>(g, 1, stream);
    }

    split_kernel<true><<<(Bb * Nn * 128) / 256, 256, 0, stream>>>(qkv, tq_s, tk_hi, Nn);
    split_kernel<false><<<(Bb * MK * 128) / 256, 256, 0, stream>>>(
        qkv + (size_t)KXOFF * QLD, kq_hi, kk_s, MK);
    vtrans_kernel<<<dim3(32, Nn / 64), 256, 0, stream>>>(qkv, tvT, Nn);
    vtrans_kernel<<<dim3(32, MK / 64), 256, 0, stream>>>(qkv + (size_t)KXOFF * QLD, kvT, MK);

    attn_c_kernel<<<Bb * Hh, 256, 0, stream>>>(qkv + (size_t)CLOFF * QLD,
                                               qkv + (size_t)KXOFF * QLD, mask, kmask,
                                               pre_cat + (size_t)CLOFF * Dd);

    for (int ch = 0; ch < 2; ++ch) {
      // ---- x-path: fused score+softmax, atten transpose, PV ----
      score_sx_kernel<<<dim3(Nn / 128, 16), 256, 0, stream>>>(
          (const short*)tq_s, (const short*)kk_s,
          mask, kmask, rdT, P1b, E24b, ch * 16);
      at_tr_kernel<<<dim3(16, Nn / 64, MK / 64), 256, 0, stream>>>(
          E24b, out + AT_OFF + (size_t)l * 32 * MK * Nn, ch * 16);
      {
        GArgs g = ga_base();
        g.A = (const short*)P1b; g.asb = (long)Nn * MK; g.lda = MK;
        g.Bt = (const short*)(kvT + (size_t)ch * 16 * 64 * MK); g.bsb = (long)64 * MK; g.ldb = MK;
        g.Cb = pre_cat + (size_t)(2 * ch) * Nn * Dd; g.czo = (long)Nn * Dd; g.czi = 64; g.ldc = Dd;
        g.M = Nn; g.N = 64; g.K = MK;
        launch_mgemm<128, 64, 4>(g, 16, stream);
      }
      // ---- k-path: score GEMM -> softmax -> PV ----
      {
        GArgs g = ga_base();
        g.A = (const short*)(kq_hi + (size_t)ch * 16 * MK * 64); g.asb = (long)MK * 64; g.lda = 64;
        g.Bt = (const short*)(tk_hi + (size_t)ch * 16 * Nn * 64); g.bsb = (long)Nn * 64; g.ldb = 64;
        g.C = S; g.czi = (long)MK * Nn; g.czo = 8L * MK * Nn; g.ldc = Nn;
        g.rowm = kmask; g.rms = MK; g.colm = mask; g.cms = Nn;
        g.z0 = ch * 16; g.M = MK; g.N = Nn; g.K = 64;
        launch_mgemm<128, 128, 1>(g, 16, stream);
      }
      softmax_k_kernel<<<dim3(MK, 16), 256, 0, stream>>>(S, rd, P2b, ch * 16);
      {
        GArgs g = ga_base();
        g.A = (const short*)P2b; g.asb = (long)MK * Nn; g.lda = Nn;
        g.Bt = (const short*)(tvT + (size_t)ch * 16 * 64 * Nn); g.bsb = (long)64 * Nn; g.ldb = Nn;
        g.Cb = pre_cat + (size_t)KXOFF * Dd + (size_t)(2 * ch) * MK * Dd;
        g.czo = (long)MK * Dd; g.czi = 64; g.ldc = Dd;
        g.M = MK; g.N = 64; g.K = Nn;
        launch_mgemm<64, 64, 4>(g, 16, stream);
      }
    }

    // ---- Wout + residual over all rows ----
    {
      GArgs g = ga_base();
      g.A = (const short*)pre_cat; g.lda = Dd;
      g.Bt = (const short*)WoutT; g.ldb = Dd;
      g.C = xcat_s; g.ldc = Dd; g.bias = bo; g.res = xcat_n; g.ldr = Dd;
      g.M = NTOK; g.N = Dd; g.K = Dd;
      launch_mgemm<128, 64, 2>(g, 1, stream);
    }

    // ---- FF over all rows ----
    ln_kernel<<<NTOK, 64, 0, stream>>>(xcat_s, ln2g + l * Dd, ln2b + l * Dd, xcat_n, xcat_nb);
    {
      GArgs g = ga_base();
      g.A = (const short*)xcat_nb; g.lda = Dd;
      g.Bt = (const short*)W1T; g.ldb = Dd;
      g.Cb = hid; g.ldc = MLPD; g.bias = b1l;
      g.M = NTOK; g.N = MLPD; g.K = Dd;
      launch_mgemm<128, 128, 3>(g, 1, stream);
      GArgs h = ga_base();
      h.A = (const short*)hid; h.lda = MLPD;
      h.Bt = (const short*)W2T; h.ldb = MLPD;
      h.C = xcat_s; h.ldc = Dd; h.bias = b2l; h.res = xcat_s; h.ldr = Dd;
      h.M = NTOK; h.N = Dd; h.K = MLPD;
      launch_mgemm<128, 64, 2>(h, 1, stream);
    }

    kreps_kernel<<<(Bb * MK * Dd) / 256, 256, 0, stream>>>(
        xcat_s + (size_t)KXOFF * Dd, kmask, out + (size_t)l * Bb * MK * Dd);
  }
  cout_kernel<<<(Bb * Dd) / 256, 256, 0, stream>>>(xcat_s + (size_t)CLOFF * Dd, out + CL_OFF);
}

// Round 10
// 925.798 us; speedup vs baseline: 1.1222x; 1.0301x over previous
//
#include <hip/hip_runtime.h>
#include <hip/hip_bf16.h>
#include <cstddef>

#define DEV __device__ __forceinline__

constexpr int Bb  = 4;
constexpr int Nn  = 2048;
constexpr int MK  = 256;
constexpr int Dd  = 512;
constexpr int Hh  = 8;
constexpr int DH  = 64;
constexpr int QLD = 1536;   // qkv row stride (3*512)
constexpr int MLPD = 2048;
constexpr int NTOK = Bb * Nn + Bb * MK + Bb;   // 9220 concatenated rows
constexpr int KXOFF = Bb * Nn;                 // 8192: first kx row
constexpr int CLOFF = Bb * Nn + Bb * MK;       // 9216: first cls row
constexpr float SCALE = 0.125f;   // 64^-0.5
constexpr float NEGV  = -1e9f;

typedef __attribute__((ext_vector_type(8))) short short8;
typedef __attribute__((ext_vector_type(4))) float f32x4;

DEV float4 ldf4(const float* p) { return *reinterpret_cast<const float4*>(p); }

// async global->LDS, 16B per lane, linear LDS dest
DEV void gload16(const short* g, short* l) {
  __builtin_amdgcn_global_load_lds(
      (const __attribute__((address_space(1))) void*)g,
      (__attribute__((address_space(3))) void*)l, 16, 0, 0);
}
DEV void drain_vm() { asm volatile("s_waitcnt vmcnt(0)" ::: "memory"); }
DEV void sbar() { __builtin_amdgcn_s_barrier(); }
DEV void schedbar() { __builtin_amdgcn_sched_barrier(0); }

DEV float waveMax(float v) {
#pragma unroll
  for (int o = 32; o; o >>= 1) v = fmaxf(v, __shfl_xor(v, o));
  return v;
}
DEV float waveSum(float v) {
#pragma unroll
  for (int o = 32; o; o >>= 1) v += __shfl_xor(v, o);
  return v;
}
DEV float blockMax256(float v, float* red) {
  v = waveMax(v);
  __syncthreads();
  if ((threadIdx.x & 63) == 0) red[threadIdx.x >> 6] = v;
  __syncthreads();
  return fmaxf(fmaxf(red[0], red[1]), fmaxf(red[2], red[3]));
}
DEV float blockSum256(float v, float* red) {
  v = waveSum(v);
  __syncthreads();
  if ((threadIdx.x & 63) == 0) red[threadIdx.x >> 6] = v;
  __syncthreads();
  return red[0] + red[1] + red[2] + red[3];
}
DEV float gelu_f(float x) { return 0.5f * x * (1.f + erff(x * 0.70710678118654752f)); }

// ---------------- input concat copy: {x, kx, cls} -> xcat_s ----------------
__global__ __launch_bounds__(256)
void copy3_kernel(const float* __restrict__ x, const float* __restrict__ kx,
                  const float* __restrict__ c, float* __restrict__ dst) {
  const int idx = blockIdx.x * 256 + threadIdx.x;   // float4 index
  const int row = idx >> 7;
  float4 v;
  if (row < KXOFF) v = ldf4(x + (size_t)idx * 4);
  else if (row < CLOFF) v = ldf4(kx + (size_t)idx * 4 - (size_t)KXOFF * Dd);
  else v = ldf4(c + (size_t)idx * 4 - (size_t)CLOFF * Dd);
  *reinterpret_cast<float4*>(dst + (size_t)idx * 4) = v;
}

// ---------------- LayerNorm: one wave per 512-float row, dual f32+bf16 out ----------------
__global__ __launch_bounds__(64)
void ln_kernel(const float* __restrict__ in, const float* __restrict__ gw,
               const float* __restrict__ bw, float* __restrict__ out,
               __hip_bfloat16* __restrict__ outb) {
  const int row = blockIdx.x;
  const int t = threadIdx.x;
  const float* p = in + (size_t)row * Dd + t * 8;
  float4 v0 = ldf4(p), v1 = ldf4(p + 4);
  float s = v0.x + v0.y + v0.z + v0.w + v1.x + v1.y + v1.z + v1.w;
  float q = v0.x*v0.x + v0.y*v0.y + v0.z*v0.z + v0.w*v0.w
          + v1.x*v1.x + v1.y*v1.y + v1.z*v1.z + v1.w*v1.w;
  s = waveSum(s); q = waveSum(q);
  const float mu = s * (1.f / Dd);
  const float rstd = rsqrtf(fmaxf(q * (1.f / Dd) - mu * mu, 0.f) + 1e-5f);
  float4 g0 = ldf4(gw + t * 8), g1 = ldf4(gw + t * 8 + 4);
  float4 b0 = ldf4(bw + t * 8), b1 = ldf4(bw + t * 8 + 4);
  float o[8];
  o[0] = (v0.x - mu) * rstd * g0.x + b0.x;
  o[1] = (v0.y - mu) * rstd * g0.y + b0.y;
  o[2] = (v0.z - mu) * rstd * g0.z + b0.z;
  o[3] = (v0.w - mu) * rstd * g0.w + b0.w;
  o[4] = (v1.x - mu) * rstd * g1.x + b1.x;
  o[5] = (v1.y - mu) * rstd * g1.y + b1.y;
  o[6] = (v1.z - mu) * rstd * g1.z + b1.z;
  o[7] = (v1.w - mu) * rstd * g1.w + b1.w;
  float* op = out + (size_t)row * Dd + t * 8;
  *reinterpret_cast<float4*>(op)     = make_float4(o[0], o[1], o[2], o[3]);
  *reinterpret_cast<float4*>(op + 4) = make_float4(o[4], o[5], o[6], o[7]);
  __hip_bfloat16* ob = outb + (size_t)row * Dd + t * 8;
#pragma unroll
  for (int e = 0; e < 8; ++e) ob[e] = __float2bfloat16(o[e]);
}

// ---------------- bf16 MFMA GEMM (pipelined, source-pre-swizzled) ----------------
// EPI: 0 = f32 write; 2 = +bias +res f32; 3 = +bias, gelu, bf16; 4 = bf16.
struct GArgs {
  const short* A;  long asb; int lda;
  const short* Bt; long bsb; int ldb;
  float* C; __hip_bfloat16* Cb;
  long czo, czi; int ldc;
  const float* bias;
  const float* res; int ldr;
  int M, N, K;
};

template<int BM, int BN, int EPI>
__global__ __launch_bounds__(256)
void mgemm(GArgs g) {
  constexpr int WMW = (BN >= 128) ? 2 : 4;
  constexpr int WNW = 4 / WMW;
  constexpr int WM = BM / WMW, WN = BN / WNW;
  constexpr int FM = WM / 16, FN = WN / 16;
  __shared__ __align__(16) short As[2][BM * 64];
  __shared__ __align__(16) short Bs[2][BN * 64];
  const int tid = threadIdx.x, l = tid & 63, w = tid >> 6;
  const int wm = (WNW == 2) ? (w >> 1) : w;
  const int wn = (WNW == 2) ? (w & 1) : 0;
  int bx = blockIdx.x, by = blockIdx.y;
  {  // bijective XCD swizzle (m204)
    const int gx = gridDim.x, nwg = gx * gridDim.y;
    const int orig = by * gx + bx;
    const int xcd = orig & 7, pos = orig >> 3;
    const int q = nwg >> 3, rmd = nwg & 7;
    const int s = (xcd < rmd ? xcd * (q + 1) : rmd * (q + 1) + (xcd - rmd) * q) + pos;
    bx = s % gx; by = s / gx;
  }
  const int z = blockIdx.z;
  const short* Ab = g.A + (size_t)z * g.asb;
  const short* Bb_ = g.Bt + (size_t)z * g.bsb;
  f32x4 acc[FM][FN] = {};
  const int lr = l & 15, lg = l >> 4;

  auto stage = [&](int k0, int buf) {
#pragma unroll
    for (int it = 0; it < BM / 32; ++it) {
      int idx = tid + it * 256, r = idx >> 3, c = idx & 7;
      int gm = by * BM + r;
      if (gm >= g.M) gm = g.M - 1;
      gload16(Ab + (size_t)gm * g.lda + k0 + ((c ^ (r & 7)) * 8), &As[buf][idx * 8]);
    }
#pragma unroll
    for (int it = 0; it < BN / 32; ++it) {
      int idx = tid + it * 256, r = idx >> 3, c = idx & 7;
      int gn = bx * BN + r;
      gload16(Bb_ + (size_t)gn * g.ldb + k0 + ((c ^ (r & 7)) * 8), &Bs[buf][idx * 8]);
    }
  };

  const int NT = g.K >> 6;
  stage(0, 0);
  drain_vm();
  sbar();
  schedbar();
  int cur = 0;
  for (int t = 0; t < NT; ++t) {
    if (t + 1 < NT) stage((t + 1) << 6, cur ^ 1);   // issue BEFORE compute
    schedbar();
#pragma unroll
    for (int ks = 0; ks < 2; ++ks) {
      short8 a[FM], b[FN];
#pragma unroll
      for (int fm = 0; fm < FM; ++fm) {
        int rr = wm * WM + fm * 16 + lr;
        int ch = (ks * 4 + lg) ^ (rr & 7);
        a[fm] = *reinterpret_cast<const short8*>(&As[cur][rr * 64 + ch * 8]);
      }
#pragma unroll
      for (int fn = 0; fn < FN; ++fn) {
        int rn = wn * WN + fn * 16 + lr;
        int ch = (ks * 4 + lg) ^ (rn & 7);
        b[fn] = *reinterpret_cast<const short8*>(&Bs[cur][rn * 64 + ch * 8]);
      }
#pragma unroll
      for (int fm = 0; fm < FM; ++fm)
#pragma unroll
        for (int fn = 0; fn < FN; ++fn)
          acc[fm][fn] = __builtin_amdgcn_mfma_f32_16x16x32_bf16(a[fm], b[fn], acc[fm][fn], 0, 0, 0);
    }
    schedbar();
    drain_vm();
    schedbar();
    sbar();
    schedbar();
    cur ^= 1;
  }

  const size_t zoff = (size_t)(z >> 3) * g.czo + (size_t)(z & 7) * g.czi;
#pragma unroll
  for (int fm = 0; fm < FM; ++fm) {
#pragma unroll
    for (int fn = 0; fn < FN; ++fn) {
#pragma unroll
      for (int r = 0; r < 4; ++r) {
        int m = by * BM + wm * WM + fm * 16 + lg * 4 + r;
        int n = bx * BN + wn * WN + fn * 16 + lr;
        if (m >= g.M) continue;
        float v = acc[fm][fn][r];
        size_t coff = zoff + (size_t)m * g.ldc + n;
        if (EPI == 0) {
          g.C[coff] = v;
        } else if (EPI == 2) {
          v += g.bias[n] + g.res[(size_t)m * g.ldr + n];
          g.C[coff] = v;
        } else if (EPI == 3) {
          v = gelu_f(v + g.bias[n]);
          g.Cb[coff] = __float2bfloat16(v);
        } else {
          g.Cb[coff] = __float2bfloat16(v);
        }
      }
    }
  }
}

template<int BM, int BN, int EPI>
static void launch_mgemm(const GArgs& g, int zdim, hipStream_t s) {
  dim3 grid((g.N + BN - 1) / BN, (g.M + BM - 1) / BM, zdim);
  mgemm<BM, BN, EPI><<<grid, 256, 0, s>>>(g);
}

// ---------------- fused x-path score GEMM + dual softmax ----------------
// grid (Nn/128, 32). BM=128, BN=256 (full j-row per block). K=128 (hi|lo).
__global__ __launch_bounds__(256)
void score_sx_kernel(const short* __restrict__ Q, const short* __restrict__ Km,
                     const float* __restrict__ mask, const float* __restrict__ kmask,
                     const float* __restrict__ rdT,
                     __hip_bfloat16* __restrict__ P1, __hip_bfloat16* __restrict__ E24) {
  __shared__ __align__(16) short As[128 * 64];
  __shared__ __align__(16) short Bs[256 * 64];
  __shared__ float red[128 * 2];
  __shared__ float red2[128 * 4];
  const int tid = threadIdx.x, l = tid & 63, w = tid >> 6;
  const int wm = w >> 1, wn = w & 1;
  const int by = blockIdx.x, bh = blockIdx.y;
  const int b = bh >> 3;
  const short* Ab = Q + (size_t)bh * Nn * 128;
  const short* Bb = Km + (size_t)bh * MK * 128;
  const int lr = l & 15, lg = l >> 4;
  f32x4 acc[4][8] = {};

  for (int k0 = 0; k0 < 128; k0 += 64) {
    __syncthreads();
#pragma unroll
    for (int it = 0; it < 4; ++it) {
      int idx = tid + it * 256, r = idx >> 3, c = idx & 7;
      gload16(Ab + (size_t)(by * 128 + r) * 128 + k0 + ((c ^ (r & 7)) * 8), As + idx * 8);
    }
#pragma unroll
    for (int it = 0; it < 8; ++it) {
      int idx = tid + it * 256, r = idx >> 3, c = idx & 7;
      gload16(Bb + (size_t)r * 128 + k0 + ((c ^ (r & 7)) * 8), Bs + idx * 8);
    }
    __syncthreads();
#pragma unroll
    for (int ks = 0; ks < 2; ++ks) {
      short8 a[4], bv[8];
#pragma unroll
      for (int fm = 0; fm < 4; ++fm) {
        int rr = wm * 64 + fm * 16 + lr;
        int ch = (ks * 4 + lg) ^ (rr & 7);
        a[fm] = *reinterpret_cast<const short8*>(As + rr * 64 + ch * 8);
      }
#pragma unroll
      for (int fn = 0; fn < 8; ++fn) {
        int rn = wn * 128 + fn * 16 + lr;
        int ch = (ks * 4 + lg) ^ (rn & 7);
        bv[fn] = *reinterpret_cast<const short8*>(Bs + rn * 64 + ch * 8);
      }
#pragma unroll
      for (int fm = 0; fm < 4; ++fm)
#pragma unroll
        for (int fn = 0; fn < 8; ++fn)
          acc[fm][fn] = __builtin_amdgcn_mfma_f32_16x16x32_bf16(a[fm], bv[fn], acc[fm][fn], 0, 0, 0);
    }
  }
  {
    float colm[8];
#pragma unroll
    for (int fn = 0; fn < 8; ++fn)
      colm[fn] = kmask[b * MK + wn * 128 + fn * 16 + lr];
#pragma unroll
    for (int fm = 0; fm < 4; ++fm)
#pragma unroll
      for (int r = 0; r < 4; ++r) {
        float rm = mask[(size_t)b * Nn + by * 128 + wm * 64 + fm * 16 + lg * 4 + r];
#pragma unroll
        for (int fn = 0; fn < 8; ++fn)
          acc[fm][fn][r] = (rm * colm[fn] < 0.5f) ? NEGV : acc[fm][fn][r] * SCALE;
      }
  }
  float mx[4][4];
#pragma unroll
  for (int fm = 0; fm < 4; ++fm)
#pragma unroll
    for (int r = 0; r < 4; ++r) {
      float m = -3.4e38f;
#pragma unroll
      for (int fn = 0; fn < 8; ++fn) m = fmaxf(m, acc[fm][fn][r]);
#pragma unroll
      for (int o = 8; o; o >>= 1) m = fmaxf(m, __shfl_xor(m, o));
      mx[fm][r] = m;
    }
  __syncthreads();
  if (lr == 0) {
#pragma unroll
    for (int fm = 0; fm < 4; ++fm)
#pragma unroll
      for (int r = 0; r < 4; ++r)
        red[(wm * 64 + fm * 16 + lg * 4 + r) * 2 + wn] = mx[fm][r];
  }
  __syncthreads();
#pragma unroll
  for (int fm = 0; fm < 4; ++fm)
#pragma unroll
    for (int r = 0; r < 4; ++r) {
      int row = wm * 64 + fm * 16 + lg * 4 + r;
      mx[fm][r] = fmaxf(red[row * 2], red[row * 2 + 1]);
    }
  float s1[4][4], s24[4][4];
#pragma unroll
  for (int fm = 0; fm < 4; ++fm)
#pragma unroll
    for (int r = 0; r < 4; ++r) {
      float a1 = 0.f, a24 = 0.f;
#pragma unroll
      for (int fn = 0; fn < 8; ++fn) {
        float d = acc[fm][fn][r] - mx[fm][r];
        a1 += __expf(d);
        a24 += __expf(24.f * d);
      }
#pragma unroll
      for (int o = 8; o; o >>= 1) { a1 += __shfl_xor(a1, o); a24 += __shfl_xor(a24, o); }
      s1[fm][r] = a1; s24[fm][r] = a24;
    }
  __syncthreads();
  if (lr == 0) {
#pragma unroll
    for (int fm = 0; fm < 4; ++fm)
#pragma unroll
      for (int r = 0; r < 4; ++r) {
        int row = wm * 64 + fm * 16 + lg * 4 + r;
        red2[row * 4 + wn * 2]     = s1[fm][r];
        red2[row * 4 + wn * 2 + 1] = s24[fm][r];
      }
  }
  __syncthreads();
#pragma unroll
  for (int fm = 0; fm < 4; ++fm)
#pragma unroll
    for (int r = 0; r < 4; ++r) {
      int row = wm * 64 + fm * 16 + lg * 4 + r;
      s1[fm][r]  = 1.f / (red2[row * 4] + red2[row * 4 + 2]);
      s24[fm][r] = 1.f / (red2[row * 4 + 1] + red2[row * 4 + 3]);
    }
#pragma unroll
  for (int fm = 0; fm < 4; ++fm) {
#pragma unroll
    for (int r = 0; r < 4; ++r) {
      int m = by * 128 + wm * 64 + fm * 16 + lg * 4 + r;
      const float* rp = rdT + ((size_t)b * Nn + m) * MK;
      size_t obase = ((size_t)bh * Nn + m) * MK;
#pragma unroll
      for (int fn = 0; fn < 8; ++fn) {
        int n = wn * 128 + fn * 16 + lr;
        float d = acc[fm][fn][r] - mx[fm][r];
        float rv = rp[n];
        P1[obase + n]  = __float2bfloat16(__expf(d) * s1[fm][r] * rv);
        E24[obase + n] = __float2bfloat16(__expf(24.f * d) * s24[fm][r] * rv);
      }
    }
  }
}

// ---------------- fused k-path score GEMM + softmax (replaces S + softmax_k) ----------------
// grid (32 bh, MK/16). Block: 16 j-rows x full 2048-i row. K=64 (hi only).
__global__ __launch_bounds__(256)
void score_sk_kernel(const short* __restrict__ Qk, const short* __restrict__ Kt,
                     const float* __restrict__ mask, const float* __restrict__ kmask,
                     const float* __restrict__ rd, __hip_bfloat16* __restrict__ P2) {
  __shared__ __align__(16) short As[16 * 64];
  __shared__ __align__(16) short Bs[256 * 64];
  __shared__ float redm[16 * 4];
  __shared__ float reds[16 * 4];
  const int tid = threadIdx.x, l = tid & 63, w = tid >> 6;
  const int lr = l & 15, lg = l >> 4;
  const int bh = blockIdx.x, j0 = blockIdx.y * 16, b = bh >> 3;
  const short* Ab = Qk + ((size_t)bh * MK + j0) * 64;
  const short* Bb = Kt + (size_t)bh * Nn * 64;
  f32x4 acc[32];
#pragma unroll
  for (int q = 0; q < 32; ++q) acc[q] = f32x4{0.f, 0.f, 0.f, 0.f};
  if (tid < 128) {     // stage A once: 16 rows x 64 (first two waves, contiguous dst)
    int r = tid >> 3, c = tid & 7;
    gload16(Ab + (size_t)r * 64 + ((c ^ (r & 7)) * 8), As + tid * 8);
  }
#pragma unroll
  for (int nc = 0; nc < 8; ++nc) {
    __syncthreads();
#pragma unroll
    for (int it = 0; it < 8; ++it) {
      int idx = tid + it * 256, r = idx >> 3, c = idx & 7;
      gload16(Bb + (size_t)(nc * 256 + r) * 64 + ((c ^ (r & 7)) * 8), Bs + idx * 8);
    }
    __syncthreads();
#pragma unroll
    for (int ks = 0; ks < 2; ++ks) {
      short8 a;
      {
        int ch = (ks * 4 + lg) ^ (lr & 7);
        a = *reinterpret_cast<const short8*>(As + lr * 64 + ch * 8);
      }
#pragma unroll
      for (int fn = 0; fn < 4; ++fn) {
        int rn = w * 64 + fn * 16 + lr;
        int ch = (ks * 4 + lg) ^ (rn & 7);
        short8 bv = *reinterpret_cast<const short8*>(Bs + rn * 64 + ch * 8);
        acc[nc * 4 + fn] =
            __builtin_amdgcn_mfma_f32_16x16x32_bf16(a, bv, acc[nc * 4 + fn], 0, 0, 0);
      }
    }
  }
  // mask + scale; row j = j0 + lg*4 + rr; col n = (q>>2)*256 + w*64 + (q&3)*16 + lr
  float rm[4];
#pragma unroll
  for (int rr = 0; rr < 4; ++rr) rm[rr] = kmask[b * MK + j0 + lg * 4 + rr];
  float mx[4] = {-3.4e38f, -3.4e38f, -3.4e38f, -3.4e38f};
#pragma unroll
  for (int q = 0; q < 32; ++q) {
    int n = (q >> 2) * 256 + w * 64 + (q & 3) * 16 + lr;
    float cm = mask[(size_t)b * Nn + n];
#pragma unroll
    for (int rr = 0; rr < 4; ++rr) {
      float v = (rm[rr] * cm < 0.5f) ? NEGV : acc[q][rr] * SCALE;
      acc[q][rr] = v;
      mx[rr] = fmaxf(mx[rr], v);
    }
  }
#pragma unroll
  for (int o = 8; o; o >>= 1)
#pragma unroll
    for (int rr = 0; rr < 4; ++rr) mx[rr] = fmaxf(mx[rr], __shfl_xor(mx[rr], o));
  __syncthreads();
  if (lr == 0) {
#pragma unroll
    for (int rr = 0; rr < 4; ++rr) redm[(lg * 4 + rr) * 4 + w] = mx[rr];
  }
  __syncthreads();
#pragma unroll
  for (int rr = 0; rr < 4; ++rr) {
    int row = lg * 4 + rr;
    mx[rr] = fmaxf(fmaxf(redm[row * 4], redm[row * 4 + 1]),
                   fmaxf(redm[row * 4 + 2], redm[row * 4 + 3]));
  }
  float sm[4] = {0.f, 0.f, 0.f, 0.f};
#pragma unroll
  for (int q = 0; q < 32; ++q)
#pragma unroll
    for (int rr = 0; rr < 4; ++rr) {
      float e = __expf(acc[q][rr] - mx[rr]);
      acc[q][rr] = e;
      sm[rr] += e;
    }
#pragma unroll
  for (int o = 8; o; o >>= 1)
#pragma unroll
    for (int rr = 0; rr < 4; ++rr) sm[rr] += __shfl_xor(sm[rr], o);
  __syncthreads();
  if (lr == 0) {
#pragma unroll
    for (int rr = 0; rr < 4; ++rr) reds[(lg * 4 + rr) * 4 + w] = sm[rr];
  }
  __syncthreads();
  float inv[4];
#pragma unroll
  for (int rr = 0; rr < 4; ++rr) {
    int row = lg * 4 + rr;
    inv[rr] = 1.f / (reds[row * 4] + reds[row * 4 + 1] + reds[row * 4 + 2] + reds[row * 4 + 3]);
  }
#pragma unroll
  for (int rr = 0; rr < 4; ++rr) {
    int j = j0 + lg * 4 + rr;
    const float* rp = rd + (size_t)(b * MK + j) * Nn;
    __hip_bfloat16* pp = P2 + ((size_t)bh * MK + j) * Nn;
#pragma unroll
    for (int q = 0; q < 32; ++q) {
      int n = (q >> 2) * 256 + w * 64 + (q & 3) * 16 + lr;
      pp[n] = __float2bfloat16(acc[q][rr] * inv[rr] * rp[n]);
    }
  }
}

// ---------------- atten transpose: E24 bf16 [bh][i][j] -> f32 [bh][j][i] ----------------
__global__ __launch_bounds__(256)
void at_tr_kernel(const __hip_bfloat16* __restrict__ E, float* __restrict__ atten) {
  __shared__ __hip_bfloat16 t[64][72];
  const int bh = blockIdx.x;
  const int i0 = blockIdx.y * 64, j0 = blockIdx.z * 64;
  const int tid = threadIdx.x;
#pragma unroll
  for (int it = 0; it < 2; ++it) {
    int idx = tid + it * 256, r = idx >> 3, c8 = (idx & 7) * 8;
    short8 v = *reinterpret_cast<const short8*>(
        (const short*)E + ((size_t)bh * Nn + i0 + r) * MK + j0 + c8);
#pragma unroll
    for (int e = 0; e < 8; ++e)
      *reinterpret_cast<short*>(&t[r][c8 + e]) = v[e];
  }
  __syncthreads();
#pragma unroll
  for (int it = 0; it < 4; ++it) {
    int idx = tid + it * 256, jr = idx >> 4, c4 = (idx & 15) * 4;
    float4 o;
    o.x = __bfloat162float(t[c4 + 0][jr]);
    o.y = __bfloat162float(t[c4 + 1][jr]);
    o.z = __bfloat162float(t[c4 + 2][jr]);
    o.w = __bfloat162float(t[c4 + 3][jr]);
    *reinterpret_cast<float4*>(
        atten + ((size_t)bh * MK + j0 + jr) * Nn + i0 + c4) = o;
  }
}

// ---------------- rd transpose: [b][j][i] -> rdT [b][i][j] (runs once) ----------------
__global__ __launch_bounds__(256)
void rd_tr_kernel(const float* __restrict__ rd, float* __restrict__ rdT) {
  __shared__ float tb[64][65];
  const int b = blockIdx.x;
  const int i0 = blockIdx.y * 64, j0 = blockIdx.z * 64;
  const int tid = threadIdx.x;
#pragma unroll
  for (int it = 0; it < 4; ++it) {
    int idx = tid + it * 256, r = idx >> 4, c4 = (idx & 15) * 4;
    float4 v = ldf4(rd + ((size_t)(b * MK + j0 + r)) * Nn + i0 + c4);
    tb[r][c4 + 0] = v.x; tb[r][c4 + 1] = v.y; tb[r][c4 + 2] = v.z; tb[r][c4 + 3] = v.w;
  }
  __syncthreads();
#pragma unroll
  for (int it = 0; it < 4; ++it) {
    int idx = tid + it * 256, r = idx >> 4, c4 = (idx & 15) * 4;
    float4 o = make_float4(tb[c4 + 0][r], tb[c4 + 1][r], tb[c4 + 2][r], tb[c4 + 3][r]);
    *reinterpret_cast<float4*>(rdT + ((size_t)(b * Nn + i0 + r)) * MK + j0 + c4) = o;
  }
}

// ---------------- batched weight transpose: 8 matrices in one launch ----------------
struct WtArgs {
  const float* W[8];
  __hip_bfloat16* T[8];
  int K[8], N[8];
};
__global__ __launch_bounds__(256)
void wtrans_all_kernel(WtArgs a) {
  __shared__ float t[64][65];
  const int e = blockIdx.z;
  const int K = a.K[e], N = a.N[e];
  const int n0 = blockIdx.x * 64, k0 = blockIdx.y * 64;
  if (n0 >= N || k0 >= K) return;
  const float* W = a.W[e];
  __hip_bfloat16* WT = a.T[e];
  const int tid = threadIdx.x;
#pragma unroll
  for (int it = 0; it < 4; ++it) {
    int idx = tid + it * 256, r = idx >> 4, f = idx & 15;
    float4 v = ldf4(W + (size_t)(k0 + r) * N + n0 + f * 4);
    t[r][f * 4 + 0] = v.x; t[r][f * 4 + 1] = v.y;
    t[r][f * 4 + 2] = v.z; t[r][f * 4 + 3] = v.w;
  }
  __syncthreads();
#pragma unroll
  for (int it = 0; it < 4; ++it) {
    int idx = tid + it * 256, r = idx >> 4, c4 = (idx & 15) * 4;
    __hip_bfloat16* op = WT + (size_t)(n0 + r) * K + k0 + c4;
#pragma unroll
    for (int e2 = 0; e2 < 4; ++e2) op[e2] = __float2bfloat16(t[c4 + e2][r]);
  }
}

// ---------------- qkv split: hi/lo bf16 operand prep ----------------
template<bool Q_SPLIT>
__global__ __launch_bounds__(256)
void split_kernel(const float* __restrict__ qkv, __hip_bfloat16* __restrict__ qout,
                  __hip_bfloat16* __restrict__ kout, int T) {
  const int idx = blockIdx.x * 256 + threadIdx.x;
  const int token = idx >> 7, c8 = (idx & 127) * 8;
  const int b = token / T, i = token - b * T;
  const float* p = qkv + (size_t)token * QLD + c8;
  float v[8];
  float4 a = ldf4(p), c = ldf4(p + 4);
  v[0]=a.x; v[1]=a.y; v[2]=a.z; v[3]=a.w; v[4]=c.x; v[5]=c.y; v[6]=c.z; v[7]=c.w;
  if (c8 < 512) {
    int h = c8 >> 6, d = c8 & 63;
    if (Q_SPLIT) {
      __hip_bfloat16* q = qout + ((size_t)((b * 8 + h) * T + i)) * 128 + d;
#pragma unroll
      for (int e = 0; e < 8; ++e) {
        __hip_bfloat16 hi = __float2bfloat16(v[e]);
        q[e] = hi;
        q[64 + e] = __float2bfloat16(v[e] - __bfloat162float(hi));
      }
    } else {
      __hip_bfloat16* q = qout + ((size_t)((b * 8 + h) * T + i)) * 64 + d;
#pragma unroll
      for (int e = 0; e < 8; ++e) q[e] = __float2bfloat16(v[e]);
    }
  } else {
    int cc = c8 - 512, h = cc >> 6, d = cc & 63;
    if (Q_SPLIT) {
      __hip_bfloat16* k = kout + ((size_t)((b * 8 + h) * T + i)) * 64 + d;
#pragma unroll
      for (int e = 0; e < 8; ++e) k[e] = __float2bfloat16(v[e]);
    } else {
      __hip_bfloat16* k = kout + ((size_t)((b * 8 + h) * T + i)) * 128 + d;
#pragma unroll
      for (int e = 0; e < 8; ++e) {
        __hip_bfloat16 hi = __float2bfloat16(v[e]);
        k[e] = hi;
        k[64 + e] = __float2bfloat16(v[e] - __bfloat162float(hi));
      }
    }
  }
}

// ---------------- v transpose: qkv v-part -> bf16 [bh][d][token] ----------------
__global__ __launch_bounds__(256)
void vtrans_kernel(const float* __restrict__ qkv, __hip_bfloat16* __restrict__ vT, int T) {
  __shared__ float t[64][65];
  const int bh = blockIdx.x, b = bh >> 3, h = bh & 7;
  const int i0 = blockIdx.y * 64;
  const int tid = threadIdx.x;
#pragma unroll
  for (int it = 0; it < 4; ++it) {
    int idx = tid + it * 256, r = idx >> 4, f = idx & 15;
    float4 v = ldf4(qkv + (size_t)(b * T + i0 + r) * QLD + 2 * Dd + h * 64 + f * 4);
    t[r][f * 4 + 0] = v.x; t[r][f * 4 + 1] = v.y;
    t[r][f * 4 + 2] = v.z; t[r][f * 4 + 3] = v.w;
  }
  __syncthreads();
#pragma unroll
  for (int it = 0; it < 4; ++it) {
    int idx = tid + it * 256, d = idx >> 4, c4 = (idx & 15) * 4;
    __hip_bfloat16* op = vT + (size_t)(bh * 64 + d) * T + i0 + c4;
#pragma unroll
    for (int e = 0; e < 4; ++e) op[e] = __float2bfloat16(t[c4 + e][d]);
  }
}

// ------------- cls-token attention: grid B*H, block 256, bf16 out -------------
__global__ __launch_bounds__(256)
void attn_c_kernel(const float* __restrict__ cqkv, const float* __restrict__ kqkv,
                   const float* __restrict__ mask, const float* __restrict__ kmask,
                   __hip_bfloat16* __restrict__ c_pre) {
  __shared__ __align__(16) float kv_s[MK][DH];
  __shared__ __align__(16) float q_s[DH];
  __shared__ float pbuf[MK];
  __shared__ float red8[8];
  __shared__ float redpv[4][DH];
  const int tid = threadIdx.x;
  const int bh = blockIdx.x, b = bh >> 3, h = bh & 7;
  const float* vp = kqkv + ((size_t)(b * MK + tid)) * QLD + 2 * Dd + h * DH;
#pragma unroll
  for (int q4 = 0; q4 < 16; ++q4)
    *reinterpret_cast<float4*>(&kv_s[tid][q4 * 4]) = ldf4(vp + q4 * 4);
  if (tid < DH) q_s[tid] = cqkv[(size_t)b * QLD + h * DH + tid];
  __syncthreads();
  const float* kp = kqkv + ((size_t)(b * MK + tid)) * QLD + Dd + h * DH;
  float dot = 0.f;
#pragma unroll
  for (int q4 = 0; q4 < 16; ++q4) {
    float4 kv4 = ldf4(kp + q4 * 4);
    float4 qv = ldf4(&q_s[q4 * 4]);
    dot = fmaf(qv.x, kv4.x, dot);
    dot = fmaf(qv.y, kv4.y, dot);
    dot = fmaf(qv.z, kv4.z, dot);
    dot = fmaf(qv.w, kv4.w, dot);
  }
  const float dm = (mask[(size_t)b * Nn] * kmask[b * MK + tid] < 0.5f) ? NEGV : dot * SCALE;
  const float mx = blockMax256(dm, red8);
  const float e = __expf(dm - mx);
  const float s = blockSum256(e, red8);
  pbuf[tid] = e / s;
  __syncthreads();
  const int d = tid & 63, g = tid >> 6;
  float acc = 0.f;
#pragma unroll 8
  for (int jj = 0; jj < 64; ++jj)
    acc = fmaf(pbuf[g * 64 + jj], kv_s[g * 64 + jj][d], acc);
  redpv[g][d] = acc;
  __syncthreads();
  if (tid < DH)
    c_pre[(size_t)b * Dd + h * DH + tid] = __float2bfloat16(
        redpv[0][tid] + redpv[1][tid] + redpv[2][tid] + redpv[3][tid]);
}

// ------------- output writers (float32 outputs) -------------
__global__ void kreps_kernel(const float* __restrict__ kx, const float* __restrict__ kmask,
                             float* __restrict__ o) {
  const int idx = blockIdx.x * 256 + threadIdx.x;
  const int bj = idx >> 9;
  const float keep = (kmask[bj] >= 0.5f) ? 1.f : 0.f;
  o[idx] = kx[idx] * keep;
}
__global__ void cout_kernel(const float* __restrict__ c_s, float* __restrict__ o) {
  const int idx = blockIdx.x * 256 + threadIdx.x;
  o[idx] = c_s[idx];
}

static GArgs ga_base() { GArgs g = {}; return g; }

extern "C" void kernel_launch(void* const* d_in, const int* in_sizes, int n_in,
                              void* d_out, int out_size, void* d_ws, size_t ws_size,
                              hipStream_t stream) {
  (void)in_sizes; (void)n_in; (void)out_size; (void)ws_size;
  const float* x_in  = (const float*)d_in[0];
  const float* kx_in = (const float*)d_in[1];
  const float* rd    = (const float*)d_in[2];
  const float* c_in  = (const float*)d_in[3];
  const float* mask  = (const float*)d_in[4];
  const float* kmask = (const float*)d_in[5];
  const float* ln1g  = (const float*)d_in[6];
  const float* ln1b  = (const float*)d_in[7];
  const float* Wqkv  = (const float*)d_in[8];
  const float* Woutw = (const float*)d_in[9];
  const float* boutw = (const float*)d_in[10];
  const float* ln2g  = (const float*)d_in[11];
  const float* ln2b  = (const float*)d_in[12];
  const float* W1    = (const float*)d_in[13];
  const float* b1    = (const float*)d_in[14];
  const float* W2    = (const float*)d_in[15];
  const float* b2    = (const float*)d_in[16];
  float* out = (float*)d_out;

  float* ws = (float*)d_ws;
  size_t off = 0;
  auto alloc = [&](size_t n) { float* p = ws + off; off += (n + 15) & ~(size_t)15; return p; };
  float* xcat_s    = alloc((size_t)NTOK * Dd);
  float* xcat_n    = alloc((size_t)NTOK * Dd);
  float* xcat_nb_f = alloc((size_t)NTOK * Dd / 2);
  float* pre_cat_f = alloc((size_t)NTOK * Dd / 2);
  float* qkv       = alloc((size_t)NTOK * QLD);     // hosts hid after attention
  float* P1_f      = alloc((size_t)32 * Nn * MK / 2);
  float* E24_f     = alloc((size_t)32 * Nn * MK / 2);
  float* P2_f      = alloc((size_t)32 * MK * Nn / 2);
  float* tq_s_f    = alloc((size_t)32 * Nn * 128 / 2);
  float* kk_s_f    = alloc((size_t)32 * MK * 128 / 2);
  float* tk_hi_f   = alloc((size_t)32 * Nn * 64 / 2);
  float* kq_hi_f   = alloc((size_t)32 * MK * 64 / 2);
  float* tvT_f     = alloc((size_t)32 * 64 * Nn / 2);
  float* kvT_f     = alloc((size_t)32 * 64 * MK / 2);
  float* rdT       = alloc((size_t)Bb * Nn * MK);
  float* WqkvT_f   = alloc((size_t)2 * QLD * Dd / 2);
  float* WoutT_f   = alloc((size_t)2 * Dd * Dd / 2);
  float* W1T_f     = alloc((size_t)2 * MLPD * Dd / 2);
  float* W2T_f     = alloc((size_t)2 * Dd * MLPD / 2);

  __hip_bfloat16* xcat_nb = (__hip_bfloat16*)xcat_nb_f;
  __hip_bfloat16* pre_cat = (__hip_bfloat16*)pre_cat_f;
  __hip_bfloat16* P1b     = (__hip_bfloat16*)P1_f;
  __hip_bfloat16* E24b    = (__hip_bfloat16*)E24_f;
  __hip_bfloat16* P2b     = (__hip_bfloat16*)P2_f;
  __hip_bfloat16* tq_s    = (__hip_bfloat16*)tq_s_f;
  __hip_bfloat16* kk_s    = (__hip_bfloat16*)kk_s_f;
  __hip_bfloat16* tk_hi   = (__hip_bfloat16*)tk_hi_f;
  __hip_bfloat16* kq_hi   = (__hip_bfloat16*)kq_hi_f;
  __hip_bfloat16* tvT     = (__hip_bfloat16*)tvT_f;
  __hip_bfloat16* kvT     = (__hip_bfloat16*)kvT_f;
  __hip_bfloat16* WqkvT   = (__hip_bfloat16*)WqkvT_f;
  __hip_bfloat16* WoutT   = (__hip_bfloat16*)WoutT_f;
  __hip_bfloat16* W1T     = (__hip_bfloat16*)W1T_f;
  __hip_bfloat16* W2T     = (__hip_bfloat16*)W2T_f;
  __hip_bfloat16* hid     = (__hip_bfloat16*)qkv;   // FF hidden overlay

  const size_t CL_OFF = (size_t)2 * Bb * MK * Dd;
  const size_t AT_OFF = CL_OFF + (size_t)Bb * Dd;

  // ---- upfront: input concat, rd transpose, all weight transposes ----
  copy3_kernel<<<(NTOK * 128) / 256, 256, 0, stream>>>(x_in, kx_in, c_in, xcat_s);
  rd_tr_kernel<<<dim3(Bb, Nn / 64, MK / 64), 256, 0, stream>>>(rd, rdT);
  {
    WtArgs a;
    for (int l = 0; l < 2; ++l) {
      a.W[l * 4 + 0] = Wqkv + (size_t)l * Dd * QLD;  a.T[l * 4 + 0] = WqkvT + (size_t)l * QLD * Dd;
      a.K[l * 4 + 0] = Dd;   a.N[l * 4 + 0] = QLD;
      a.W[l * 4 + 1] = Woutw + (size_t)l * Dd * Dd;  a.T[l * 4 + 1] = WoutT + (size_t)l * Dd * Dd;
      a.K[l * 4 + 1] = Dd;   a.N[l * 4 + 1] = Dd;
      a.W[l * 4 + 2] = W1 + (size_t)l * Dd * MLPD;   a.T[l * 4 + 2] = W1T + (size_t)l * MLPD * Dd;
      a.K[l * 4 + 2] = Dd;   a.N[l * 4 + 2] = MLPD;
      a.W[l * 4 + 3] = W2 + (size_t)l * MLPD * Dd;   a.T[l * 4 + 3] = W2T + (size_t)l * Dd * MLPD;
      a.K[l * 4 + 3] = MLPD; a.N[l * 4 + 3] = Dd;
    }
    wtrans_all_kernel<<<dim3(32, 32, 8), 256, 0, stream>>>(a);
  }

  for (int l = 0; l < 2; ++l) {
    const float* bo  = boutw + (size_t)l * Dd;
    const float* b1l = b1 + (size_t)l * MLPD;
    const float* b2l = b2 + (size_t)l * Dd;
    __hip_bfloat16* WqkvTl = WqkvT + (size_t)l * QLD * Dd;
    __hip_bfloat16* WoutTl = WoutT + (size_t)l * Dd * Dd;
    __hip_bfloat16* W1Tl   = W1T + (size_t)l * MLPD * Dd;
    __hip_bfloat16* W2Tl   = W2T + (size_t)l * Dd * MLPD;

    ln_kernel<<<NTOK, 64, 0, stream>>>(xcat_s, ln1g + l * Dd, ln1b + l * Dd, xcat_n, xcat_nb);

    // QKV: one GEMM over all 9220 rows
    {
      GArgs g = ga_base();
      g.A = (const short*)xcat_nb; g.lda = Dd;
      g.Bt = (const short*)WqkvTl; g.ldb = Dd;
      g.C = qkv; g.ldc = QLD;
      g.M = NTOK; g.N = QLD; g.K = Dd;
      launch_mgemm<128, 128, 0>(g, 1, stream);
    }

    split_kernel<true><<<(Bb * Nn * 128) / 256, 256, 0, stream>>>(qkv, tq_s, tk_hi, Nn);
    split_kernel<false><<<(Bb * MK * 128) / 256, 256, 0, stream>>>(
        qkv + (size_t)KXOFF * QLD, kq_hi, kk_s, MK);
    vtrans_kernel<<<dim3(32, Nn / 64), 256, 0, stream>>>(qkv, tvT, Nn);
    vtrans_kernel<<<dim3(32, MK / 64), 256, 0, stream>>>(qkv + (size_t)KXOFF * QLD, kvT, MK);

    attn_c_kernel<<<Bb * Hh, 256, 0, stream>>>(qkv + (size_t)CLOFF * QLD,
                                               qkv + (size_t)KXOFF * QLD, mask, kmask,
                                               pre_cat + (size_t)CLOFF * Dd);

    // ---- x-path: fused score+softmax -> atten transpose -> PV ----
    score_sx_kernel<<<dim3(Nn / 128, 32), 256, 0, stream>>>(
        (const short*)tq_s, (const short*)kk_s, mask, kmask, rdT, P1b, E24b);
    at_tr_kernel<<<dim3(32, Nn / 64, MK / 64), 256, 0, stream>>>(
        E24b, out + AT_OFF + (size_t)l * 32 * MK * Nn);
    {
      GArgs g = ga_base();
      g.A = (const short*)P1b; g.asb = (long)Nn * MK; g.lda = MK;
      g.Bt = (const short*)kvT; g.bsb = (long)64 * MK; g.ldb = MK;
      g.Cb = pre_cat; g.czo = (long)Nn * Dd; g.czi = 64; g.ldc = Dd;
      g.M = Nn; g.N = 64; g.K = MK;
      launch_mgemm<128, 64, 4>(g, 32, stream);
    }
    // ---- k-path: fused score+softmax -> PV ----
    score_sk_kernel<<<dim3(32, MK / 16), 256, 0, stream>>>(
        (const short*)kq_hi, (const short*)tk_hi, mask, kmask, rd, P2b);
    {
      GArgs g = ga_base();
      g.A = (const short*)P2b; g.asb = (long)MK * Nn; g.lda = Nn;
      g.Bt = (const short*)tvT; g.bsb = (long)64 * Nn; g.ldb = Nn;
      g.Cb = pre_cat + (size_t)KXOFF * Dd; g.czo = (long)MK * Dd; g.czi = 64; g.ldc = Dd;
      g.M = MK; g.N = 64; g.K = Nn;
      launch_mgemm<64, 64, 4>(g, 32, stream);
    }

    // ---- Wout + residual over all rows ----
    {
      GArgs g = ga_base();
      g.A = (const short*)pre_cat; g.lda = Dd;
      g.Bt = (const short*)WoutTl; g.ldb = Dd;
      g.C = xcat_s; g.ldc = Dd; g.bias = bo; g.res = xcat_n; g.ldr = Dd;
      g.M = NTOK; g.N = Dd; g.K = Dd;
      launch_mgemm<128, 64, 2>(g, 1, stream);
    }

    // ---- FF over all rows ----
    ln_kernel<<<NTOK, 64, 0, stream>>>(xcat_s, ln2g + l * Dd, ln2b + l * Dd, xcat_n, xcat_nb);
    {
      GArgs g = ga_base();
      g.A = (const short*)xcat_nb; g.lda = Dd;
      g.Bt = (const short*)W1Tl; g.ldb = Dd;
      g.Cb = hid; g.ldc = MLPD; g.bias = b1l;
      g.M = NTOK; g.N = MLPD; g.K = Dd;
      launch_mgemm<128, 128, 3>(g, 1, stream);
      GArgs h = ga_base();
      h.A = (const short*)hid; h.lda = MLPD;
      h.Bt = (const short*)W2Tl; h.ldb = MLPD;
      h.C = xcat_s; h.ldc = Dd; h.bias = b2l; h.res = xcat_s; h.ldr = Dd;
      h.M = NTOK; h.N = Dd; h.K = MLPD;
      launch_mgemm<128, 64, 2>(h, 1, stream);
    }

    kreps_kernel<<<(Bb * MK * Dd) / 256, 256, 0, stream>>>(
        xcat_s + (size_t)KXOFF * Dd, kmask, out + (size_t)l * Bb * MK * Dd);
  }
  cout_kernel<<<(Bb * Dd) / 256, 256, 0, stream>>>(xcat_s + (size_t)CLOFF * Dd, out + CL_OFF);
}

// Round 11
// 808.375 us; speedup vs baseline: 1.2852x; 1.1453x over previous
//
#include <hip/hip_runtime.h>
#include <hip/hip_bf16.h>
#include <cstddef>

#define DEV __device__ __forceinline__

constexpr int Bb  = 4;
constexpr int Nn  = 2048;
constexpr int MK  = 256;
constexpr int Dd  = 512;
constexpr int Hh  = 8;
constexpr int DH  = 64;
constexpr int QLD = 1536;   // qkv row stride (3*512)
constexpr int MLPD = 2048;
constexpr int NTOK = Bb * Nn + Bb * MK + Bb;   // 9220 concatenated rows
constexpr int KXOFF = Bb * Nn;                 // 8192: first kx row
constexpr int CLOFF = Bb * Nn + Bb * MK;       // 9216: first cls row
constexpr float SCALE = 0.125f;   // 64^-0.5
constexpr float NEGV  = -1e9f;

typedef __attribute__((ext_vector_type(8))) short short8;
typedef __attribute__((ext_vector_type(4))) float f32x4;

DEV float4 ldf4(const float* p) { return *reinterpret_cast<const float4*>(p); }

// async global->LDS, 16B per lane, linear LDS dest
DEV void gload16(const short* g, short* l) {
  __builtin_amdgcn_global_load_lds(
      (const __attribute__((address_space(1))) void*)g,
      (__attribute__((address_space(3))) void*)l, 16, 0, 0);
}
DEV void drain_vm() { asm volatile("s_waitcnt vmcnt(0)" ::: "memory"); }
DEV void sbar() { __builtin_amdgcn_s_barrier(); }
DEV void schedbar() { __builtin_amdgcn_sched_barrier(0); }

DEV float waveMax(float v) {
#pragma unroll
  for (int o = 32; o; o >>= 1) v = fmaxf(v, __shfl_xor(v, o));
  return v;
}
DEV float waveSum(float v) {
#pragma unroll
  for (int o = 32; o; o >>= 1) v += __shfl_xor(v, o);
  return v;
}
DEV float blockMax256(float v, float* red) {
  v = waveMax(v);
  __syncthreads();
  if ((threadIdx.x & 63) == 0) red[threadIdx.x >> 6] = v;
  __syncthreads();
  return fmaxf(fmaxf(red[0], red[1]), fmaxf(red[2], red[3]));
}
DEV float blockSum256(float v, float* red) {
  v = waveSum(v);
  __syncthreads();
  if ((threadIdx.x & 63) == 0) red[threadIdx.x >> 6] = v;
  __syncthreads();
  return red[0] + red[1] + red[2] + red[3];
}
DEV float gelu_f(float x) { return 0.5f * x * (1.f + erff(x * 0.70710678118654752f)); }
// exact: e1^24 (5 multiplies)
DEV float pow24(float e1) {
  float e2 = e1 * e1, e4 = e2 * e2, e8 = e4 * e4, e16 = e8 * e8;
  return e16 * e8;
}

// ---------------- input concat copy: {x, kx, cls} -> xcat_s ----------------
__global__ __launch_bounds__(256)
void copy3_kernel(const float* __restrict__ x, const float* __restrict__ kx,
                  const float* __restrict__ c, float* __restrict__ dst) {
  const int idx = blockIdx.x * 256 + threadIdx.x;   // float4 index
  const int row = idx >> 7;
  float4 v;
  if (row < KXOFF) v = ldf4(x + (size_t)idx * 4);
  else if (row < CLOFF) v = ldf4(kx + (size_t)idx * 4 - (size_t)KXOFF * Dd);
  else v = ldf4(c + (size_t)idx * 4 - (size_t)CLOFF * Dd);
  *reinterpret_cast<float4*>(dst + (size_t)idx * 4) = v;
}

// ---------------- LayerNorm: one wave per 512-float row, dual f32+bf16 out ----------------
__global__ __launch_bounds__(64)
void ln_kernel(const float* __restrict__ in, const float* __restrict__ gw,
               const float* __restrict__ bw, float* __restrict__ out,
               __hip_bfloat16* __restrict__ outb) {
  const int row = blockIdx.x;
  const int t = threadIdx.x;
  const float* p = in + (size_t)row * Dd + t * 8;
  float4 v0 = ldf4(p), v1 = ldf4(p + 4);
  float s = v0.x + v0.y + v0.z + v0.w + v1.x + v1.y + v1.z + v1.w;
  float q = v0.x*v0.x + v0.y*v0.y + v0.z*v0.z + v0.w*v0.w
          + v1.x*v1.x + v1.y*v1.y + v1.z*v1.z + v1.w*v1.w;
  s = waveSum(s); q = waveSum(q);
  const float mu = s * (1.f / Dd);
  const float rstd = rsqrtf(fmaxf(q * (1.f / Dd) - mu * mu, 0.f) + 1e-5f);
  float4 g0 = ldf4(gw + t * 8), g1 = ldf4(gw + t * 8 + 4);
  float4 b0 = ldf4(bw + t * 8), b1 = ldf4(bw + t * 8 + 4);
  float o[8];
  o[0] = (v0.x - mu) * rstd * g0.x + b0.x;
  o[1] = (v0.y - mu) * rstd * g0.y + b0.y;
  o[2] = (v0.z - mu) * rstd * g0.z + b0.z;
  o[3] = (v0.w - mu) * rstd * g0.w + b0.w;
  o[4] = (v1.x - mu) * rstd * g1.x + b1.x;
  o[5] = (v1.y - mu) * rstd * g1.y + b1.y;
  o[6] = (v1.z - mu) * rstd * g1.z + b1.z;
  o[7] = (v1.w - mu) * rstd * g1.w + b1.w;
  float* op = out + (size_t)row * Dd + t * 8;
  *reinterpret_cast<float4*>(op)     = make_float4(o[0], o[1], o[2], o[3]);
  *reinterpret_cast<float4*>(op + 4) = make_float4(o[4], o[5], o[6], o[7]);
  __hip_bfloat16* ob = outb + (size_t)row * Dd + t * 8;
#pragma unroll
  for (int e = 0; e < 8; ++e) ob[e] = __float2bfloat16(o[e]);
}

// ---------------- bf16 MFMA GEMM (pipelined, source-pre-swizzled) ----------------
// EPI: 0 = f32 write; 2 = +bias +res f32; 3 = +bias, gelu, bf16; 4 = bf16.
struct GArgs {
  const short* A;  long asb; int lda;
  const short* Bt; long bsb; int ldb;
  float* C; __hip_bfloat16* Cb;
  long czo, czi; int ldc;
  const float* bias;
  const float* res; int ldr;
  int M, N, K;
};

template<int BM, int BN, int EPI>
__global__ __launch_bounds__(256)
void mgemm(GArgs g) {
  constexpr int WMW = (BN >= 128) ? 2 : 4;
  constexpr int WNW = 4 / WMW;
  constexpr int WM = BM / WMW, WN = BN / WNW;
  constexpr int FM = WM / 16, FN = WN / 16;
  __shared__ __align__(16) short As[2][BM * 64];
  __shared__ __align__(16) short Bs[2][BN * 64];
  const int tid = threadIdx.x, l = tid & 63, w = tid >> 6;
  const int wm = (WNW == 2) ? (w >> 1) : w;
  const int wn = (WNW == 2) ? (w & 1) : 0;
  int bx = blockIdx.x, by = blockIdx.y;
  {  // bijective XCD swizzle (m204)
    const int gx = gridDim.x, nwg = gx * gridDim.y;
    const int orig = by * gx + bx;
    const int xcd = orig & 7, pos = orig >> 3;
    const int q = nwg >> 3, rmd = nwg & 7;
    const int s = (xcd < rmd ? xcd * (q + 1) : rmd * (q + 1) + (xcd - rmd) * q) + pos;
    bx = s % gx; by = s / gx;
  }
  const int z = blockIdx.z;
  const short* Ab = g.A + (size_t)z * g.asb;
  const short* Bb_ = g.Bt + (size_t)z * g.bsb;
  f32x4 acc[FM][FN] = {};
  const int lr = l & 15, lg = l >> 4;

  auto stage = [&](int k0, int buf) {
#pragma unroll
    for (int it = 0; it < BM / 32; ++it) {
      int idx = tid + it * 256, r = idx >> 3, c = idx & 7;
      int gm = by * BM + r;
      if (gm >= g.M) gm = g.M - 1;
      gload16(Ab + (size_t)gm * g.lda + k0 + ((c ^ (r & 7)) * 8), &As[buf][idx * 8]);
    }
#pragma unroll
    for (int it = 0; it < BN / 32; ++it) {
      int idx = tid + it * 256, r = idx >> 3, c = idx & 7;
      int gn = bx * BN + r;
      gload16(Bb_ + (size_t)gn * g.ldb + k0 + ((c ^ (r & 7)) * 8), &Bs[buf][idx * 8]);
    }
  };

  const int NT = g.K >> 6;
  stage(0, 0);
  drain_vm();
  sbar();
  schedbar();
  int cur = 0;
  for (int t = 0; t < NT; ++t) {
    if (t + 1 < NT) stage((t + 1) << 6, cur ^ 1);   // issue BEFORE compute
    schedbar();
#pragma unroll
    for (int ks = 0; ks < 2; ++ks) {
      short8 a[FM], b[FN];
#pragma unroll
      for (int fm = 0; fm < FM; ++fm) {
        int rr = wm * WM + fm * 16 + lr;
        int ch = (ks * 4 + lg) ^ (rr & 7);
        a[fm] = *reinterpret_cast<const short8*>(&As[cur][rr * 64 + ch * 8]);
      }
#pragma unroll
      for (int fn = 0; fn < FN; ++fn) {
        int rn = wn * WN + fn * 16 + lr;
        int ch = (ks * 4 + lg) ^ (rn & 7);
        b[fn] = *reinterpret_cast<const short8*>(&Bs[cur][rn * 64 + ch * 8]);
      }
#pragma unroll
      for (int fm = 0; fm < FM; ++fm)
#pragma unroll
        for (int fn = 0; fn < FN; ++fn)
          acc[fm][fn] = __builtin_amdgcn_mfma_f32_16x16x32_bf16(a[fm], b[fn], acc[fm][fn], 0, 0, 0);
    }
    schedbar();
    drain_vm();
    schedbar();
    sbar();
    schedbar();
    cur ^= 1;
  }

  const size_t zoff = (size_t)(z >> 3) * g.czo + (size_t)(z & 7) * g.czi;
#pragma unroll
  for (int fm = 0; fm < FM; ++fm) {
#pragma unroll
    for (int fn = 0; fn < FN; ++fn) {
#pragma unroll
      for (int r = 0; r < 4; ++r) {
        int m = by * BM + wm * WM + fm * 16 + lg * 4 + r;
        int n = bx * BN + wn * WN + fn * 16 + lr;
        if (m >= g.M) continue;
        float v = acc[fm][fn][r];
        size_t coff = zoff + (size_t)m * g.ldc + n;
        if (EPI == 0) {
          g.C[coff] = v;
        } else if (EPI == 2) {
          v += g.bias[n] + g.res[(size_t)m * g.ldr + n];
          g.C[coff] = v;
        } else if (EPI == 3) {
          v = gelu_f(v + g.bias[n]);
          g.Cb[coff] = __float2bfloat16(v);
        } else {
          g.Cb[coff] = __float2bfloat16(v);
        }
      }
    }
  }
}

template<int BM, int BN, int EPI>
static void launch_mgemm(const GArgs& g, int zdim, hipStream_t s) {
  dim3 grid((g.N + BN - 1) / BN, (g.M + BM - 1) / BM, zdim);
  mgemm<BM, BN, EPI><<<grid, 256, 0, s>>>(g);
}

// ---------------- fused x-path score GEMM + dual softmax (512 threads) ----------------
// grid (Nn/128, 32). BM=128, BN=256 (full j-row). 8 waves: wm=w>>1 (32-row
// groups), wn=w&1 (128-col halves). Single exp per element; e24 = e1^24.
__global__ __launch_bounds__(512)
void score_sx_kernel(const short* __restrict__ Q, const short* __restrict__ Km,
                     const float* __restrict__ mask, const float* __restrict__ kmask,
                     const float* __restrict__ rdT,
                     __hip_bfloat16* __restrict__ P1, __hip_bfloat16* __restrict__ E24) {
  __shared__ __align__(16) short As[128 * 64];
  __shared__ __align__(16) short Bs[256 * 64];
  __shared__ float red[128 * 2];
  __shared__ float red2[128 * 4];
  const int tid = threadIdx.x, l = tid & 63, w = tid >> 6;
  const int wm = w >> 1, wn = w & 1;
  const int by = blockIdx.x, bh = blockIdx.y;
  const int b = bh >> 3;
  const short* Ab = Q + (size_t)bh * Nn * 128;
  const short* Bb = Km + (size_t)bh * MK * 128;
  const int lr = l & 15, lg = l >> 4;
  f32x4 acc[2][8] = {};

  for (int k0 = 0; k0 < 128; k0 += 64) {
    __syncthreads();
#pragma unroll
    for (int it = 0; it < 2; ++it) {
      int idx = tid + it * 512, r = idx >> 3, c = idx & 7;
      gload16(Ab + (size_t)(by * 128 + r) * 128 + k0 + ((c ^ (r & 7)) * 8), As + idx * 8);
    }
#pragma unroll
    for (int it = 0; it < 4; ++it) {
      int idx = tid + it * 512, r = idx >> 3, c = idx & 7;
      gload16(Bb + (size_t)r * 128 + k0 + ((c ^ (r & 7)) * 8), Bs + idx * 8);
    }
    __syncthreads();
#pragma unroll
    for (int ks = 0; ks < 2; ++ks) {
      short8 a[2], bv[8];
#pragma unroll
      for (int fm = 0; fm < 2; ++fm) {
        int rr = wm * 32 + fm * 16 + lr;
        int ch = (ks * 4 + lg) ^ (rr & 7);
        a[fm] = *reinterpret_cast<const short8*>(As + rr * 64 + ch * 8);
      }
#pragma unroll
      for (int fn = 0; fn < 8; ++fn) {
        int rn = wn * 128 + fn * 16 + lr;
        int ch = (ks * 4 + lg) ^ (rn & 7);
        bv[fn] = *reinterpret_cast<const short8*>(Bs + rn * 64 + ch * 8);
      }
#pragma unroll
      for (int fm = 0; fm < 2; ++fm)
#pragma unroll
        for (int fn = 0; fn < 8; ++fn)
          acc[fm][fn] = __builtin_amdgcn_mfma_f32_16x16x32_bf16(a[fm], bv[fn], acc[fm][fn], 0, 0, 0);
    }
  }
  // mask + scale in place
  {
    float colm[8];
#pragma unroll
    for (int fn = 0; fn < 8; ++fn)
      colm[fn] = kmask[b * MK + wn * 128 + fn * 16 + lr];
#pragma unroll
    for (int fm = 0; fm < 2; ++fm)
#pragma unroll
      for (int r = 0; r < 4; ++r) {
        float rm = mask[(size_t)b * Nn + by * 128 + wm * 32 + fm * 16 + lg * 4 + r];
#pragma unroll
        for (int fn = 0; fn < 8; ++fn)
          acc[fm][fn][r] = (rm * colm[fn] < 0.5f) ? NEGV : acc[fm][fn][r] * SCALE;
      }
  }
  // row max: local frags -> 16-lane shfl -> cross-wave (wn) via LDS
  float mx[2][4];
#pragma unroll
  for (int fm = 0; fm < 2; ++fm)
#pragma unroll
    for (int r = 0; r < 4; ++r) {
      float m = -3.4e38f;
#pragma unroll
      for (int fn = 0; fn < 8; ++fn) m = fmaxf(m, acc[fm][fn][r]);
#pragma unroll
      for (int o = 8; o; o >>= 1) m = fmaxf(m, __shfl_xor(m, o));
      mx[fm][r] = m;
    }
  __syncthreads();
  if (lr == 0) {
#pragma unroll
    for (int fm = 0; fm < 2; ++fm)
#pragma unroll
      for (int r = 0; r < 4; ++r)
        red[(wm * 32 + fm * 16 + lg * 4 + r) * 2 + wn] = mx[fm][r];
  }
  __syncthreads();
#pragma unroll
  for (int fm = 0; fm < 2; ++fm)
#pragma unroll
    for (int r = 0; r < 4; ++r) {
      int row = wm * 32 + fm * 16 + lg * 4 + r;
      mx[fm][r] = fmaxf(red[row * 2], red[row * 2 + 1]);
    }
  // single exp per element: store e1 in acc; e24 via 5 mults
  float s1[2][4], s24[2][4];
#pragma unroll
  for (int fm = 0; fm < 2; ++fm)
#pragma unroll
    for (int r = 0; r < 4; ++r) {
      float a1 = 0.f, a24 = 0.f;
#pragma unroll
      for (int fn = 0; fn < 8; ++fn) {
        float e1 = __expf(acc[fm][fn][r] - mx[fm][r]);
        acc[fm][fn][r] = e1;
        a1 += e1;
        a24 += pow24(e1);
      }
#pragma unroll
      for (int o = 8; o; o >>= 1) { a1 += __shfl_xor(a1, o); a24 += __shfl_xor(a24, o); }
      s1[fm][r] = a1; s24[fm][r] = a24;
    }
  __syncthreads();
  if (lr == 0) {
#pragma unroll
    for (int fm = 0; fm < 2; ++fm)
#pragma unroll
      for (int r = 0; r < 4; ++r) {
        int row = wm * 32 + fm * 16 + lg * 4 + r;
        red2[row * 4 + wn * 2]     = s1[fm][r];
        red2[row * 4 + wn * 2 + 1] = s24[fm][r];
      }
  }
  __syncthreads();
#pragma unroll
  for (int fm = 0; fm < 2; ++fm)
#pragma unroll
    for (int r = 0; r < 4; ++r) {
      int row = wm * 32 + fm * 16 + lg * 4 + r;
      s1[fm][r]  = 1.f / (red2[row * 4] + red2[row * 4 + 2]);
      s24[fm][r] = 1.f / (red2[row * 4 + 1] + red2[row * 4 + 3]);
    }
  // normalized writes (e1 already in acc; no exp here)
#pragma unroll
  for (int fm = 0; fm < 2; ++fm) {
#pragma unroll
    for (int r = 0; r < 4; ++r) {
      int m = by * 128 + wm * 32 + fm * 16 + lg * 4 + r;
      const float* rp = rdT + ((size_t)b * Nn + m) * MK;
      size_t obase = ((size_t)bh * Nn + m) * MK;
#pragma unroll
      for (int fn = 0; fn < 8; ++fn) {
        int n = wn * 128 + fn * 16 + lr;
        float e1 = acc[fm][fn][r];
        float rv = rp[n];
        P1[obase + n]  = __float2bfloat16(e1 * s1[fm][r] * rv);
        E24[obase + n] = __float2bfloat16(pow24(e1) * s24[fm][r] * rv);
      }
    }
  }
}

// ---------------- fused k-path score GEMM + softmax ----------------
// grid (32 bh, MK/16). Block: 16 j-rows x full 2048-i row. K=64 (hi only).
__global__ __launch_bounds__(256)
void score_sk_kernel(const short* __restrict__ Qk, const short* __restrict__ Kt,
                     const float* __restrict__ mask, const float* __restrict__ kmask,
                     const float* __restrict__ rd, __hip_bfloat16* __restrict__ P2) {
  __shared__ __align__(16) short As[16 * 64];
  __shared__ __align__(16) short Bs[256 * 64];
  __shared__ float redm[16 * 4];
  __shared__ float reds[16 * 4];
  const int tid = threadIdx.x, l = tid & 63, w = tid >> 6;
  const int lr = l & 15, lg = l >> 4;
  const int bh = blockIdx.x, j0 = blockIdx.y * 16, b = bh >> 3;
  const short* Ab = Qk + ((size_t)bh * MK + j0) * 64;
  const short* Bb = Kt + (size_t)bh * Nn * 64;
  f32x4 acc[32];
#pragma unroll
  for (int q = 0; q < 32; ++q) acc[q] = f32x4{0.f, 0.f, 0.f, 0.f};
  if (tid < 128) {     // stage A once: 16 rows x 64 (first two waves)
    int r = tid >> 3, c = tid & 7;
    gload16(Ab + (size_t)r * 64 + ((c ^ (r & 7)) * 8), As + tid * 8);
  }
#pragma unroll
  for (int nc = 0; nc < 8; ++nc) {
    __syncthreads();
#pragma unroll
    for (int it = 0; it < 8; ++it) {
      int idx = tid + it * 256, r = idx >> 3, c = idx & 7;
      gload16(Bb + (size_t)(nc * 256 + r) * 64 + ((c ^ (r & 7)) * 8), Bs + idx * 8);
    }
    __syncthreads();
#pragma unroll
    for (int ks = 0; ks < 2; ++ks) {
      short8 a;
      {
        int ch = (ks * 4 + lg) ^ (lr & 7);
        a = *reinterpret_cast<const short8*>(As + lr * 64 + ch * 8);
      }
#pragma unroll
      for (int fn = 0; fn < 4; ++fn) {
        int rn = w * 64 + fn * 16 + lr;
        int ch = (ks * 4 + lg) ^ (rn & 7);
        short8 bv = *reinterpret_cast<const short8*>(Bs + rn * 64 + ch * 8);
        acc[nc * 4 + fn] =
            __builtin_amdgcn_mfma_f32_16x16x32_bf16(a, bv, acc[nc * 4 + fn], 0, 0, 0);
      }
    }
  }
  float rm[4];
#pragma unroll
  for (int rr = 0; rr < 4; ++rr) rm[rr] = kmask[b * MK + j0 + lg * 4 + rr];
  float mx[4] = {-3.4e38f, -3.4e38f, -3.4e38f, -3.4e38f};
#pragma unroll
  for (int q = 0; q < 32; ++q) {
    int n = (q >> 2) * 256 + w * 64 + (q & 3) * 16 + lr;
    float cm = mask[(size_t)b * Nn + n];
#pragma unroll
    for (int rr = 0; rr < 4; ++rr) {
      float v = (rm[rr] * cm < 0.5f) ? NEGV : acc[q][rr] * SCALE;
      acc[q][rr] = v;
      mx[rr] = fmaxf(mx[rr], v);
    }
  }
#pragma unroll
  for (int o = 8; o; o >>= 1)
#pragma unroll
    for (int rr = 0; rr < 4; ++rr) mx[rr] = fmaxf(mx[rr], __shfl_xor(mx[rr], o));
  __syncthreads();
  if (lr == 0) {
#pragma unroll
    for (int rr = 0; rr < 4; ++rr) redm[(lg * 4 + rr) * 4 + w] = mx[rr];
  }
  __syncthreads();
#pragma unroll
  for (int rr = 0; rr < 4; ++rr) {
    int row = lg * 4 + rr;
    mx[rr] = fmaxf(fmaxf(redm[row * 4], redm[row * 4 + 1]),
                   fmaxf(redm[row * 4 + 2], redm[row * 4 + 3]));
  }
  float sm[4] = {0.f, 0.f, 0.f, 0.f};
#pragma unroll
  for (int q = 0; q < 32; ++q)
#pragma unroll
    for (int rr = 0; rr < 4; ++rr) {
      float e = __expf(acc[q][rr] - mx[rr]);
      acc[q][rr] = e;
      sm[rr] += e;
    }
#pragma unroll
  for (int o = 8; o; o >>= 1)
#pragma unroll
    for (int rr = 0; rr < 4; ++rr) sm[rr] += __shfl_xor(sm[rr], o);
  __syncthreads();
  if (lr == 0) {
#pragma unroll
    for (int rr = 0; rr < 4; ++rr) reds[(lg * 4 + rr) * 4 + w] = sm[rr];
  }
  __syncthreads();
  float inv[4];
#pragma unroll
  for (int rr = 0; rr < 4; ++rr) {
    int row = lg * 4 + rr;
    inv[rr] = 1.f / (reds[row * 4] + reds[row * 4 + 1] + reds[row * 4 + 2] + reds[row * 4 + 3]);
  }
#pragma unroll
  for (int rr = 0; rr < 4; ++rr) {
    int j = j0 + lg * 4 + rr;
    const float* rp = rd + (size_t)(b * MK + j) * Nn;
    __hip_bfloat16* pp = P2 + ((size_t)bh * MK + j) * Nn;
#pragma unroll
    for (int q = 0; q < 32; ++q) {
      int n = (q >> 2) * 256 + w * 64 + (q & 3) * 16 + lr;
      pp[n] = __float2bfloat16(acc[q][rr] * inv[rr] * rp[n]);
    }
  }
}

// ---------------- atten transpose: E24 bf16 [bh][i][j] -> f32 [bh][j][i] ----------------
__global__ __launch_bounds__(256)
void at_tr_kernel(const __hip_bfloat16* __restrict__ E, float* __restrict__ atten) {
  __shared__ __hip_bfloat16 t[64][72];
  const int bh = blockIdx.x;
  const int i0 = blockIdx.y * 64, j0 = blockIdx.z * 64;
  const int tid = threadIdx.x;
#pragma unroll
  for (int it = 0; it < 2; ++it) {
    int idx = tid + it * 256, r = idx >> 3, c8 = (idx & 7) * 8;
    short8 v = *reinterpret_cast<const short8*>(
        (const short*)E + ((size_t)bh * Nn + i0 + r) * MK + j0 + c8);
#pragma unroll
    for (int e = 0; e < 8; ++e)
      *reinterpret_cast<short*>(&t[r][c8 + e]) = v[e];
  }
  __syncthreads();
#pragma unroll
  for (int it = 0; it < 4; ++it) {
    int idx = tid + it * 256, jr = idx >> 4, c4 = (idx & 15) * 4;
    float4 o;
    o.x = __bfloat162float(t[c4 + 0][jr]);
    o.y = __bfloat162float(t[c4 + 1][jr]);
    o.z = __bfloat162float(t[c4 + 2][jr]);
    o.w = __bfloat162float(t[c4 + 3][jr]);
    *reinterpret_cast<float4*>(
        atten + ((size_t)bh * MK + j0 + jr) * Nn + i0 + c4) = o;
  }
}

// ---------------- rd transpose: [b][j][i] -> rdT [b][i][j] (runs once) ----------------
__global__ __launch_bounds__(256)
void rd_tr_kernel(const float* __restrict__ rd, float* __restrict__ rdT) {
  __shared__ float tb[64][65];
  const int b = blockIdx.x;
  const int i0 = blockIdx.y * 64, j0 = blockIdx.z * 64;
  const int tid = threadIdx.x;
#pragma unroll
  for (int it = 0; it < 4; ++it) {
    int idx = tid + it * 256, r = idx >> 4, c4 = (idx & 15) * 4;
    float4 v = ldf4(rd + ((size_t)(b * MK + j0 + r)) * Nn + i0 + c4);
    tb[r][c4 + 0] = v.x; tb[r][c4 + 1] = v.y; tb[r][c4 + 2] = v.z; tb[r][c4 + 3] = v.w;
  }
  __syncthreads();
#pragma unroll
  for (int it = 0; it < 4; ++it) {
    int idx = tid + it * 256, r = idx >> 4, c4 = (idx & 15) * 4;
    float4 o = make_float4(tb[c4 + 0][r], tb[c4 + 1][r], tb[c4 + 2][r], tb[c4 + 3][r]);
    *reinterpret_cast<float4*>(rdT + ((size_t)(b * Nn + i0 + r)) * MK + j0 + c4) = o;
  }
}

// ---------------- batched weight transpose: 8 matrices in one launch ----------------
struct WtArgs {
  const float* W[8];
  __hip_bfloat16* T[8];
  int K[8], N[8];
};
__global__ __launch_bounds__(256)
void wtrans_all_kernel(WtArgs a) {
  __shared__ float t[64][65];
  const int e = blockIdx.z;
  const int K = a.K[e], N = a.N[e];
  const int n0 = blockIdx.x * 64, k0 = blockIdx.y * 64;
  if (n0 >= N || k0 >= K) return;
  const float* W = a.W[e];
  __hip_bfloat16* WT = a.T[e];
  const int tid = threadIdx.x;
#pragma unroll
  for (int it = 0; it < 4; ++it) {
    int idx = tid + it * 256, r = idx >> 4, f = idx & 15;
    float4 v = ldf4(W + (size_t)(k0 + r) * N + n0 + f * 4);
    t[r][f * 4 + 0] = v.x; t[r][f * 4 + 1] = v.y;
    t[r][f * 4 + 2] = v.z; t[r][f * 4 + 3] = v.w;
  }
  __syncthreads();
#pragma unroll
  for (int it = 0; it < 4; ++it) {
    int idx = tid + it * 256, r = idx >> 4, c4 = (idx & 15) * 4;
    __hip_bfloat16* op = WT + (size_t)(n0 + r) * K + k0 + c4;
#pragma unroll
    for (int e2 = 0; e2 < 4; ++e2) op[e2] = __float2bfloat16(t[c4 + e2][r]);
  }
}

// ---------------- qkv split: hi/lo bf16 operand prep ----------------
template<bool Q_SPLIT>
__global__ __launch_bounds__(256)
void split_kernel(const float* __restrict__ qkv, __hip_bfloat16* __restrict__ qout,
                  __hip_bfloat16* __restrict__ kout, int T) {
  const int idx = blockIdx.x * 256 + threadIdx.x;
  const int token = idx >> 7, c8 = (idx & 127) * 8;
  const int b = token / T, i = token - b * T;
  const float* p = qkv + (size_t)token * QLD + c8;
  float v[8];
  float4 a = ldf4(p), c = ldf4(p + 4);
  v[0]=a.x; v[1]=a.y; v[2]=a.z; v[3]=a.w; v[4]=c.x; v[5]=c.y; v[6]=c.z; v[7]=c.w;
  if (c8 < 512) {
    int h = c8 >> 6, d = c8 & 63;
    if (Q_SPLIT) {
      __hip_bfloat16* q = qout + ((size_t)((b * 8 + h) * T + i)) * 128 + d;
#pragma unroll
      for (int e = 0; e < 8; ++e) {
        __hip_bfloat16 hi = __float2bfloat16(v[e]);
        q[e] = hi;
        q[64 + e] = __float2bfloat16(v[e] - __bfloat162float(hi));
      }
    } else {
      __hip_bfloat16* q = qout + ((size_t)((b * 8 + h) * T + i)) * 64 + d;
#pragma unroll
      for (int e = 0; e < 8; ++e) q[e] = __float2bfloat16(v[e]);
    }
  } else {
    int cc = c8 - 512, h = cc >> 6, d = cc & 63;
    if (Q_SPLIT) {
      __hip_bfloat16* k = kout + ((size_t)((b * 8 + h) * T + i)) * 64 + d;
#pragma unroll
      for (int e = 0; e < 8; ++e) k[e] = __float2bfloat16(v[e]);
    } else {
      __hip_bfloat16* k = kout + ((size_t)((b * 8 + h) * T + i)) * 128 + d;
#pragma unroll
      for (int e = 0; e < 8; ++e) {
        __hip_bfloat16 hi = __float2bfloat16(v[e]);
        k[e] = hi;
        k[64 + e] = __float2bfloat16(v[e] - __bfloat162float(hi));
      }
    }
  }
}

// ---------------- v transpose: qkv v-part -> bf16 [bh][d][token] ----------------
__global__ __launch_bounds__(256)
void vtrans_kernel(const float* __restrict__ qkv, __hip_bfloat16* __restrict__ vT, int T) {
  __shared__ float t[64][65];
  const int bh = blockIdx.x, b = bh >> 3, h = bh & 7;
  const int i0 = blockIdx.y * 64;
  const int tid = threadIdx.x;
#pragma unroll
  for (int it = 0; it < 4; ++it) {
    int idx = tid + it * 256, r = idx >> 4, f = idx & 15;
    float4 v = ldf4(qkv + (size_t)(b * T + i0 + r) * QLD + 2 * Dd + h * 64 + f * 4);
    t[r][f * 4 + 0] = v.x; t[r][f * 4 + 1] = v.y;
    t[r][f * 4 + 2] = v.z; t[r][f * 4 + 3] = v.w;
  }
  __syncthreads();
#pragma unroll
  for (int it = 0; it < 4; ++it) {
    int idx = tid + it * 256, d = idx >> 4, c4 = (idx & 15) * 4;
    __hip_bfloat16* op = vT + (size_t)(bh * 64 + d) * T + i0 + c4;
#pragma unroll
    for (int e = 0; e < 4; ++e) op[e] = __float2bfloat16(t[c4 + e][d]);
  }
}

// ------------- cls-token attention: grid B*H, block 256, bf16 out -------------
__global__ __launch_bounds__(256)
void attn_c_kernel(const float* __restrict__ cqkv, const float* __restrict__ kqkv,
                   const float* __restrict__ mask, const float* __restrict__ kmask,
                   __hip_bfloat16* __restrict__ c_pre) {
  __shared__ __align__(16) float kv_s[MK][DH];
  __shared__ __align__(16) float q_s[DH];
  __shared__ float pbuf[MK];
  __shared__ float red8[8];
  __shared__ float redpv[4][DH];
  const int tid = threadIdx.x;
  const int bh = blockIdx.x, b = bh >> 3, h = bh & 7;
  const float* vp = kqkv + ((size_t)(b * MK + tid)) * QLD + 2 * Dd + h * DH;
#pragma unroll
  for (int q4 = 0; q4 < 16; ++q4)
    *reinterpret_cast<float4*>(&kv_s[tid][q4 * 4]) = ldf4(vp + q4 * 4);
  if (tid < DH) q_s[tid] = cqkv[(size_t)b * QLD + h * DH + tid];
  __syncthreads();
  const float* kp = kqkv + ((size_t)(b * MK + tid)) * QLD + Dd + h * DH;
  float dot = 0.f;
#pragma unroll
  for (int q4 = 0; q4 < 16; ++q4) {
    float4 kv4 = ldf4(kp + q4 * 4);
    float4 qv = ldf4(&q_s[q4 * 4]);
    dot = fmaf(qv.x, kv4.x, dot);
    dot = fmaf(qv.y, kv4.y, dot);
    dot = fmaf(qv.z, kv4.z, dot);
    dot = fmaf(qv.w, kv4.w, dot);
  }
  const float dm = (mask[(size_t)b * Nn] * kmask[b * MK + tid] < 0.5f) ? NEGV : dot * SCALE;
  const float mx = blockMax256(dm, red8);
  const float e = __expf(dm - mx);
  const float s = blockSum256(e, red8);
  pbuf[tid] = e / s;
  __syncthreads();
  const int d = tid & 63, g = tid >> 6;
  float acc = 0.f;
#pragma unroll 8
  for (int jj = 0; jj < 64; ++jj)
    acc = fmaf(pbuf[g * 64 + jj], kv_s[g * 64 + jj][d], acc);
  redpv[g][d] = acc;
  __syncthreads();
  if (tid < DH)
    c_pre[(size_t)b * Dd + h * DH + tid] = __float2bfloat16(
        redpv[0][tid] + redpv[1][tid] + redpv[2][tid] + redpv[3][tid]);
}

// ------------- output writers (float32 outputs) -------------
__global__ void kreps_kernel(const float* __restrict__ kx, const float* __restrict__ kmask,
                             float* __restrict__ o) {
  const int idx = blockIdx.x * 256 + threadIdx.x;
  const int bj = idx >> 9;
  const float keep = (kmask[bj] >= 0.5f) ? 1.f : 0.f;
  o[idx] = kx[idx] * keep;
}
__global__ void cout_kernel(const float* __restrict__ c_s, float* __restrict__ o) {
  const int idx = blockIdx.x * 256 + threadIdx.x;
  o[idx] = c_s[idx];
}

static GArgs ga_base() { GArgs g = {}; return g; }

extern "C" void kernel_launch(void* const* d_in, const int* in_sizes, int n_in,
                              void* d_out, int out_size, void* d_ws, size_t ws_size,
                              hipStream_t stream) {
  (void)in_sizes; (void)n_in; (void)out_size; (void)ws_size;
  const float* x_in  = (const float*)d_in[0];
  const float* kx_in = (const float*)d_in[1];
  const float* rd    = (const float*)d_in[2];
  const float* c_in  = (const float*)d_in[3];
  const float* mask  = (const float*)d_in[4];
  const float* kmask = (const float*)d_in[5];
  const float* ln1g  = (const float*)d_in[6];
  const float* ln1b  = (const float*)d_in[7];
  const float* Wqkv  = (const float*)d_in[8];
  const float* Woutw = (const float*)d_in[9];
  const float* boutw = (const float*)d_in[10];
  const float* ln2g  = (const float*)d_in[11];
  const float* ln2b  = (const float*)d_in[12];
  const float* W1    = (const float*)d_in[13];
  const float* b1    = (const float*)d_in[14];
  const float* W2    = (const float*)d_in[15];
  const float* b2    = (const float*)d_in[16];
  float* out = (float*)d_out;

  float* ws = (float*)d_ws;
  size_t off = 0;
  auto alloc = [&](size_t n) { float* p = ws + off; off += (n + 15) & ~(size_t)15; return p; };
  float* xcat_s    = alloc((size_t)NTOK * Dd);
  float* xcat_n    = alloc((size_t)NTOK * Dd);
  float* xcat_nb_f = alloc((size_t)NTOK * Dd / 2);
  float* pre_cat_f = alloc((size_t)NTOK * Dd / 2);
  float* qkv       = alloc((size_t)NTOK * QLD);     // hosts hid after attention
  float* P1_f      = alloc((size_t)32 * Nn * MK / 2);
  float* E24_f     = alloc((size_t)32 * Nn * MK / 2);
  float* P2_f      = alloc((size_t)32 * MK * Nn / 2);
  float* tq_s_f    = alloc((size_t)32 * Nn * 128 / 2);
  float* kk_s_f    = alloc((size_t)32 * MK * 128 / 2);
  float* tk_hi_f   = alloc((size_t)32 * Nn * 64 / 2);
  float* kq_hi_f   = alloc((size_t)32 * MK * 64 / 2);
  float* tvT_f     = alloc((size_t)32 * 64 * Nn / 2);
  float* kvT_f     = alloc((size_t)32 * 64 * MK / 2);
  float* rdT       = alloc((size_t)Bb * Nn * MK);
  float* WqkvT_f   = alloc((size_t)2 * QLD * Dd / 2);
  float* WoutT_f   = alloc((size_t)2 * Dd * Dd / 2);
  float* W1T_f     = alloc((size_t)2 * MLPD * Dd / 2);
  float* W2T_f     = alloc((size_t)2 * Dd * MLPD / 2);

  __hip_bfloat16* xcat_nb = (__hip_bfloat16*)xcat_nb_f;
  __hip_bfloat16* pre_cat = (__hip_bfloat16*)pre_cat_f;
  __hip_bfloat16* P1b     = (__hip_bfloat16*)P1_f;
  __hip_bfloat16* E24b    = (__hip_bfloat16*)E24_f;
  __hip_bfloat16* P2b     = (__hip_bfloat16*)P2_f;
  __hip_bfloat16* tq_s    = (__hip_bfloat16*)tq_s_f;
  __hip_bfloat16* kk_s    = (__hip_bfloat16*)kk_s_f;
  __hip_bfloat16* tk_hi   = (__hip_bfloat16*)tk_hi_f;
  __hip_bfloat16* kq_hi   = (__hip_bfloat16*)kq_hi_f;
  __hip_bfloat16* tvT     = (__hip_bfloat16*)tvT_f;
  __hip_bfloat16* kvT     = (__hip_bfloat16*)kvT_f;
  __hip_bfloat16* WqkvT   = (__hip_bfloat16*)WqkvT_f;
  __hip_bfloat16* WoutT   = (__hip_bfloat16*)WoutT_f;
  __hip_bfloat16* W1T     = (__hip_bfloat16*)W1T_f;
  __hip_bfloat16* W2T     = (__hip_bfloat16*)W2T_f;
  __hip_bfloat16* hid     = (__hip_bfloat16*)qkv;   // FF hidden overlay

  const size_t CL_OFF = (size_t)2 * Bb * MK * Dd;
  const size_t AT_OFF = CL_OFF + (size_t)Bb * Dd;

  // ---- upfront: input concat, rd transpose, all weight transposes ----
  copy3_kernel<<<(NTOK * 128) / 256, 256, 0, stream>>>(x_in, kx_in, c_in, xcat_s);
  rd_tr_kernel<<<dim3(Bb, Nn / 64, MK / 64), 256, 0, stream>>>(rd, rdT);
  {
    WtArgs a;
    for (int l = 0; l < 2; ++l) {
      a.W[l * 4 + 0] = Wqkv + (size_t)l * Dd * QLD;  a.T[l * 4 + 0] = WqkvT + (size_t)l * QLD * Dd;
      a.K[l * 4 + 0] = Dd;   a.N[l * 4 + 0] = QLD;
      a.W[l * 4 + 1] = Woutw + (size_t)l * Dd * Dd;  a.T[l * 4 + 1] = WoutT + (size_t)l * Dd * Dd;
      a.K[l * 4 + 1] = Dd;   a.N[l * 4 + 1] = Dd;
      a.W[l * 4 + 2] = W1 + (size_t)l * Dd * MLPD;   a.T[l * 4 + 2] = W1T + (size_t)l * MLPD * Dd;
      a.K[l * 4 + 2] = Dd;   a.N[l * 4 + 2] = MLPD;
      a.W[l * 4 + 3] = W2 + (size_t)l * MLPD * Dd;   a.T[l * 4 + 3] = W2T + (size_t)l * Dd * MLPD;
      a.K[l * 4 + 3] = MLPD; a.N[l * 4 + 3] = Dd;
    }
    wtrans_all_kernel<<<dim3(32, 32, 8), 256, 0, stream>>>(a);
  }

  for (int l = 0; l < 2; ++l) {
    const float* bo  = boutw + (size_t)l * Dd;
    const float* b1l = b1 + (size_t)l * MLPD;
    const float* b2l = b2 + (size_t)l * Dd;
    __hip_bfloat16* WqkvTl = WqkvT + (size_t)l * QLD * Dd;
    __hip_bfloat16* WoutTl = WoutT + (size_t)l * Dd * Dd;
    __hip_bfloat16* W1Tl   = W1T + (size_t)l * MLPD * Dd;
    __hip_bfloat16* W2Tl   = W2T + (size_t)l * Dd * MLPD;

    ln_kernel<<<NTOK, 64, 0, stream>>>(xcat_s, ln1g + l * Dd, ln1b + l * Dd, xcat_n, xcat_nb);

    // QKV: one GEMM over all 9220 rows
    {
      GArgs g = ga_base();
      g.A = (const short*)xcat_nb; g.lda = Dd;
      g.Bt = (const short*)WqkvTl; g.ldb = Dd;
      g.C = qkv; g.ldc = QLD;
      g.M = NTOK; g.N = QLD; g.K = Dd;
      launch_mgemm<128, 128, 0>(g, 1, stream);
    }

    split_kernel<true><<<(Bb * Nn * 128) / 256, 256, 0, stream>>>(qkv, tq_s, tk_hi, Nn);
    split_kernel<false><<<(Bb * MK * 128) / 256, 256, 0, stream>>>(
        qkv + (size_t)KXOFF * QLD, kq_hi, kk_s, MK);
    vtrans_kernel<<<dim3(32, Nn / 64), 256, 0, stream>>>(qkv, tvT, Nn);
    vtrans_kernel<<<dim3(32, MK / 64), 256, 0, stream>>>(qkv + (size_t)KXOFF * QLD, kvT, MK);

    attn_c_kernel<<<Bb * Hh, 256, 0, stream>>>(qkv + (size_t)CLOFF * QLD,
                                               qkv + (size_t)KXOFF * QLD, mask, kmask,
                                               pre_cat + (size_t)CLOFF * Dd);

    // ---- x-path: fused score+softmax -> atten transpose -> PV ----
    score_sx_kernel<<<dim3(Nn / 128, 32), 512, 0, stream>>>(
        (const short*)tq_s, (const short*)kk_s, mask, kmask, rdT, P1b, E24b);
    at_tr_kernel<<<dim3(32, Nn / 64, MK / 64), 256, 0, stream>>>(
        E24b, out + AT_OFF + (size_t)l * 32 * MK * Nn);
    {
      GArgs g = ga_base();
      g.A = (const short*)P1b; g.asb = (long)Nn * MK; g.lda = MK;
      g.Bt = (const short*)kvT; g.bsb = (long)64 * MK; g.ldb = MK;
      g.Cb = pre_cat; g.czo = (long)Nn * Dd; g.czi = 64; g.ldc = Dd;
      g.M = Nn; g.N = 64; g.K = MK;
      launch_mgemm<128, 64, 4>(g, 32, stream);
    }
    // ---- k-path: fused score+softmax -> PV ----
    score_sk_kernel<<<dim3(32, MK / 16), 256, 0, stream>>>(
        (const short*)kq_hi, (const short*)tk_hi, mask, kmask, rd, P2b);
    {
      GArgs g = ga_base();
      g.A = (const short*)P2b; g.asb = (long)MK * Nn; g.lda = Nn;
      g.Bt = (const short*)tvT; g.bsb = (long)64 * Nn; g.ldb = Nn;
      g.Cb = pre_cat + (size_t)KXOFF * Dd; g.czo = (long)MK * Dd; g.czi = 64; g.ldc = Dd;
      g.M = MK; g.N = 64; g.K = Nn;
      launch_mgemm<64, 64, 4>(g, 32, stream);
    }

    // ---- Wout + residual over all rows ----
    {
      GArgs g = ga_base();
      g.A = (const short*)pre_cat; g.lda = Dd;
      g.Bt = (const short*)WoutTl; g.ldb = Dd;
      g.C = xcat_s; g.ldc = Dd; g.bias = bo; g.res = xcat_n; g.ldr = Dd;
      g.M = NTOK; g.N = Dd; g.K = Dd;
      launch_mgemm<128, 64, 2>(g, 1, stream);
    }

    // ---- FF over all rows ----
    ln_kernel<<<NTOK, 64, 0, stream>>>(xcat_s, ln2g + l * Dd, ln2b + l * Dd, xcat_n, xcat_nb);
    {
      GArgs g = ga_base();
      g.A = (const short*)xcat_nb; g.lda = Dd;
      g.Bt = (const short*)W1Tl; g.ldb = Dd;
      g.Cb = hid; g.ldc = MLPD; g.bias = b1l;
      g.M = NTOK; g.N = MLPD; g.K = Dd;
      launch_mgemm<128, 128, 3>(g, 1, stream);
      GArgs h = ga_base();
      h.A = (const short*)hid; h.lda = MLPD;
      h.Bt = (const short*)W2Tl; h.ldb = MLPD;
      h.C = xcat_s; h.ldc = Dd; h.bias = b2l; h.res = xcat_s; h.ldr = Dd;
      h.M = NTOK; h.N = Dd; h.K = MLPD;
      launch_mgemm<128, 64, 2>(h, 1, stream);
    }

    kreps_kernel<<<(Bb * MK * Dd) / 256, 256, 0, stream>>>(
        xcat_s + (size_t)KXOFF * Dd, kmask, out + (size_t)l * Bb * MK * Dd);
  }
  cout_kernel<<<(Bb * Dd) / 256, 256, 0, stream>>>(xcat_s + (size_t)CLOFF * Dd, out + CL_OFF);
}

// Round 12
// 772.275 us; speedup vs baseline: 1.3452x; 1.0467x over previous
//
#include <hip/hip_runtime.h>
#include <hip/hip_bf16.h>
#include <cstddef>

#define DEV __device__ __forceinline__

constexpr int Bb  = 4;
constexpr int Nn  = 2048;
constexpr int MK  = 256;
constexpr int Dd  = 512;
constexpr int Hh  = 8;
constexpr int DH  = 64;
constexpr int QLD = 1536;   // qkv row stride (3*512)
constexpr int MLPD = 2048;
constexpr int NTOK = Bb * Nn + Bb * MK + Bb;   // 9220 concatenated rows
constexpr int KXOFF = Bb * Nn;                 // 8192: first kx row
constexpr int CLOFF = Bb * Nn + Bb * MK;       // 9216: first cls row
constexpr float SCALE = 0.125f;   // 64^-0.5
constexpr float NEGV  = -1e9f;

typedef __attribute__((ext_vector_type(8))) short short8;
typedef __attribute__((ext_vector_type(4))) float f32x4;

DEV float4 ldf4(const float* p) { return *reinterpret_cast<const float4*>(p); }

// async global->LDS, 16B per lane, linear LDS dest
DEV void gload16(const short* g, short* l) {
  __builtin_amdgcn_global_load_lds(
      (const __attribute__((address_space(1))) void*)g,
      (__attribute__((address_space(3))) void*)l, 16, 0, 0);
}

DEV float waveMax(float v) {
#pragma unroll
  for (int o = 32; o; o >>= 1) v = fmaxf(v, __shfl_xor(v, o));
  return v;
}
DEV float waveSum(float v) {
#pragma unroll
  for (int o = 32; o; o >>= 1) v += __shfl_xor(v, o);
  return v;
}
DEV float blockMax256(float v, float* red) {
  v = waveMax(v);
  __syncthreads();
  if ((threadIdx.x & 63) == 0) red[threadIdx.x >> 6] = v;
  __syncthreads();
  return fmaxf(fmaxf(red[0], red[1]), fmaxf(red[2], red[3]));
}
DEV float blockSum256(float v, float* red) {
  v = waveSum(v);
  __syncthreads();
  if ((threadIdx.x & 63) == 0) red[threadIdx.x >> 6] = v;
  __syncthreads();
  return red[0] + red[1] + red[2] + red[3];
}
DEV float gelu_f(float x) { return 0.5f * x * (1.f + erff(x * 0.70710678118654752f)); }
// exact: e1^24 (5 multiplies)
DEV float pow24(float e1) {
  float e2 = e1 * e1, e4 = e2 * e2, e8 = e4 * e4, e16 = e8 * e8;
  return e16 * e8;
}

// ---------------- input concat copy: {x, kx, cls} -> xcat_s ----------------
__global__ __launch_bounds__(256)
void copy3_kernel(const float* __restrict__ x, const float* __restrict__ kx,
                  const float* __restrict__ c, float* __restrict__ dst) {
  const int idx = blockIdx.x * 256 + threadIdx.x;   // float4 index
  const int row = idx >> 7;
  float4 v;
  if (row < KXOFF) v = ldf4(x + (size_t)idx * 4);
  else if (row < CLOFF) v = ldf4(kx + (size_t)idx * 4 - (size_t)KXOFF * Dd);
  else v = ldf4(c + (size_t)idx * 4 - (size_t)CLOFF * Dd);
  *reinterpret_cast<float4*>(dst + (size_t)idx * 4) = v;
}

// ---------------- LayerNorm: one wave per 512-float row, dual f32+bf16 out ----------------
__global__ __launch_bounds__(64)
void ln_kernel(const float* __restrict__ in, const float* __restrict__ gw,
               const float* __restrict__ bw, float* __restrict__ out,
               __hip_bfloat16* __restrict__ outb) {
  const int row = blockIdx.x;
  const int t = threadIdx.x;
  const float* p = in + (size_t)row * Dd + t * 8;
  float4 v0 = ldf4(p), v1 = ldf4(p + 4);
  float s = v0.x + v0.y + v0.z + v0.w + v1.x + v1.y + v1.z + v1.w;
  float q = v0.x*v0.x + v0.y*v0.y + v0.z*v0.z + v0.w*v0.w
          + v1.x*v1.x + v1.y*v1.y + v1.z*v1.z + v1.w*v1.w;
  s = waveSum(s); q = waveSum(q);
  const float mu = s * (1.f / Dd);
  const float rstd = rsqrtf(fmaxf(q * (1.f / Dd) - mu * mu, 0.f) + 1e-5f);
  float4 g0 = ldf4(gw + t * 8), g1 = ldf4(gw + t * 8 + 4);
  float4 b0 = ldf4(bw + t * 8), b1 = ldf4(bw + t * 8 + 4);
  float o[8];
  o[0] = (v0.x - mu) * rstd * g0.x + b0.x;
  o[1] = (v0.y - mu) * rstd * g0.y + b0.y;
  o[2] = (v0.z - mu) * rstd * g0.z + b0.z;
  o[3] = (v0.w - mu) * rstd * g0.w + b0.w;
  o[4] = (v1.x - mu) * rstd * g1.x + b1.x;
  o[5] = (v1.y - mu) * rstd * g1.y + b1.y;
  o[6] = (v1.z - mu) * rstd * g1.z + b1.z;
  o[7] = (v1.w - mu) * rstd * g1.w + b1.w;
  float* op = out + (size_t)row * Dd + t * 8;
  *reinterpret_cast<float4*>(op)     = make_float4(o[0], o[1], o[2], o[3]);
  *reinterpret_cast<float4*>(op + 4) = make_float4(o[4], o[5], o[6], o[7]);
  __hip_bfloat16* ob = outb + (size_t)row * Dd + t * 8;
#pragma unroll
  for (int e = 0; e < 8; ++e) ob[e] = __float2bfloat16(o[e]);
}

// ---------------- bf16 MFMA GEMM ----------------
// Single-buffered (32 KB LDS -> 5 blocks/CU; wave-level cross-block overlap
// hides the vmcnt drain per m114), source-pre-swizzled staging (conflict-free
// ds_read_b128), bijective XCD swizzle.
// EPI: 0 = f32 write; 2 = +bias +res f32; 3 = +bias, gelu, bf16; 4 = bf16.
struct GArgs {
  const short* A;  long asb; int lda;
  const short* Bt; long bsb; int ldb;
  float* C; __hip_bfloat16* Cb;
  long czo, czi; int ldc;
  const float* bias;
  const float* res; int ldr;
  int M, N, K;
};

template<int BM, int BN, int EPI>
__global__ __launch_bounds__(256)
void mgemm(GArgs g) {
  constexpr int WMW = (BN >= 128) ? 2 : 4;
  constexpr int WNW = 4 / WMW;
  constexpr int WM = BM / WMW, WN = BN / WNW;
  constexpr int FM = WM / 16, FN = WN / 16;
  __shared__ __align__(16) short As[BM * 64];
  __shared__ __align__(16) short Bs[BN * 64];
  const int tid = threadIdx.x, l = tid & 63, w = tid >> 6;
  const int wm = (WNW == 2) ? (w >> 1) : w;
  const int wn = (WNW == 2) ? (w & 1) : 0;
  int bx = blockIdx.x, by = blockIdx.y;
  {  // bijective XCD swizzle (m204)
    const int gx = gridDim.x, nwg = gx * gridDim.y;
    const int orig = by * gx + bx;
    const int xcd = orig & 7, pos = orig >> 3;
    const int q = nwg >> 3, rmd = nwg & 7;
    const int s = (xcd < rmd ? xcd * (q + 1) : rmd * (q + 1) + (xcd - rmd) * q) + pos;
    bx = s % gx; by = s / gx;
  }
  const int z = blockIdx.z;
  const short* Ab = g.A + (size_t)z * g.asb;
  const short* Bb_ = g.Bt + (size_t)z * g.bsb;
  f32x4 acc[FM][FN] = {};
  const int lr = l & 15, lg = l >> 4;

  for (int k0 = 0; k0 < g.K; k0 += 64) {
    __syncthreads();     // previous reads done before overwrite
#pragma unroll
    for (int it = 0; it < BM / 32; ++it) {
      int idx = tid + it * 256, r = idx >> 3, c = idx & 7;
      int gm = by * BM + r;
      if (gm >= g.M) gm = g.M - 1;   // clamp; rows independent, masked at write
      gload16(Ab + (size_t)gm * g.lda + k0 + ((c ^ (r & 7)) * 8), As + idx * 8);
    }
#pragma unroll
    for (int it = 0; it < BN / 32; ++it) {
      int idx = tid + it * 256, r = idx >> 3, c = idx & 7;
      int gn = bx * BN + r;
      gload16(Bb_ + (size_t)gn * g.ldb + k0 + ((c ^ (r & 7)) * 8), Bs + idx * 8);
    }
    __syncthreads();     // compiler-inserted vmcnt(0) drain + barrier
#pragma unroll
    for (int ks = 0; ks < 2; ++ks) {
      short8 a[FM], b[FN];
#pragma unroll
      for (int fm = 0; fm < FM; ++fm) {
        int rr = wm * WM + fm * 16 + lr;
        int ch = (ks * 4 + lg) ^ (rr & 7);
        a[fm] = *reinterpret_cast<const short8*>(As + rr * 64 + ch * 8);
      }
#pragma unroll
      for (int fn = 0; fn < FN; ++fn) {
        int rn = wn * WN + fn * 16 + lr;
        int ch = (ks * 4 + lg) ^ (rn & 7);
        b[fn] = *reinterpret_cast<const short8*>(Bs + rn * 64 + ch * 8);
      }
#pragma unroll
      for (int fm = 0; fm < FM; ++fm)
#pragma unroll
        for (int fn = 0; fn < FN; ++fn)
          acc[fm][fn] = __builtin_amdgcn_mfma_f32_16x16x32_bf16(a[fm], b[fn], acc[fm][fn], 0, 0, 0);
    }
  }

  const size_t zoff = (size_t)(z >> 3) * g.czo + (size_t)(z & 7) * g.czi;
#pragma unroll
  for (int fm = 0; fm < FM; ++fm) {
#pragma unroll
    for (int fn = 0; fn < FN; ++fn) {
#pragma unroll
      for (int r = 0; r < 4; ++r) {
        int m = by * BM + wm * WM + fm * 16 + lg * 4 + r;
        int n = bx * BN + wn * WN + fn * 16 + lr;
        if (m >= g.M) continue;
        float v = acc[fm][fn][r];
        size_t coff = zoff + (size_t)m * g.ldc + n;
        if (EPI == 0) {
          g.C[coff] = v;
        } else if (EPI == 2) {
          v += g.bias[n] + g.res[(size_t)m * g.ldr + n];
          g.C[coff] = v;
        } else if (EPI == 3) {
          v = gelu_f(v + g.bias[n]);
          g.Cb[coff] = __float2bfloat16(v);
        } else {
          g.Cb[coff] = __float2bfloat16(v);
        }
      }
    }
  }
}

template<int BM, int BN, int EPI>
static void launch_mgemm(const GArgs& g, int zdim, hipStream_t s) {
  dim3 grid((g.N + BN - 1) / BN, (g.M + BM - 1) / BM, zdim);
  mgemm<BM, BN, EPI><<<grid, 256, 0, s>>>(g);
}

// ---------------- fused x-path score GEMM + dual softmax (512 threads) ----------------
// grid (Nn/128, 32). BM=128, BN=256 (full j-row). 8 waves: wm=w>>1 (32-row
// groups), wn=w&1 (128-col halves). Single exp per element; e24 = e1^24.
__global__ __launch_bounds__(512)
void score_sx_kernel(const short* __restrict__ Q, const short* __restrict__ Km,
                     const float* __restrict__ mask, const float* __restrict__ kmask,
                     const float* __restrict__ rdT,
                     __hip_bfloat16* __restrict__ P1, __hip_bfloat16* __restrict__ E24) {
  __shared__ __align__(16) short As[128 * 64];
  __shared__ __align__(16) short Bs[256 * 64];
  __shared__ float red[128 * 2];
  __shared__ float red2[128 * 4];
  const int tid = threadIdx.x, l = tid & 63, w = tid >> 6;
  const int wm = w >> 1, wn = w & 1;
  const int by = blockIdx.x, bh = blockIdx.y;
  const int b = bh >> 3;
  const short* Ab = Q + (size_t)bh * Nn * 128;
  const short* Bb = Km + (size_t)bh * MK * 128;
  const int lr = l & 15, lg = l >> 4;
  f32x4 acc[2][8] = {};

  for (int k0 = 0; k0 < 128; k0 += 64) {
    __syncthreads();
#pragma unroll
    for (int it = 0; it < 2; ++it) {
      int idx = tid + it * 512, r = idx >> 3, c = idx & 7;
      gload16(Ab + (size_t)(by * 128 + r) * 128 + k0 + ((c ^ (r & 7)) * 8), As + idx * 8);
    }
#pragma unroll
    for (int it = 0; it < 4; ++it) {
      int idx = tid + it * 512, r = idx >> 3, c = idx & 7;
      gload16(Bb + (size_t)r * 128 + k0 + ((c ^ (r & 7)) * 8), Bs + idx * 8);
    }
    __syncthreads();
#pragma unroll
    for (int ks = 0; ks < 2; ++ks) {
      short8 a[2], bv[8];
#pragma unroll
      for (int fm = 0; fm < 2; ++fm) {
        int rr = wm * 32 + fm * 16 + lr;
        int ch = (ks * 4 + lg) ^ (rr & 7);
        a[fm] = *reinterpret_cast<const short8*>(As + rr * 64 + ch * 8);
      }
#pragma unroll
      for (int fn = 0; fn < 8; ++fn) {
        int rn = wn * 128 + fn * 16 + lr;
        int ch = (ks * 4 + lg) ^ (rn & 7);
        bv[fn] = *reinterpret_cast<const short8*>(Bs + rn * 64 + ch * 8);
      }
#pragma unroll
      for (int fm = 0; fm < 2; ++fm)
#pragma unroll
        for (int fn = 0; fn < 8; ++fn)
          acc[fm][fn] = __builtin_amdgcn_mfma_f32_16x16x32_bf16(a[fm], bv[fn], acc[fm][fn], 0, 0, 0);
    }
  }
  // mask + scale in place
  {
    float colm[8];
#pragma unroll
    for (int fn = 0; fn < 8; ++fn)
      colm[fn] = kmask[b * MK + wn * 128 + fn * 16 + lr];
#pragma unroll
    for (int fm = 0; fm < 2; ++fm)
#pragma unroll
      for (int r = 0; r < 4; ++r) {
        float rm = mask[(size_t)b * Nn + by * 128 + wm * 32 + fm * 16 + lg * 4 + r];
#pragma unroll
        for (int fn = 0; fn < 8; ++fn)
          acc[fm][fn][r] = (rm * colm[fn] < 0.5f) ? NEGV : acc[fm][fn][r] * SCALE;
      }
  }
  // row max: local frags -> 16-lane shfl -> cross-wave (wn) via LDS
  float mx[2][4];
#pragma unroll
  for (int fm = 0; fm < 2; ++fm)
#pragma unroll
    for (int r = 0; r < 4; ++r) {
      float m = -3.4e38f;
#pragma unroll
      for (int fn = 0; fn < 8; ++fn) m = fmaxf(m, acc[fm][fn][r]);
#pragma unroll
      for (int o = 8; o; o >>= 1) m = fmaxf(m, __shfl_xor(m, o));
      mx[fm][r] = m;
    }
  __syncthreads();
  if (lr == 0) {
#pragma unroll
    for (int fm = 0; fm < 2; ++fm)
#pragma unroll
      for (int r = 0; r < 4; ++r)
        red[(wm * 32 + fm * 16 + lg * 4 + r) * 2 + wn] = mx[fm][r];
  }
  __syncthreads();
#pragma unroll
  for (int fm = 0; fm < 2; ++fm)
#pragma unroll
    for (int r = 0; r < 4; ++r) {
      int row = wm * 32 + fm * 16 + lg * 4 + r;
      mx[fm][r] = fmaxf(red[row * 2], red[row * 2 + 1]);
    }
  // single exp per element: store e1 in acc; e24 via 5 mults
  float s1[2][4], s24[2][4];
#pragma unroll
  for (int fm = 0; fm < 2; ++fm)
#pragma unroll
    for (int r = 0; r < 4; ++r) {
      float a1 = 0.f, a24 = 0.f;
#pragma unroll
      for (int fn = 0; fn < 8; ++fn) {
        float e1 = __expf(acc[fm][fn][r] - mx[fm][r]);
        acc[fm][fn][r] = e1;
        a1 += e1;
        a24 += pow24(e1);
      }
#pragma unroll
      for (int o = 8; o; o >>= 1) { a1 += __shfl_xor(a1, o); a24 += __shfl_xor(a24, o); }
      s1[fm][r] = a1; s24[fm][r] = a24;
    }
  __syncthreads();
  if (lr == 0) {
#pragma unroll
    for (int fm = 0; fm < 2; ++fm)
#pragma unroll
      for (int r = 0; r < 4; ++r) {
        int row = wm * 32 + fm * 16 + lg * 4 + r;
        red2[row * 4 + wn * 2]     = s1[fm][r];
        red2[row * 4 + wn * 2 + 1] = s24[fm][r];
      }
  }
  __syncthreads();
#pragma unroll
  for (int fm = 0; fm < 2; ++fm)
#pragma unroll
    for (int r = 0; r < 4; ++r) {
      int row = wm * 32 + fm * 16 + lg * 4 + r;
      s1[fm][r]  = 1.f / (red2[row * 4] + red2[row * 4 + 2]);
      s24[fm][r] = 1.f / (red2[row * 4 + 1] + red2[row * 4 + 3]);
    }
  // normalized writes (e1 already in acc; no exp here)
#pragma unroll
  for (int fm = 0; fm < 2; ++fm) {
#pragma unroll
    for (int r = 0; r < 4; ++r) {
      int m = by * 128 + wm * 32 + fm * 16 + lg * 4 + r;
      const float* rp = rdT + ((size_t)b * Nn + m) * MK;
      size_t obase = ((size_t)bh * Nn + m) * MK;
#pragma unroll
      for (int fn = 0; fn < 8; ++fn) {
        int n = wn * 128 + fn * 16 + lr;
        float e1 = acc[fm][fn][r];
        float rv = rp[n];
        P1[obase + n]  = __float2bfloat16(e1 * s1[fm][r] * rv);
        E24[obase + n] = __float2bfloat16(pow24(e1) * s24[fm][r] * rv);
      }
    }
  }
}

// ---------------- fused k-path score GEMM + softmax ----------------
// grid (32 bh, MK/16). Block: 16 j-rows x full 2048-i row. K=64 (hi only).
__global__ __launch_bounds__(256)
void score_sk_kernel(const short* __restrict__ Qk, const short* __restrict__ Kt,
                     const float* __restrict__ mask, const float* __restrict__ kmask,
                     const float* __restrict__ rd, __hip_bfloat16* __restrict__ P2) {
  __shared__ __align__(16) short As[16 * 64];
  __shared__ __align__(16) short Bs[256 * 64];
  __shared__ float redm[16 * 4];
  __shared__ float reds[16 * 4];
  const int tid = threadIdx.x, l = tid & 63, w = tid >> 6;
  const int lr = l & 15, lg = l >> 4;
  const int bh = blockIdx.x, j0 = blockIdx.y * 16, b = bh >> 3;
  const short* Ab = Qk + ((size_t)bh * MK + j0) * 64;
  const short* Bb = Kt + (size_t)bh * Nn * 64;
  f32x4 acc[32];
#pragma unroll
  for (int q = 0; q < 32; ++q) acc[q] = f32x4{0.f, 0.f, 0.f, 0.f};
  if (tid < 128) {     // stage A once: 16 rows x 64 (first two waves)
    int r = tid >> 3, c = tid & 7;
    gload16(Ab + (size_t)r * 64 + ((c ^ (r & 7)) * 8), As + tid * 8);
  }
#pragma unroll
  for (int nc = 0; nc < 8; ++nc) {
    __syncthreads();
#pragma unroll
    for (int it = 0; it < 8; ++it) {
      int idx = tid + it * 256, r = idx >> 3, c = idx & 7;
      gload16(Bb + (size_t)(nc * 256 + r) * 64 + ((c ^ (r & 7)) * 8), Bs + idx * 8);
    }
    __syncthreads();
#pragma unroll
    for (int ks = 0; ks < 2; ++ks) {
      short8 a;
      {
        int ch = (ks * 4 + lg) ^ (lr & 7);
        a = *reinterpret_cast<const short8*>(As + lr * 64 + ch * 8);
      }
#pragma unroll
      for (int fn = 0; fn < 4; ++fn) {
        int rn = w * 64 + fn * 16 + lr;
        int ch = (ks * 4 + lg) ^ (rn & 7);
        short8 bv = *reinterpret_cast<const short8*>(Bs + rn * 64 + ch * 8);
        acc[nc * 4 + fn] =
            __builtin_amdgcn_mfma_f32_16x16x32_bf16(a, bv, acc[nc * 4 + fn], 0, 0, 0);
      }
    }
  }
  float rm[4];
#pragma unroll
  for (int rr = 0; rr < 4; ++rr) rm[rr] = kmask[b * MK + j0 + lg * 4 + rr];
  float mx[4] = {-3.4e38f, -3.4e38f, -3.4e38f, -3.4e38f};
#pragma unroll
  for (int q = 0; q < 32; ++q) {
    int n = (q >> 2) * 256 + w * 64 + (q & 3) * 16 + lr;
    float cm = mask[(size_t)b * Nn + n];
#pragma unroll
    for (int rr = 0; rr < 4; ++rr) {
      float v = (rm[rr] * cm < 0.5f) ? NEGV : acc[q][rr] * SCALE;
      acc[q][rr] = v;
      mx[rr] = fmaxf(mx[rr], v);
    }
  }
#pragma unroll
  for (int o = 8; o; o >>= 1)
#pragma unroll
    for (int rr = 0; rr < 4; ++rr) mx[rr] = fmaxf(mx[rr], __shfl_xor(mx[rr], o));
  __syncthreads();
  if (lr == 0) {
#pragma unroll
    for (int rr = 0; rr < 4; ++rr) redm[(lg * 4 + rr) * 4 + w] = mx[rr];
  }
  __syncthreads();
#pragma unroll
  for (int rr = 0; rr < 4; ++rr) {
    int row = lg * 4 + rr;
    mx[rr] = fmaxf(fmaxf(redm[row * 4], redm[row * 4 + 1]),
                   fmaxf(redm[row * 4 + 2], redm[row * 4 + 3]));
  }
  float sm[4] = {0.f, 0.f, 0.f, 0.f};
#pragma unroll
  for (int q = 0; q < 32; ++q)
#pragma unroll
    for (int rr = 0; rr < 4; ++rr) {
      float e = __expf(acc[q][rr] - mx[rr]);
      acc[q][rr] = e;
      sm[rr] += e;
    }
#pragma unroll
  for (int o = 8; o; o >>= 1)
#pragma unroll
    for (int rr = 0; rr < 4; ++rr) sm[rr] += __shfl_xor(sm[rr], o);
  __syncthreads();
  if (lr == 0) {
#pragma unroll
    for (int rr = 0; rr < 4; ++rr) reds[(lg * 4 + rr) * 4 + w] = sm[rr];
  }
  __syncthreads();
  float inv[4];
#pragma unroll
  for (int rr = 0; rr < 4; ++rr) {
    int row = lg * 4 + rr;
    inv[rr] = 1.f / (reds[row * 4] + reds[row * 4 + 1] + reds[row * 4 + 2] + reds[row * 4 + 3]);
  }
#pragma unroll
  for (int rr = 0; rr < 4; ++rr) {
    int j = j0 + lg * 4 + rr;
    const float* rp = rd + (size_t)(b * MK + j) * Nn;
    __hip_bfloat16* pp = P2 + ((size_t)bh * MK + j) * Nn;
#pragma unroll
    for (int q = 0; q < 32; ++q) {
      int n = (q >> 2) * 256 + w * 64 + (q & 3) * 16 + lr;
      pp[n] = __float2bfloat16(acc[q][rr] * inv[rr] * rp[n]);
    }
  }
}

// ---------------- atten transpose: E24 bf16 [bh][i][j] -> f32 [bh][j][i] ----------------
__global__ __launch_bounds__(256)
void at_tr_kernel(const __hip_bfloat16* __restrict__ E, float* __restrict__ atten) {
  __shared__ __hip_bfloat16 t[64][72];
  const int bh = blockIdx.x;
  const int i0 = blockIdx.y * 64, j0 = blockIdx.z * 64;
  const int tid = threadIdx.x;
#pragma unroll
  for (int it = 0; it < 2; ++it) {
    int idx = tid + it * 256, r = idx >> 3, c8 = (idx & 7) * 8;
    short8 v = *reinterpret_cast<const short8*>(
        (const short*)E + ((size_t)bh * Nn + i0 + r) * MK + j0 + c8);
#pragma unroll
    for (int e = 0; e < 8; ++e)
      *reinterpret_cast<short*>(&t[r][c8 + e]) = v[e];
  }
  __syncthreads();
#pragma unroll
  for (int it = 0; it < 4; ++it) {
    int idx = tid + it * 256, jr = idx >> 4, c4 = (idx & 15) * 4;
    float4 o;
    o.x = __bfloat162float(t[c4 + 0][jr]);
    o.y = __bfloat162float(t[c4 + 1][jr]);
    o.z = __bfloat162float(t[c4 + 2][jr]);
    o.w = __bfloat162float(t[c4 + 3][jr]);
    *reinterpret_cast<float4*>(
        atten + ((size_t)bh * MK + j0 + jr) * Nn + i0 + c4) = o;
  }
}

// ---------------- rd transpose: [b][j][i] -> rdT [b][i][j] (runs once) ----------------
__global__ __launch_bounds__(256)
void rd_tr_kernel(const float* __restrict__ rd, float* __restrict__ rdT) {
  __shared__ float tb[64][65];
  const int b = blockIdx.x;
  const int i0 = blockIdx.y * 64, j0 = blockIdx.z * 64;
  const int tid = threadIdx.x;
#pragma unroll
  for (int it = 0; it < 4; ++it) {
    int idx = tid + it * 256, r = idx >> 4, c4 = (idx & 15) * 4;
    float4 v = ldf4(rd + ((size_t)(b * MK + j0 + r)) * Nn + i0 + c4);
    tb[r][c4 + 0] = v.x; tb[r][c4 + 1] = v.y; tb[r][c4 + 2] = v.z; tb[r][c4 + 3] = v.w;
  }
  __syncthreads();
#pragma unroll
  for (int it = 0; it < 4; ++it) {
    int idx = tid + it * 256, r = idx >> 4, c4 = (idx & 15) * 4;
    float4 o = make_float4(tb[c4 + 0][r], tb[c4 + 1][r], tb[c4 + 2][r], tb[c4 + 3][r]);
    *reinterpret_cast<float4*>(rdT + ((size_t)(b * Nn + i0 + r)) * MK + j0 + c4) = o;
  }
}

// ---------------- batched weight transpose: 8 matrices in one launch ----------------
struct WtArgs {
  const float* W[8];
  __hip_bfloat16* T[8];
  int K[8], N[8];
};
__global__ __launch_bounds__(256)
void wtrans_all_kernel(WtArgs a) {
  __shared__ float t[64][65];
  const int e = blockIdx.z;
  const int K = a.K[e], N = a.N[e];
  const int n0 = blockIdx.x * 64, k0 = blockIdx.y * 64;
  if (n0 >= N || k0 >= K) return;
  const float* W = a.W[e];
  __hip_bfloat16* WT = a.T[e];
  const int tid = threadIdx.x;
#pragma unroll
  for (int it = 0; it < 4; ++it) {
    int idx = tid + it * 256, r = idx >> 4, f = idx & 15;
    float4 v = ldf4(W + (size_t)(k0 + r) * N + n0 + f * 4);
    t[r][f * 4 + 0] = v.x; t[r][f * 4 + 1] = v.y;
    t[r][f * 4 + 2] = v.z; t[r][f * 4 + 3] = v.w;
  }
  __syncthreads();
#pragma unroll
  for (int it = 0; it < 4; ++it) {
    int idx = tid + it * 256, r = idx >> 4, c4 = (idx & 15) * 4;
    __hip_bfloat16* op = WT + (size_t)(n0 + r) * K + k0 + c4;
#pragma unroll
    for (int e2 = 0; e2 < 4; ++e2) op[e2] = __float2bfloat16(t[c4 + e2][r]);
  }
}

// ---------------- qkv split: hi/lo bf16 operand prep ----------------
template<bool Q_SPLIT>
__global__ __launch_bounds__(256)
void split_kernel(const float* __restrict__ qkv, __hip_bfloat16* __restrict__ qout,
                  __hip_bfloat16* __restrict__ kout, int T) {
  const int idx = blockIdx.x * 256 + threadIdx.x;
  const int token = idx >> 7, c8 = (idx & 127) * 8;
  const int b = token / T, i = token - b * T;
  const float* p = qkv + (size_t)token * QLD + c8;
  float v[8];
  float4 a = ldf4(p), c = ldf4(p + 4);
  v[0]=a.x; v[1]=a.y; v[2]=a.z; v[3]=a.w; v[4]=c.x; v[5]=c.y; v[6]=c.z; v[7]=c.w;
  if (c8 < 512) {
    int h = c8 >> 6, d = c8 & 63;
    if (Q_SPLIT) {
      __hip_bfloat16* q = qout + ((size_t)((b * 8 + h) * T + i)) * 128 + d;
#pragma unroll
      for (int e = 0; e < 8; ++e) {
        __hip_bfloat16 hi = __float2bfloat16(v[e]);
        q[e] = hi;
        q[64 + e] = __float2bfloat16(v[e] - __bfloat162float(hi));
      }
    } else {
      __hip_bfloat16* q = qout + ((size_t)((b * 8 + h) * T + i)) * 64 + d;
#pragma unroll
      for (int e = 0; e < 8; ++e) q[e] = __float2bfloat16(v[e]);
    }
  } else {
    int cc = c8 - 512, h = cc >> 6, d = cc & 63;
    if (Q_SPLIT) {
      __hip_bfloat16* k = kout + ((size_t)((b * 8 + h) * T + i)) * 64 + d;
#pragma unroll
      for (int e = 0; e < 8; ++e) k[e] = __float2bfloat16(v[e]);
    } else {
      __hip_bfloat16* k = kout + ((size_t)((b * 8 + h) * T + i)) * 128 + d;
#pragma unroll
      for (int e = 0; e < 8; ++e) {
        __hip_bfloat16 hi = __float2bfloat16(v[e]);
        k[e] = hi;
        k[64 + e] = __float2bfloat16(v[e] - __bfloat162float(hi));
      }
    }
  }
}

// ---------------- v transpose: qkv v-part -> bf16 [bh][d][token] ----------------
__global__ __launch_bounds__(256)
void vtrans_kernel(const float* __restrict__ qkv, __hip_bfloat16* __restrict__ vT, int T) {
  __shared__ float t[64][65];
  const int bh = blockIdx.x, b = bh >> 3, h = bh & 7;
  const int i0 = blockIdx.y * 64;
  const int tid = threadIdx.x;
#pragma unroll
  for (int it = 0; it < 4; ++it) {
    int idx = tid + it * 256, r = idx >> 4, f = idx & 15;
    float4 v = ldf4(qkv + (size_t)(b * T + i0 + r) * QLD + 2 * Dd + h * 64 + f * 4);
    t[r][f * 4 + 0] = v.x; t[r][f * 4 + 1] = v.y;
    t[r][f * 4 + 2] = v.z; t[r][f * 4 + 3] = v.w;
  }
  __syncthreads();
#pragma unroll
  for (int it = 0; it < 4; ++it) {
    int idx = tid + it * 256, d = idx >> 4, c4 = (idx & 15) * 4;
    __hip_bfloat16* op = vT + (size_t)(bh * 64 + d) * T + i0 + c4;
#pragma unroll
    for (int e = 0; e < 4; ++e) op[e] = __float2bfloat16(t[c4 + e][d]);
  }
}

// ------------- cls-token attention: grid B*H, block 256, bf16 out -------------
__global__ __launch_bounds__(256)
void attn_c_kernel(const float* __restrict__ cqkv, const float* __restrict__ kqkv,
                   const float* __restrict__ mask, const float* __restrict__ kmask,
                   __hip_bfloat16* __restrict__ c_pre) {
  __shared__ __align__(16) float kv_s[MK][DH];
  __shared__ __align__(16) float q_s[DH];
  __shared__ float pbuf[MK];
  __shared__ float red8[8];
  __shared__ float redpv[4][DH];
  const int tid = threadIdx.x;
  const int bh = blockIdx.x, b = bh >> 3, h = bh & 7;
  const float* vp = kqkv + ((size_t)(b * MK + tid)) * QLD + 2 * Dd + h * DH;
#pragma unroll
  for (int q4 = 0; q4 < 16; ++q4)
    *reinterpret_cast<float4*>(&kv_s[tid][q4 * 4]) = ldf4(vp + q4 * 4);
  if (tid < DH) q_s[tid] = cqkv[(size_t)b * QLD + h * DH + tid];
  __syncthreads();
  const float* kp = kqkv + ((size_t)(b * MK + tid)) * QLD + Dd + h * DH;
  float dot = 0.f;
#pragma unroll
  for (int q4 = 0; q4 < 16; ++q4) {
    float4 kv4 = ldf4(kp + q4 * 4);
    float4 qv = ldf4(&q_s[q4 * 4]);
    dot = fmaf(qv.x, kv4.x, dot);
    dot = fmaf(qv.y, kv4.y, dot);
    dot = fmaf(qv.z, kv4.z, dot);
    dot = fmaf(qv.w, kv4.w, dot);
  }
  const float dm = (mask[(size_t)b * Nn] * kmask[b * MK + tid] < 0.5f) ? NEGV : dot * SCALE;
  const float mx = blockMax256(dm, red8);
  const float e = __expf(dm - mx);
  const float s = blockSum256(e, red8);
  pbuf[tid] = e / s;
  __syncthreads();
  const int d = tid & 63, g = tid >> 6;
  float acc = 0.f;
#pragma unroll 8
  for (int jj = 0; jj < 64; ++jj)
    acc = fmaf(pbuf[g * 64 + jj], kv_s[g * 64 + jj][d], acc);
  redpv[g][d] = acc;
  __syncthreads();
  if (tid < DH)
    c_pre[(size_t)b * Dd + h * DH + tid] = __float2bfloat16(
        redpv[0][tid] + redpv[1][tid] + redpv[2][tid] + redpv[3][tid]);
}

// ------------- output writers (float32 outputs) -------------
__global__ void kreps_kernel(const float* __restrict__ kx, const float* __restrict__ kmask,
                             float* __restrict__ o) {
  const int idx = blockIdx.x * 256 + threadIdx.x;
  const int bj = idx >> 9;
  const float keep = (kmask[bj] >= 0.5f) ? 1.f : 0.f;
  o[idx] = kx[idx] * keep;
}
__global__ void cout_kernel(const float* __restrict__ c_s, float* __restrict__ o) {
  const int idx = blockIdx.x * 256 + threadIdx.x;
  o[idx] = c_s[idx];
}

static GArgs ga_base() { GArgs g = {}; return g; }

extern "C" void kernel_launch(void* const* d_in, const int* in_sizes, int n_in,
                              void* d_out, int out_size, void* d_ws, size_t ws_size,
                              hipStream_t stream) {
  (void)in_sizes; (void)n_in; (void)out_size; (void)ws_size;
  const float* x_in  = (const float*)d_in[0];
  const float* kx_in = (const float*)d_in[1];
  const float* rd    = (const float*)d_in[2];
  const float* c_in  = (const float*)d_in[3];
  const float* mask  = (const float*)d_in[4];
  const float* kmask = (const float*)d_in[5];
  const float* ln1g  = (const float*)d_in[6];
  const float* ln1b  = (const float*)d_in[7];
  const float* Wqkv  = (const float*)d_in[8];
  const float* Woutw = (const float*)d_in[9];
  const float* boutw = (const float*)d_in[10];
  const float* ln2g  = (const float*)d_in[11];
  const float* ln2b  = (const float*)d_in[12];
  const float* W1    = (const float*)d_in[13];
  const float* b1    = (const float*)d_in[14];
  const float* W2    = (const float*)d_in[15];
  const float* b2    = (const float*)d_in[16];
  float* out = (float*)d_out;

  float* ws = (float*)d_ws;
  size_t off = 0;
  auto alloc = [&](size_t n) { float* p = ws + off; off += (n + 15) & ~(size_t)15; return p; };
  float* xcat_s    = alloc((size_t)NTOK * Dd);
  float* xcat_n    = alloc((size_t)NTOK * Dd);
  float* xcat_nb_f = alloc((size_t)NTOK * Dd / 2);
  float* pre_cat_f = alloc((size_t)NTOK * Dd / 2);
  float* qkv       = alloc((size_t)NTOK * QLD);     // hosts hid after attention
  float* P1_f      = alloc((size_t)32 * Nn * MK / 2);
  float* E24_f     = alloc((size_t)32 * Nn * MK / 2);
  float* P2_f      = alloc((size_t)32 * MK * Nn / 2);
  float* tq_s_f    = alloc((size_t)32 * Nn * 128 / 2);
  float* kk_s_f    = alloc((size_t)32 * MK * 128 / 2);
  float* tk_hi_f   = alloc((size_t)32 * Nn * 64 / 2);
  float* kq_hi_f   = alloc((size_t)32 * MK * 64 / 2);
  float* tvT_f     = alloc((size_t)32 * 64 * Nn / 2);
  float* kvT_f     = alloc((size_t)32 * 64 * MK / 2);
  float* rdT       = alloc((size_t)Bb * Nn * MK);
  float* WqkvT_f   = alloc((size_t)2 * QLD * Dd / 2);
  float* WoutT_f   = alloc((size_t)2 * Dd * Dd / 2);
  float* W1T_f     = alloc((size_t)2 * MLPD * Dd / 2);
  float* W2T_f     = alloc((size_t)2 * Dd * MLPD / 2);

  __hip_bfloat16* xcat_nb = (__hip_bfloat16*)xcat_nb_f;
  __hip_bfloat16* pre_cat = (__hip_bfloat16*)pre_cat_f;
  __hip_bfloat16* P1b     = (__hip_bfloat16*)P1_f;
  __hip_bfloat16* E24b    = (__hip_bfloat16*)E24_f;
  __hip_bfloat16* P2b     = (__hip_bfloat16*)P2_f;
  __hip_bfloat16* tq_s    = (__hip_bfloat16*)tq_s_f;
  __hip_bfloat16* kk_s    = (__hip_bfloat16*)kk_s_f;
  __hip_bfloat16* tk_hi   = (__hip_bfloat16*)tk_hi_f;
  __hip_bfloat16* kq_hi   = (__hip_bfloat16*)kq_hi_f;
  __hip_bfloat16* tvT     = (__hip_bfloat16*)tvT_f;
  __hip_bfloat16* kvT     = (__hip_bfloat16*)kvT_f;
  __hip_bfloat16* WqkvT   = (__hip_bfloat16*)WqkvT_f;
  __hip_bfloat16* WoutT   = (__hip_bfloat16*)WoutT_f;
  __hip_bfloat16* W1T     = (__hip_bfloat16*)W1T_f;
  __hip_bfloat16* W2T     = (__hip_bfloat16*)W2T_f;
  __hip_bfloat16* hid     = (__hip_bfloat16*)qkv;   // FF hidden overlay

  const size_t CL_OFF = (size_t)2 * Bb * MK * Dd;
  const size_t AT_OFF = CL_OFF + (size_t)Bb * Dd;

  // ---- upfront: input concat, rd transpose, all weight transposes ----
  copy3_kernel<<<(NTOK * 128) / 256, 256, 0, stream>>>(x_in, kx_in, c_in, xcat_s);
  rd_tr_kernel<<<dim3(Bb, Nn / 64, MK / 64), 256, 0, stream>>>(rd, rdT);
  {
    WtArgs a;
    for (int l = 0; l < 2; ++l) {
      a.W[l * 4 + 0] = Wqkv + (size_t)l * Dd * QLD;  a.T[l * 4 + 0] = WqkvT + (size_t)l * QLD * Dd;
      a.K[l * 4 + 0] = Dd;   a.N[l * 4 + 0] = QLD;
      a.W[l * 4 + 1] = Woutw + (size_t)l * Dd * Dd;  a.T[l * 4 + 1] = WoutT + (size_t)l * Dd * Dd;
      a.K[l * 4 + 1] = Dd;   a.N[l * 4 + 1] = Dd;
      a.W[l * 4 + 2] = W1 + (size_t)l * Dd * MLPD;   a.T[l * 4 + 2] = W1T + (size_t)l * MLPD * Dd;
      a.K[l * 4 + 2] = Dd;   a.N[l * 4 + 2] = MLPD;
      a.W[l * 4 + 3] = W2 + (size_t)l * MLPD * Dd;   a.T[l * 4 + 3] = W2T + (size_t)l * Dd * MLPD;
      a.K[l * 4 + 3] = MLPD; a.N[l * 4 + 3] = Dd;
    }
    wtrans_all_kernel<<<dim3(32, 32, 8), 256, 0, stream>>>(a);
  }

  for (int l = 0; l < 2; ++l) {
    const float* bo  = boutw + (size_t)l * Dd;
    const float* b1l = b1 + (size_t)l * MLPD;
    const float* b2l = b2 + (size_t)l * Dd;
    __hip_bfloat16* WqkvTl = WqkvT + (size_t)l * QLD * Dd;
    __hip_bfloat16* WoutTl = WoutT + (size_t)l * Dd * Dd;
    __hip_bfloat16* W1Tl   = W1T + (size_t)l * MLPD * Dd;
    __hip_bfloat16* W2Tl   = W2T + (size_t)l * Dd * MLPD;

    ln_kernel<<<NTOK, 64, 0, stream>>>(xcat_s, ln1g + l * Dd, ln1b + l * Dd, xcat_n, xcat_nb);

    // QKV: one GEMM over all 9220 rows
    {
      GArgs g = ga_base();
      g.A = (const short*)xcat_nb; g.lda = Dd;
      g.Bt = (const short*)WqkvTl; g.ldb = Dd;
      g.C = qkv; g.ldc = QLD;
      g.M = NTOK; g.N = QLD; g.K = Dd;
      launch_mgemm<128, 128, 0>(g, 1, stream);
    }

    split_kernel<true><<<(Bb * Nn * 128) / 256, 256, 0, stream>>>(qkv, tq_s, tk_hi, Nn);
    split_kernel<false><<<(Bb * MK * 128) / 256, 256, 0, stream>>>(
        qkv + (size_t)KXOFF * QLD, kq_hi, kk_s, MK);
    vtrans_kernel<<<dim3(32, Nn / 64), 256, 0, stream>>>(qkv, tvT, Nn);
    vtrans_kernel<<<dim3(32, MK / 64), 256, 0, stream>>>(qkv + (size_t)KXOFF * QLD, kvT, MK);

    attn_c_kernel<<<Bb * Hh, 256, 0, stream>>>(qkv + (size_t)CLOFF * QLD,
                                               qkv + (size_t)KXOFF * QLD, mask, kmask,
                                               pre_cat + (size_t)CLOFF * Dd);

    // ---- x-path: fused score+softmax -> atten transpose -> PV ----
    score_sx_kernel<<<dim3(Nn / 128, 32), 512, 0, stream>>>(
        (const short*)tq_s, (const short*)kk_s, mask, kmask, rdT, P1b, E24b);
    at_tr_kernel<<<dim3(32, Nn / 64, MK / 64), 256, 0, stream>>>(
        E24b, out + AT_OFF + (size_t)l * 32 * MK * Nn);
    {
      GArgs g = ga_base();
      g.A = (const short*)P1b; g.asb = (long)Nn * MK; g.lda = MK;
      g.Bt = (const short*)kvT; g.bsb = (long)64 * MK; g.ldb = MK;
      g.Cb = pre_cat; g.czo = (long)Nn * Dd; g.czi = 64; g.ldc = Dd;
      g.M = Nn; g.N = 64; g.K = MK;
      launch_mgemm<128, 64, 4>(g, 32, stream);
    }
    // ---- k-path: fused score+softmax -> PV ----
    score_sk_kernel<<<dim3(32, MK / 16), 256, 0, stream>>>(
        (const short*)kq_hi, (const short*)tk_hi, mask, kmask, rd, P2b);
    {
      GArgs g = ga_base();
      g.A = (const short*)P2b; g.asb = (long)MK * Nn; g.lda = Nn;
      g.Bt = (const short*)tvT; g.bsb = (long)64 * Nn; g.ldb = Nn;
      g.Cb = pre_cat + (size_t)KXOFF * Dd; g.czo = (long)MK * Dd; g.czi = 64; g.ldc = Dd;
      g.M = MK; g.N = 64; g.K = Nn;
      launch_mgemm<64, 64, 4>(g, 32, stream);
    }

    // ---- Wout + residual over all rows ----
    {
      GArgs g = ga_base();
      g.A = (const short*)pre_cat; g.lda = Dd;
      g.Bt = (const short*)WoutTl; g.ldb = Dd;
      g.C = xcat_s; g.ldc = Dd; g.bias = bo; g.res = xcat_n; g.ldr = Dd;
      g.M = NTOK; g.N = Dd; g.K = Dd;
      launch_mgemm<128, 64, 2>(g, 1, stream);
    }

    // ---- FF over all rows ----
    ln_kernel<<<NTOK, 64, 0, stream>>>(xcat_s, ln2g + l * Dd, ln2b + l * Dd, xcat_n, xcat_nb);
    {
      GArgs g = ga_base();
      g.A = (const short*)xcat_nb; g.lda = Dd;
      g.Bt = (const short*)W1Tl; g.ldb = Dd;
      g.Cb = hid; g.ldc = MLPD; g.bias = b1l;
      g.M = NTOK; g.N = MLPD; g.K = Dd;
      launch_mgemm<128, 128, 3>(g, 1, stream);
      GArgs h = ga_base();
      h.A = (const short*)hid; h.lda = MLPD;
      h.Bt = (const short*)W2Tl; h.ldb = MLPD;
      h.C = xcat_s; h.ldc = Dd; h.bias = b2l; h.res = xcat_s; h.ldr = Dd;
      h.M = NTOK; h.N = Dd; h.K = MLPD;
      launch_mgemm<128, 64, 2>(h, 1, stream);
    }

    kreps_kernel<<<(Bb * MK * Dd) / 256, 256, 0, stream>>>(
        xcat_s + (size_t)KXOFF * Dd, kmask, out + (size_t)l * Bb * MK * Dd);
  }
  cout_kernel<<<(Bb * Dd) / 256, 256, 0, stream>>>(xcat_s + (size_t)CLOFF * Dd, out + CL_OFF);
}

// Round 13
// 732.581 us; speedup vs baseline: 1.4181x; 1.0542x over previous
//
#include <hip/hip_runtime.h>
#include <hip/hip_bf16.h>
#include <cstddef>

#define DEV __device__ __forceinline__

constexpr int Bb  = 4;
constexpr int Nn  = 2048;
constexpr int MK  = 256;
constexpr int Dd  = 512;
constexpr int Hh  = 8;
constexpr int DH  = 64;
constexpr int QLD = 1536;   // qkv row stride (3*512)
constexpr int MLPD = 2048;
constexpr int NTOK = Bb * Nn + Bb * MK + Bb;   // 9220 concatenated rows
constexpr int KXOFF = Bb * Nn;                 // 8192: first kx row
constexpr int CLOFF = Bb * Nn + Bb * MK;       // 9216: first cls row
constexpr float SCALE = 0.125f;   // 64^-0.5
constexpr float NEGV  = -1e9f;

typedef __attribute__((ext_vector_type(8))) short short8;
typedef __attribute__((ext_vector_type(4))) float f32x4;

DEV float4 ldf4(const float* p) { return *reinterpret_cast<const float4*>(p); }

// async global->LDS, 16B per lane, linear LDS dest
DEV void gload16(const short* g, short* l) {
  __builtin_amdgcn_global_load_lds(
      (const __attribute__((address_space(1))) void*)g,
      (__attribute__((address_space(3))) void*)l, 16, 0, 0);
}

DEV float waveMax(float v) {
#pragma unroll
  for (int o = 32; o; o >>= 1) v = fmaxf(v, __shfl_xor(v, o));
  return v;
}
DEV float waveSum(float v) {
#pragma unroll
  for (int o = 32; o; o >>= 1) v += __shfl_xor(v, o);
  return v;
}
DEV float blockMax256(float v, float* red) {
  v = waveMax(v);
  __syncthreads();
  if ((threadIdx.x & 63) == 0) red[threadIdx.x >> 6] = v;
  __syncthreads();
  return fmaxf(fmaxf(red[0], red[1]), fmaxf(red[2], red[3]));
}
DEV float blockSum256(float v, float* red) {
  v = waveSum(v);
  __syncthreads();
  if ((threadIdx.x & 63) == 0) red[threadIdx.x >> 6] = v;
  __syncthreads();
  return red[0] + red[1] + red[2] + red[3];
}
DEV float gelu_f(float x) { return 0.5f * x * (1.f + erff(x * 0.70710678118654752f)); }
// exact: e1^24 (5 multiplies)
DEV float pow24(float e1) {
  float e2 = e1 * e1, e4 = e2 * e2, e8 = e4 * e4, e16 = e8 * e8;
  return e16 * e8;
}

// ---------------- input concat copy: {x, kx, cls} -> xcat_s ----------------
__global__ __launch_bounds__(256)
void copy3_kernel(const float* __restrict__ x, const float* __restrict__ kx,
                  const float* __restrict__ c, float* __restrict__ dst) {
  const int idx = blockIdx.x * 256 + threadIdx.x;   // float4 index
  const int row = idx >> 7;
  float4 v;
  if (row < KXOFF) v = ldf4(x + (size_t)idx * 4);
  else if (row < CLOFF) v = ldf4(kx + (size_t)idx * 4 - (size_t)KXOFF * Dd);
  else v = ldf4(c + (size_t)idx * 4 - (size_t)CLOFF * Dd);
  *reinterpret_cast<float4*>(dst + (size_t)idx * 4) = v;
}

// ---------------- LayerNorm: one wave per 512-float row, bf16 out ----------------
__global__ __launch_bounds__(64)
void ln_kernel(const float* __restrict__ in, const float* __restrict__ gw,
               const float* __restrict__ bw, __hip_bfloat16* __restrict__ outb) {
  const int row = blockIdx.x;
  const int t = threadIdx.x;
  const float* p = in + (size_t)row * Dd + t * 8;
  float4 v0 = ldf4(p), v1 = ldf4(p + 4);
  float s = v0.x + v0.y + v0.z + v0.w + v1.x + v1.y + v1.z + v1.w;
  float q = v0.x*v0.x + v0.y*v0.y + v0.z*v0.z + v0.w*v0.w
          + v1.x*v1.x + v1.y*v1.y + v1.z*v1.z + v1.w*v1.w;
  s = waveSum(s); q = waveSum(q);
  const float mu = s * (1.f / Dd);
  const float rstd = rsqrtf(fmaxf(q * (1.f / Dd) - mu * mu, 0.f) + 1e-5f);
  float4 g0 = ldf4(gw + t * 8), g1 = ldf4(gw + t * 8 + 4);
  float4 b0 = ldf4(bw + t * 8), b1 = ldf4(bw + t * 8 + 4);
  float o[8];
  o[0] = (v0.x - mu) * rstd * g0.x + b0.x;
  o[1] = (v0.y - mu) * rstd * g0.y + b0.y;
  o[2] = (v0.z - mu) * rstd * g0.z + b0.z;
  o[3] = (v0.w - mu) * rstd * g0.w + b0.w;
  o[4] = (v1.x - mu) * rstd * g1.x + b1.x;
  o[5] = (v1.y - mu) * rstd * g1.y + b1.y;
  o[6] = (v1.z - mu) * rstd * g1.z + b1.z;
  o[7] = (v1.w - mu) * rstd * g1.w + b1.w;
  __hip_bfloat16* ob = outb + (size_t)row * Dd + t * 8;
#pragma unroll
  for (int e = 0; e < 8; ++e) ob[e] = __float2bfloat16(o[e]);
}

// ---------------- bf16 MFMA GEMM ----------------
// Single-buffered (32 KB LDS), source-pre-swizzled staging, XCD swizzle.
// EPI: 0 = f32 write; 3 = +bias, gelu, bf16; 4 = bf16;
//      2 = +bias + f32 res, f32 write; 5 = +bias + bf16 res, f32 write.
struct GArgs {
  const short* A;  long asb; int lda;
  const short* Bt; long bsb; int ldb;
  float* C; __hip_bfloat16* Cb;
  long czo, czi; int ldc;
  const float* bias;
  const float* res; const __hip_bfloat16* resb; int ldr;
  int M, N, K;
};

template<int BM, int BN, int EPI>
__global__ __launch_bounds__(256)
void mgemm(GArgs g) {
  constexpr int WMW = (BN >= 128) ? 2 : 4;
  constexpr int WNW = 4 / WMW;
  constexpr int WM = BM / WMW, WN = BN / WNW;
  constexpr int FM = WM / 16, FN = WN / 16;
  __shared__ __align__(16) short As[BM * 64];
  __shared__ __align__(16) short Bs[BN * 64];
  const int tid = threadIdx.x, l = tid & 63, w = tid >> 6;
  const int wm = (WNW == 2) ? (w >> 1) : w;
  const int wn = (WNW == 2) ? (w & 1) : 0;
  int bx = blockIdx.x, by = blockIdx.y;
  {  // bijective XCD swizzle (m204)
    const int gx = gridDim.x, nwg = gx * gridDim.y;
    const int orig = by * gx + bx;
    const int xcd = orig & 7, pos = orig >> 3;
    const int q = nwg >> 3, rmd = nwg & 7;
    const int s = (xcd < rmd ? xcd * (q + 1) : rmd * (q + 1) + (xcd - rmd) * q) + pos;
    bx = s % gx; by = s / gx;
  }
  const int z = blockIdx.z;
  const short* Ab = g.A + (size_t)z * g.asb;
  const short* Bb_ = g.Bt + (size_t)z * g.bsb;
  f32x4 acc[FM][FN] = {};
  const int lr = l & 15, lg = l >> 4;

  for (int k0 = 0; k0 < g.K; k0 += 64) {
    __syncthreads();
#pragma unroll
    for (int it = 0; it < BM / 32; ++it) {
      int idx = tid + it * 256, r = idx >> 3, c = idx & 7;
      int gm = by * BM + r;
      if (gm >= g.M) gm = g.M - 1;   // clamp; rows independent, masked at write
      gload16(Ab + (size_t)gm * g.lda + k0 + ((c ^ (r & 7)) * 8), As + idx * 8);
    }
#pragma unroll
    for (int it = 0; it < BN / 32; ++it) {
      int idx = tid + it * 256, r = idx >> 3, c = idx & 7;
      int gn = bx * BN + r;
      gload16(Bb_ + (size_t)gn * g.ldb + k0 + ((c ^ (r & 7)) * 8), Bs + idx * 8);
    }
    __syncthreads();
#pragma unroll
    for (int ks = 0; ks < 2; ++ks) {
      short8 a[FM], b[FN];
#pragma unroll
      for (int fm = 0; fm < FM; ++fm) {
        int rr = wm * WM + fm * 16 + lr;
        int ch = (ks * 4 + lg) ^ (rr & 7);
        a[fm] = *reinterpret_cast<const short8*>(As + rr * 64 + ch * 8);
      }
#pragma unroll
      for (int fn = 0; fn < FN; ++fn) {
        int rn = wn * WN + fn * 16 + lr;
        int ch = (ks * 4 + lg) ^ (rn & 7);
        b[fn] = *reinterpret_cast<const short8*>(Bs + rn * 64 + ch * 8);
      }
#pragma unroll
      for (int fm = 0; fm < FM; ++fm)
#pragma unroll
        for (int fn = 0; fn < FN; ++fn)
          acc[fm][fn] = __builtin_amdgcn_mfma_f32_16x16x32_bf16(a[fm], b[fn], acc[fm][fn], 0, 0, 0);
    }
  }

  const size_t zoff = (size_t)(z >> 3) * g.czo + (size_t)(z & 7) * g.czi;
#pragma unroll
  for (int fm = 0; fm < FM; ++fm) {
#pragma unroll
    for (int fn = 0; fn < FN; ++fn) {
#pragma unroll
      for (int r = 0; r < 4; ++r) {
        int m = by * BM + wm * WM + fm * 16 + lg * 4 + r;
        int n = bx * BN + wn * WN + fn * 16 + lr;
        if (m >= g.M) continue;
        float v = acc[fm][fn][r];
        size_t coff = zoff + (size_t)m * g.ldc + n;
        if (EPI == 0) {
          g.C[coff] = v;
        } else if (EPI == 2) {
          v += g.bias[n] + g.res[(size_t)m * g.ldr + n];
          g.C[coff] = v;
        } else if (EPI == 5) {
          v += g.bias[n] + __bfloat162float(g.resb[(size_t)m * g.ldr + n]);
          g.C[coff] = v;
        } else if (EPI == 3) {
          v = gelu_f(v + g.bias[n]);
          g.Cb[coff] = __float2bfloat16(v);
        } else {
          g.Cb[coff] = __float2bfloat16(v);
        }
      }
    }
  }
}

template<int BM, int BN, int EPI>
static void launch_mgemm(const GArgs& g, int zdim, hipStream_t s) {
  dim3 grid((g.N + BN - 1) / BN, (g.M + BM - 1) / BM, zdim);
  mgemm<BM, BN, EPI><<<grid, 256, 0, s>>>(g);
}

// ---------------- fused attention prep: splits + v transposes in one launch ----------------
// regions (flat blockIdx.x):
//   [0, 4096)        split x tokens (q hi/lo + k hi)
//   [4096, 4608)     split kx tokens (q hi + k hi/lo)
//   [4608, 5632)     vtrans x  (bh = r/32, i0 = (r%32)*64)
//   [5632, 5760)     vtrans kx (bh = r/4,  i0 = (r%4)*64)
__global__ __launch_bounds__(256)
void prep_attn_kernel(const float* __restrict__ qkv_x, const float* __restrict__ qkv_k,
                      __hip_bfloat16* __restrict__ tq_s, __hip_bfloat16* __restrict__ tk_hi,
                      __hip_bfloat16* __restrict__ kq_hi, __hip_bfloat16* __restrict__ kk_s,
                      __hip_bfloat16* __restrict__ tvT, __hip_bfloat16* __restrict__ kvT) {
  __shared__ float t[64][65];
  const int blk = blockIdx.x, tid = threadIdx.x;
  if (blk < 4096 + 512) {
    // ---- split path ----
    const bool isX = blk < 4096;
    const int T = isX ? Nn : MK;
    const float* qkv = isX ? qkv_x : qkv_k;
    const int idx = (isX ? blk : blk - 4096) * 256 + tid;
    const int token = idx >> 7, c8 = (idx & 127) * 8;
    const int b = token / T, i = token - b * T;
    const float* p = qkv + (size_t)token * QLD + c8;
    float v[8];
    float4 a = ldf4(p), c = ldf4(p + 4);
    v[0]=a.x; v[1]=a.y; v[2]=a.z; v[3]=a.w; v[4]=c.x; v[5]=c.y; v[6]=c.z; v[7]=c.w;
    if (c8 < 512) {
      int h = c8 >> 6, d = c8 & 63;
      if (isX) {     // q -> hi|lo [128]
        __hip_bfloat16* q = tq_s + ((size_t)((b * 8 + h) * T + i)) * 128 + d;
#pragma unroll
        for (int e = 0; e < 8; ++e) {
          __hip_bfloat16 hi = __float2bfloat16(v[e]);
          q[e] = hi;
          q[64 + e] = __float2bfloat16(v[e] - __bfloat162float(hi));
        }
      } else {       // q -> hi [64]
        __hip_bfloat16* q = kq_hi + ((size_t)((b * 8 + h) * T + i)) * 64 + d;
#pragma unroll
        for (int e = 0; e < 8; ++e) q[e] = __float2bfloat16(v[e]);
      }
    } else {
      int cc = c8 - 512, h = cc >> 6, d = cc & 63;
      if (isX) {     // k -> hi [64]
        __hip_bfloat16* k = tk_hi + ((size_t)((b * 8 + h) * T + i)) * 64 + d;
#pragma unroll
        for (int e = 0; e < 8; ++e) k[e] = __float2bfloat16(v[e]);
      } else {       // k -> hi|lo [128]
        __hip_bfloat16* k = kk_s + ((size_t)((b * 8 + h) * T + i)) * 128 + d;
#pragma unroll
        for (int e = 0; e < 8; ++e) {
          __hip_bfloat16 hi = __float2bfloat16(v[e]);
          k[e] = hi;
          k[64 + e] = __float2bfloat16(v[e] - __bfloat162float(hi));
        }
      }
    }
    return;
  }
  // ---- vtrans path ----
  const bool isX = blk < 5632;
  const int r = isX ? blk - 4608 : blk - 5632;
  const int T = isX ? Nn : MK;
  const int tilesPerBh = T / 64;
  const int bh = r / tilesPerBh, i0 = (r % tilesPerBh) * 64;
  const int b = bh >> 3, h = bh & 7;
  const float* qkv = isX ? qkv_x : qkv_k;
  __hip_bfloat16* vT = isX ? tvT : kvT;
#pragma unroll
  for (int it = 0; it < 4; ++it) {
    int idx = tid + it * 256, rr = idx >> 4, f = idx & 15;
    float4 v = ldf4(qkv + (size_t)(b * T + i0 + rr) * QLD + 2 * Dd + h * 64 + f * 4);
    t[rr][f * 4 + 0] = v.x; t[rr][f * 4 + 1] = v.y;
    t[rr][f * 4 + 2] = v.z; t[rr][f * 4 + 3] = v.w;
  }
  __syncthreads();
#pragma unroll
  for (int it = 0; it < 4; ++it) {
    int idx = tid + it * 256, d = idx >> 4, c4 = (idx & 15) * 4;
    __hip_bfloat16* op = vT + (size_t)(bh * 64 + d) * T + i0 + c4;
#pragma unroll
    for (int e = 0; e < 4; ++e) op[e] = __float2bfloat16(t[c4 + e][d]);
  }
}

// ---------------- fused x-path score GEMM + dual softmax (512 threads) ----------------
__global__ __launch_bounds__(512)
void score_sx_kernel(const short* __restrict__ Q, const short* __restrict__ Km,
                     const float* __restrict__ mask, const float* __restrict__ kmask,
                     const float* __restrict__ rdT,
                     __hip_bfloat16* __restrict__ P1, __hip_bfloat16* __restrict__ E24) {
  __shared__ __align__(16) short As[128 * 64];
  __shared__ __align__(16) short Bs[256 * 64];
  __shared__ float red[128 * 2];
  __shared__ float red2[128 * 4];
  const int tid = threadIdx.x, l = tid & 63, w = tid >> 6;
  const int wm = w >> 1, wn = w & 1;
  const int by = blockIdx.x, bh = blockIdx.y;
  const int b = bh >> 3;
  const short* Ab = Q + (size_t)bh * Nn * 128;
  const short* Bb = Km + (size_t)bh * MK * 128;
  const int lr = l & 15, lg = l >> 4;
  f32x4 acc[2][8] = {};

  for (int k0 = 0; k0 < 128; k0 += 64) {
    __syncthreads();
#pragma unroll
    for (int it = 0; it < 2; ++it) {
      int idx = tid + it * 512, r = idx >> 3, c = idx & 7;
      gload16(Ab + (size_t)(by * 128 + r) * 128 + k0 + ((c ^ (r & 7)) * 8), As + idx * 8);
    }
#pragma unroll
    for (int it = 0; it < 4; ++it) {
      int idx = tid + it * 512, r = idx >> 3, c = idx & 7;
      gload16(Bb + (size_t)r * 128 + k0 + ((c ^ (r & 7)) * 8), Bs + idx * 8);
    }
    __syncthreads();
#pragma unroll
    for (int ks = 0; ks < 2; ++ks) {
      short8 a[2], bv[8];
#pragma unroll
      for (int fm = 0; fm < 2; ++fm) {
        int rr = wm * 32 + fm * 16 + lr;
        int ch = (ks * 4 + lg) ^ (rr & 7);
        a[fm] = *reinterpret_cast<const short8*>(As + rr * 64 + ch * 8);
      }
#pragma unroll
      for (int fn = 0; fn < 8; ++fn) {
        int rn = wn * 128 + fn * 16 + lr;
        int ch = (ks * 4 + lg) ^ (rn & 7);
        bv[fn] = *reinterpret_cast<const short8*>(Bs + rn * 64 + ch * 8);
      }
#pragma unroll
      for (int fm = 0; fm < 2; ++fm)
#pragma unroll
        for (int fn = 0; fn < 8; ++fn)
          acc[fm][fn] = __builtin_amdgcn_mfma_f32_16x16x32_bf16(a[fm], bv[fn], acc[fm][fn], 0, 0, 0);
    }
  }
  {
    float colm[8];
#pragma unroll
    for (int fn = 0; fn < 8; ++fn)
      colm[fn] = kmask[b * MK + wn * 128 + fn * 16 + lr];
#pragma unroll
    for (int fm = 0; fm < 2; ++fm)
#pragma unroll
      for (int r = 0; r < 4; ++r) {
        float rm = mask[(size_t)b * Nn + by * 128 + wm * 32 + fm * 16 + lg * 4 + r];
#pragma unroll
        for (int fn = 0; fn < 8; ++fn)
          acc[fm][fn][r] = (rm * colm[fn] < 0.5f) ? NEGV : acc[fm][fn][r] * SCALE;
      }
  }
  float mx[2][4];
#pragma unroll
  for (int fm = 0; fm < 2; ++fm)
#pragma unroll
    for (int r = 0; r < 4; ++r) {
      float m = -3.4e38f;
#pragma unroll
      for (int fn = 0; fn < 8; ++fn) m = fmaxf(m, acc[fm][fn][r]);
#pragma unroll
      for (int o = 8; o; o >>= 1) m = fmaxf(m, __shfl_xor(m, o));
      mx[fm][r] = m;
    }
  __syncthreads();
  if (lr == 0) {
#pragma unroll
    for (int fm = 0; fm < 2; ++fm)
#pragma unroll
      for (int r = 0; r < 4; ++r)
        red[(wm * 32 + fm * 16 + lg * 4 + r) * 2 + wn] = mx[fm][r];
  }
  __syncthreads();
#pragma unroll
  for (int fm = 0; fm < 2; ++fm)
#pragma unroll
    for (int r = 0; r < 4; ++r) {
      int row = wm * 32 + fm * 16 + lg * 4 + r;
      mx[fm][r] = fmaxf(red[row * 2], red[row * 2 + 1]);
    }
  float s1[2][4], s24[2][4];
#pragma unroll
  for (int fm = 0; fm < 2; ++fm)
#pragma unroll
    for (int r = 0; r < 4; ++r) {
      float a1 = 0.f, a24 = 0.f;
#pragma unroll
      for (int fn = 0; fn < 8; ++fn) {
        float e1 = __expf(acc[fm][fn][r] - mx[fm][r]);
        acc[fm][fn][r] = e1;
        a1 += e1;
        a24 += pow24(e1);
      }
#pragma unroll
      for (int o = 8; o; o >>= 1) { a1 += __shfl_xor(a1, o); a24 += __shfl_xor(a24, o); }
      s1[fm][r] = a1; s24[fm][r] = a24;
    }
  __syncthreads();
  if (lr == 0) {
#pragma unroll
    for (int fm = 0; fm < 2; ++fm)
#pragma unroll
      for (int r = 0; r < 4; ++r) {
        int row = wm * 32 + fm * 16 + lg * 4 + r;
        red2[row * 4 + wn * 2]     = s1[fm][r];
        red2[row * 4 + wn * 2 + 1] = s24[fm][r];
      }
  }
  __syncthreads();
#pragma unroll
  for (int fm = 0; fm < 2; ++fm)
#pragma unroll
    for (int r = 0; r < 4; ++r) {
      int row = wm * 32 + fm * 16 + lg * 4 + r;
      s1[fm][r]  = 1.f / (red2[row * 4] + red2[row * 4 + 2]);
      s24[fm][r] = 1.f / (red2[row * 4 + 1] + red2[row * 4 + 3]);
    }
#pragma unroll
  for (int fm = 0; fm < 2; ++fm) {
#pragma unroll
    for (int r = 0; r < 4; ++r) {
      int m = by * 128 + wm * 32 + fm * 16 + lg * 4 + r;
      const float* rp = rdT + ((size_t)b * Nn + m) * MK;
      size_t obase = ((size_t)bh * Nn + m) * MK;
#pragma unroll
      for (int fn = 0; fn < 8; ++fn) {
        int n = wn * 128 + fn * 16 + lr;
        float e1 = acc[fm][fn][r];
        float rv = rp[n];
        P1[obase + n]  = __float2bfloat16(e1 * s1[fm][r] * rv);
        E24[obase + n] = __float2bfloat16(pow24(e1) * s24[fm][r] * rv);
      }
    }
  }
}

// ---------------- fused k-path score GEMM + softmax ----------------
__global__ __launch_bounds__(256)
void score_sk_kernel(const short* __restrict__ Qk, const short* __restrict__ Kt,
                     const float* __restrict__ mask, const float* __restrict__ kmask,
                     const float* __restrict__ rd, __hip_bfloat16* __restrict__ P2) {
  __shared__ __align__(16) short As[16 * 64];
  __shared__ __align__(16) short Bs[256 * 64];
  __shared__ float redm[16 * 4];
  __shared__ float reds[16 * 4];
  const int tid = threadIdx.x, l = tid & 63, w = tid >> 6;
  const int lr = l & 15, lg = l >> 4;
  const int bh = blockIdx.x, j0 = blockIdx.y * 16, b = bh >> 3;
  const short* Ab = Qk + ((size_t)bh * MK + j0) * 64;
  const short* Bb = Kt + (size_t)bh * Nn * 64;
  f32x4 acc[32];
#pragma unroll
  for (int q = 0; q < 32; ++q) acc[q] = f32x4{0.f, 0.f, 0.f, 0.f};
  if (tid < 128) {
    int r = tid >> 3, c = tid & 7;
    gload16(Ab + (size_t)r * 64 + ((c ^ (r & 7)) * 8), As + tid * 8);
  }
#pragma unroll
  for (int nc = 0; nc < 8; ++nc) {
    __syncthreads();
#pragma unroll
    for (int it = 0; it < 8; ++it) {
      int idx = tid + it * 256, r = idx >> 3, c = idx & 7;
      gload16(Bb + (size_t)(nc * 256 + r) * 64 + ((c ^ (r & 7)) * 8), Bs + idx * 8);
    }
    __syncthreads();
#pragma unroll
    for (int ks = 0; ks < 2; ++ks) {
      short8 a;
      {
        int ch = (ks * 4 + lg) ^ (lr & 7);
        a = *reinterpret_cast<const short8*>(As + lr * 64 + ch * 8);
      }
#pragma unroll
      for (int fn = 0; fn < 4; ++fn) {
        int rn = w * 64 + fn * 16 + lr;
        int ch = (ks * 4 + lg) ^ (rn & 7);
        short8 bv = *reinterpret_cast<const short8*>(Bs + rn * 64 + ch * 8);
        acc[nc * 4 + fn] =
            __builtin_amdgcn_mfma_f32_16x16x32_bf16(a, bv, acc[nc * 4 + fn], 0, 0, 0);
      }
    }
  }
  float rm[4];
#pragma unroll
  for (int rr = 0; rr < 4; ++rr) rm[rr] = kmask[b * MK + j0 + lg * 4 + rr];
  float mx[4] = {-3.4e38f, -3.4e38f, -3.4e38f, -3.4e38f};
#pragma unroll
  for (int q = 0; q < 32; ++q) {
    int n = (q >> 2) * 256 + w * 64 + (q & 3) * 16 + lr;
    float cm = mask[(size_t)b * Nn + n];
#pragma unroll
    for (int rr = 0; rr < 4; ++rr) {
      float v = (rm[rr] * cm < 0.5f) ? NEGV : acc[q][rr] * SCALE;
      acc[q][rr] = v;
      mx[rr] = fmaxf(mx[rr], v);
    }
  }
#pragma unroll
  for (int o = 8; o; o >>= 1)
#pragma unroll
    for (int rr = 0; rr < 4; ++rr) mx[rr] = fmaxf(mx[rr], __shfl_xor(mx[rr], o));
  __syncthreads();
  if (lr == 0) {
#pragma unroll
    for (int rr = 0; rr < 4; ++rr) redm[(lg * 4 + rr) * 4 + w] = mx[rr];
  }
  __syncthreads();
#pragma unroll
  for (int rr = 0; rr < 4; ++rr) {
    int row = lg * 4 + rr;
    mx[rr] = fmaxf(fmaxf(redm[row * 4], redm[row * 4 + 1]),
                   fmaxf(redm[row * 4 + 2], redm[row * 4 + 3]));
  }
  float sm[4] = {0.f, 0.f, 0.f, 0.f};
#pragma unroll
  for (int q = 0; q < 32; ++q)
#pragma unroll
    for (int rr = 0; rr < 4; ++rr) {
      float e = __expf(acc[q][rr] - mx[rr]);
      acc[q][rr] = e;
      sm[rr] += e;
    }
#pragma unroll
  for (int o = 8; o; o >>= 1)
#pragma unroll
    for (int rr = 0; rr < 4; ++rr) sm[rr] += __shfl_xor(sm[rr], o);
  __syncthreads();
  if (lr == 0) {
#pragma unroll
    for (int rr = 0; rr < 4; ++rr) reds[(lg * 4 + rr) * 4 + w] = sm[rr];
  }
  __syncthreads();
  float inv[4];
#pragma unroll
  for (int rr = 0; rr < 4; ++rr) {
    int row = lg * 4 + rr;
    inv[rr] = 1.f / (reds[row * 4] + reds[row * 4 + 1] + reds[row * 4 + 2] + reds[row * 4 + 3]);
  }
#pragma unroll
  for (int rr = 0; rr < 4; ++rr) {
    int j = j0 + lg * 4 + rr;
    const float* rp = rd + (size_t)(b * MK + j) * Nn;
    __hip_bfloat16* pp = P2 + ((size_t)bh * MK + j) * Nn;
#pragma unroll
    for (int q = 0; q < 32; ++q) {
      int n = (q >> 2) * 256 + w * 64 + (q & 3) * 16 + lr;
      pp[n] = __float2bfloat16(acc[q][rr] * inv[rr] * rp[n]);
    }
  }
}

// ---------------- atten transpose: E24 bf16 [bh][i][j] -> f32 [bh][j][i] ----------------
// grid (32, Nn/64); each block handles all 4 j-tiles of its (bh, i0) strip.
__global__ __launch_bounds__(256)
void at_tr_kernel(const __hip_bfloat16* __restrict__ E, float* __restrict__ atten) {
  __shared__ __hip_bfloat16 t[64][72];
  const int bh = blockIdx.x;
  const int i0 = blockIdx.y * 64;
  const int tid = threadIdx.x;
  for (int jt = 0; jt < 4; ++jt) {
    const int j0 = jt * 64;
    if (jt) __syncthreads();
#pragma unroll
    for (int it = 0; it < 2; ++it) {
      int idx = tid + it * 256, r = idx >> 3, c8 = (idx & 7) * 8;
      short8 v = *reinterpret_cast<const short8*>(
          (const short*)E + ((size_t)bh * Nn + i0 + r) * MK + j0 + c8);
#pragma unroll
      for (int e = 0; e < 8; ++e)
        *reinterpret_cast<short*>(&t[r][c8 + e]) = v[e];
    }
    __syncthreads();
#pragma unroll
    for (int it = 0; it < 4; ++it) {
      int idx = tid + it * 256, jr = idx >> 4, c4 = (idx & 15) * 4;
      float4 o;
      o.x = __bfloat162float(t[c4 + 0][jr]);
      o.y = __bfloat162float(t[c4 + 1][jr]);
      o.z = __bfloat162float(t[c4 + 2][jr]);
      o.w = __bfloat162float(t[c4 + 3][jr]);
      *reinterpret_cast<float4*>(
          atten + ((size_t)bh * MK + j0 + jr) * Nn + i0 + c4) = o;
    }
  }
}

// ---------------- rd transpose: [b][j][i] -> rdT [b][i][j] (runs once) ----------------
__global__ __launch_bounds__(256)
void rd_tr_kernel(const float* __restrict__ rd, float* __restrict__ rdT) {
  __shared__ float tb[64][65];
  const int b = blockIdx.x;
  const int i0 = blockIdx.y * 64, j0 = blockIdx.z * 64;
  const int tid = threadIdx.x;
#pragma unroll
  for (int it = 0; it < 4; ++it) {
    int idx = tid + it * 256, r = idx >> 4, c4 = (idx & 15) * 4;
    float4 v = ldf4(rd + ((size_t)(b * MK + j0 + r)) * Nn + i0 + c4);
    tb[r][c4 + 0] = v.x; tb[r][c4 + 1] = v.y; tb[r][c4 + 2] = v.z; tb[r][c4 + 3] = v.w;
  }
  __syncthreads();
#pragma unroll
  for (int it = 0; it < 4; ++it) {
    int idx = tid + it * 256, r = idx >> 4, c4 = (idx & 15) * 4;
    float4 o = make_float4(tb[c4 + 0][r], tb[c4 + 1][r], tb[c4 + 2][r], tb[c4 + 3][r]);
    *reinterpret_cast<float4*>(rdT + ((size_t)(b * Nn + i0 + r)) * MK + j0 + c4) = o;
  }
}

// ---------------- batched weight transpose: 8 matrices in one launch ----------------
struct WtArgs {
  const float* W[8];
  __hip_bfloat16* T[8];
  int K[8], N[8];
};
__global__ __launch_bounds__(256)
void wtrans_all_kernel(WtArgs a) {
  __shared__ float t[64][65];
  const int e = blockIdx.z;
  const int K = a.K[e], N = a.N[e];
  const int n0 = blockIdx.x * 64, k0 = blockIdx.y * 64;
  if (n0 >= N || k0 >= K) return;
  const float* W = a.W[e];
  __hip_bfloat16* WT = a.T[e];
  const int tid = threadIdx.x;
#pragma unroll
  for (int it = 0; it < 4; ++it) {
    int idx = tid + it * 256, r = idx >> 4, f = idx & 15;
    float4 v = ldf4(W + (size_t)(k0 + r) * N + n0 + f * 4);
    t[r][f * 4 + 0] = v.x; t[r][f * 4 + 1] = v.y;
    t[r][f * 4 + 2] = v.z; t[r][f * 4 + 3] = v.w;
  }
  __syncthreads();
#pragma unroll
  for (int it = 0; it < 4; ++it) {
    int idx = tid + it * 256, r = idx >> 4, c4 = (idx & 15) * 4;
    __hip_bfloat16* op = WT + (size_t)(n0 + r) * K + k0 + c4;
#pragma unroll
    for (int e2 = 0; e2 < 4; ++e2) op[e2] = __float2bfloat16(t[c4 + e2][r]);
  }
}

// ------------- cls-token attention: grid B*H, block 256, bf16 out -------------
__global__ __launch_bounds__(256)
void attn_c_kernel(const float* __restrict__ cqkv, const float* __restrict__ kqkv,
                   const float* __restrict__ mask, const float* __restrict__ kmask,
                   __hip_bfloat16* __restrict__ c_pre) {
  __shared__ __align__(16) float kv_s[MK][DH];
  __shared__ __align__(16) float q_s[DH];
  __shared__ float pbuf[MK];
  __shared__ float red8[8];
  __shared__ float redpv[4][DH];
  const int tid = threadIdx.x;
  const int bh = blockIdx.x, b = bh >> 3, h = bh & 7;
  const float* vp = kqkv + ((size_t)(b * MK + tid)) * QLD + 2 * Dd + h * DH;
#pragma unroll
  for (int q4 = 0; q4 < 16; ++q4)
    *reinterpret_cast<float4*>(&kv_s[tid][q4 * 4]) = ldf4(vp + q4 * 4);
  if (tid < DH) q_s[tid] = cqkv[(size_t)b * QLD + h * DH + tid];
  __syncthreads();
  const float* kp = kqkv + ((size_t)(b * MK + tid)) * QLD + Dd + h * DH;
  float dot = 0.f;
#pragma unroll
  for (int q4 = 0; q4 < 16; ++q4) {
    float4 kv4 = ldf4(kp + q4 * 4);
    float4 qv = ldf4(&q_s[q4 * 4]);
    dot = fmaf(qv.x, kv4.x, dot);
    dot = fmaf(qv.y, kv4.y, dot);
    dot = fmaf(qv.z, kv4.z, dot);
    dot = fmaf(qv.w, kv4.w, dot);
  }
  const float dm = (mask[(size_t)b * Nn] * kmask[b * MK + tid] < 0.5f) ? NEGV : dot * SCALE;
  const float mx = blockMax256(dm, red8);
  const float e = __expf(dm - mx);
  const float s = blockSum256(e, red8);
  pbuf[tid] = e / s;
  __syncthreads();
  const int d = tid & 63, g = tid >> 6;
  float acc = 0.f;
#pragma unroll 8
  for (int jj = 0; jj < 64; ++jj)
    acc = fmaf(pbuf[g * 64 + jj], kv_s[g * 64 + jj][d], acc);
  redpv[g][d] = acc;
  __syncthreads();
  if (tid < DH)
    c_pre[(size_t)b * Dd + h * DH + tid] = __float2bfloat16(
        redpv[0][tid] + redpv[1][tid] + redpv[2][tid] + redpv[3][tid]);
}

// ------------- output writers (float32 outputs) -------------
__global__ void kreps_kernel(const float* __restrict__ kx, const float* __restrict__ kmask,
                             float* __restrict__ o) {
  const int idx = blockIdx.x * 256 + threadIdx.x;
  const int bj = idx >> 9;
  const float keep = (kmask[bj] >= 0.5f) ? 1.f : 0.f;
  o[idx] = kx[idx] * keep;
}
__global__ void cout_kernel(const float* __restrict__ c_s, float* __restrict__ o) {
  const int idx = blockIdx.x * 256 + threadIdx.x;
  o[idx] = c_s[idx];
}

static GArgs ga_base() { GArgs g = {}; return g; }

extern "C" void kernel_launch(void* const* d_in, const int* in_sizes, int n_in,
                              void* d_out, int out_size, void* d_ws, size_t ws_size,
                              hipStream_t stream) {
  (void)in_sizes; (void)n_in; (void)out_size; (void)ws_size;
  const float* x_in  = (const float*)d_in[0];
  const float* kx_in = (const float*)d_in[1];
  const float* rd    = (const float*)d_in[2];
  const float* c_in  = (const float*)d_in[3];
  const float* mask  = (const float*)d_in[4];
  const float* kmask = (const float*)d_in[5];
  const float* ln1g  = (const float*)d_in[6];
  const float* ln1b  = (const float*)d_in[7];
  const float* Wqkv  = (const float*)d_in[8];
  const float* Woutw = (const float*)d_in[9];
  const float* boutw = (const float*)d_in[10];
  const float* ln2g  = (const float*)d_in[11];
  const float* ln2b  = (const float*)d_in[12];
  const float* W1    = (const float*)d_in[13];
  const float* b1    = (const float*)d_in[14];
  const float* W2    = (const float*)d_in[15];
  const float* b2    = (const float*)d_in[16];
  float* out = (float*)d_out;

  float* ws = (float*)d_ws;
  size_t off = 0;
  auto alloc = [&](size_t n) { float* p = ws + off; off += (n + 15) & ~(size_t)15; return p; };
  float* xcat_s    = alloc((size_t)NTOK * Dd);
  float* xcat_nb_f = alloc((size_t)NTOK * Dd / 2);
  float* pre_cat_f = alloc((size_t)NTOK * Dd / 2);
  float* qkv       = alloc((size_t)NTOK * QLD);     // hosts hid after attention
  float* P1_f      = alloc((size_t)32 * Nn * MK / 2);
  float* E24_f     = alloc((size_t)32 * Nn * MK / 2);
  float* P2_f      = alloc((size_t)32 * MK * Nn / 2);
  float* tq_s_f    = alloc((size_t)32 * Nn * 128 / 2);
  float* kk_s_f    = alloc((size_t)32 * MK * 128 / 2);
  float* tk_hi_f   = alloc((size_t)32 * Nn * 64 / 2);
  float* kq_hi_f   = alloc((size_t)32 * MK * 64 / 2);
  float* tvT_f     = alloc((size_t)32 * 64 * Nn / 2);
  float* kvT_f     = alloc((size_t)32 * 64 * MK / 2);
  float* rdT       = alloc((size_t)Bb * Nn * MK);
  float* WqkvT_f   = alloc((size_t)2 * QLD * Dd / 2);
  float* WoutT_f   = alloc((size_t)2 * Dd * Dd / 2);
  float* W1T_f     = alloc((size_t)2 * MLPD * Dd / 2);
  float* W2T_f     = alloc((size_t)2 * Dd * MLPD / 2);

  __hip_bfloat16* xcat_nb = (__hip_bfloat16*)xcat_nb_f;
  __hip_bfloat16* pre_cat = (__hip_bfloat16*)pre_cat_f;
  __hip_bfloat16* P1b     = (__hip_bfloat16*)P1_f;
  __hip_bfloat16* E24b    = (__hip_bfloat16*)E24_f;
  __hip_bfloat16* P2b     = (__hip_bfloat16*)P2_f;
  __hip_bfloat16* tq_s    = (__hip_bfloat16*)tq_s_f;
  __hip_bfloat16* kk_s    = (__hip_bfloat16*)kk_s_f;
  __hip_bfloat16* tk_hi   = (__hip_bfloat16*)tk_hi_f;
  __hip_bfloat16* kq_hi   = (__hip_bfloat16*)kq_hi_f;
  __hip_bfloat16* tvT     = (__hip_bfloat16*)tvT_f;
  __hip_bfloat16* kvT     = (__hip_bfloat16*)kvT_f;
  __hip_bfloat16* WqkvT   = (__hip_bfloat16*)WqkvT_f;
  __hip_bfloat16* WoutT   = (__hip_bfloat16*)WoutT_f;
  __hip_bfloat16* W1T     = (__hip_bfloat16*)W1T_f;
  __hip_bfloat16* W2T     = (__hip_bfloat16*)W2T_f;
  __hip_bfloat16* hid     = (__hip_bfloat16*)qkv;   // FF hidden overlay

  const size_t CL_OFF = (size_t)2 * Bb * MK * Dd;
  const size_t AT_OFF = CL_OFF + (size_t)Bb * Dd;

  // ---- upfront: input concat, rd transpose, all weight transposes ----
  copy3_kernel<<<(NTOK * 128) / 256, 256, 0, stream>>>(x_in, kx_in, c_in, xcat_s);
  rd_tr_kernel<<<dim3(Bb, Nn / 64, MK / 64), 256, 0, stream>>>(rd, rdT);
  {
    WtArgs a;
    for (int l = 0; l < 2; ++l) {
      a.W[l * 4 + 0] = Wqkv + (size_t)l * Dd * QLD;  a.T[l * 4 + 0] = WqkvT + (size_t)l * QLD * Dd;
      a.K[l * 4 + 0] = Dd;   a.N[l * 4 + 0] = QLD;
      a.W[l * 4 + 1] = Woutw + (size_t)l * Dd * Dd;  a.T[l * 4 + 1] = WoutT + (size_t)l * Dd * Dd;
      a.K[l * 4 + 1] = Dd;   a.N[l * 4 + 1] = Dd;
      a.W[l * 4 + 2] = W1 + (size_t)l * Dd * MLPD;   a.T[l * 4 + 2] = W1T + (size_t)l * MLPD * Dd;
      a.K[l * 4 + 2] = Dd;   a.N[l * 4 + 2] = MLPD;
      a.W[l * 4 + 3] = W2 + (size_t)l * MLPD * Dd;   a.T[l * 4 + 3] = W2T + (size_t)l * Dd * MLPD;
      a.K[l * 4 + 3] = MLPD; a.N[l * 4 + 3] = Dd;
    }
    wtrans_all_kernel<<<dim3(32, 32, 8), 256, 0, stream>>>(a);
  }

  for (int l = 0; l < 2; ++l) {
    const float* bo  = boutw + (size_t)l * Dd;
    const float* b1l = b1 + (size_t)l * MLPD;
    const float* b2l = b2 + (size_t)l * Dd;
    __hip_bfloat16* WqkvTl = WqkvT + (size_t)l * QLD * Dd;
    __hip_bfloat16* WoutTl = WoutT + (size_t)l * Dd * Dd;
    __hip_bfloat16* W1Tl   = W1T + (size_t)l * MLPD * Dd;
    __hip_bfloat16* W2Tl   = W2T + (size_t)l * Dd * MLPD;

    ln_kernel<<<NTOK, 64, 0, stream>>>(xcat_s, ln1g + l * Dd, ln1b + l * Dd, xcat_nb);

    // QKV: one GEMM over all 9220 rows
    {
      GArgs g = ga_base();
      g.A = (const short*)xcat_nb; g.lda = Dd;
      g.Bt = (const short*)WqkvTl; g.ldb = Dd;
      g.C = qkv; g.ldc = QLD;
      g.M = NTOK; g.N = QLD; g.K = Dd;
      launch_mgemm<128, 128, 0>(g, 1, stream);
    }

    prep_attn_kernel<<<5760, 256, 0, stream>>>(
        qkv, qkv + (size_t)KXOFF * QLD, tq_s, tk_hi, kq_hi, kk_s, tvT, kvT);

    attn_c_kernel<<<Bb * Hh, 256, 0, stream>>>(qkv + (size_t)CLOFF * QLD,
                                               qkv + (size_t)KXOFF * QLD, mask, kmask,
                                               pre_cat + (size_t)CLOFF * Dd);

    // ---- x-path: fused score+softmax -> atten transpose -> PV ----
    score_sx_kernel<<<dim3(Nn / 128, 32), 512, 0, stream>>>(
        (const short*)tq_s, (const short*)kk_s, mask, kmask, rdT, P1b, E24b);
    at_tr_kernel<<<dim3(32, Nn / 64), 256, 0, stream>>>(
        E24b, out + AT_OFF + (size_t)l * 32 * MK * Nn);
    {
      GArgs g = ga_base();
      g.A = (const short*)P1b; g.asb = (long)Nn * MK; g.lda = MK;
      g.Bt = (const short*)kvT; g.bsb = (long)64 * MK; g.ldb = MK;
      g.Cb = pre_cat; g.czo = (long)Nn * Dd; g.czi = 64; g.ldc = Dd;
      g.M = Nn; g.N = 64; g.K = MK;
      launch_mgemm<128, 64, 4>(g, 32, stream);
    }
    // ---- k-path: fused score+softmax -> PV ----
    score_sk_kernel<<<dim3(32, MK / 16), 256, 0, stream>>>(
        (const short*)kq_hi, (const short*)tk_hi, mask, kmask, rd, P2b);
    {
      GArgs g = ga_base();
      g.A = (const short*)P2b; g.asb = (long)MK * Nn; g.lda = Nn;
      g.Bt = (const short*)tvT; g.bsb = (long)64 * Nn; g.ldb = Nn;
      g.Cb = pre_cat + (size_t)KXOFF * Dd; g.czo = (long)MK * Dd; g.czi = 64; g.ldc = Dd;
      g.M = MK; g.N = 64; g.K = Nn;
      launch_mgemm<64, 64, 4>(g, 32, stream);
    }

    // ---- Wout + bf16 residual over all rows ----
    {
      GArgs g = ga_base();
      g.A = (const short*)pre_cat; g.lda = Dd;
      g.Bt = (const short*)WoutTl; g.ldb = Dd;
      g.C = xcat_s; g.ldc = Dd; g.bias = bo; g.resb = xcat_nb; g.ldr = Dd;
      g.M = NTOK; g.N = Dd; g.K = Dd;
      launch_mgemm<128, 64, 5>(g, 1, stream);
    }

    // ---- FF over all rows ----
    ln_kernel<<<NTOK, 64, 0, stream>>>(xcat_s, ln2g + l * Dd, ln2b + l * Dd, xcat_nb);
    {
      GArgs g = ga_base();
      g.A = (const short*)xcat_nb; g.lda = Dd;
      g.Bt = (const short*)W1Tl; g.ldb = Dd;
      g.Cb = hid; g.ldc = MLPD; g.bias = b1l;
      g.M = NTOK; g.N = MLPD; g.K = Dd;
      launch_mgemm<128, 128, 3>(g, 1, stream);
      GArgs h = ga_base();
      h.A = (const short*)hid; h.lda = MLPD;
      h.Bt = (const short*)W2Tl; h.ldb = MLPD;
      h.C = xcat_s; h.ldc = Dd; h.bias = b2l; h.res = xcat_s; h.ldr = Dd;
      h.M = NTOK; h.N = Dd; h.K = MLPD;
      launch_mgemm<128, 64, 2>(h, 1, stream);
    }

    kreps_kernel<<<(Bb * MK * Dd) / 256, 256, 0, stream>>>(
        xcat_s + (size_t)KXOFF * Dd, kmask, out + (size_t)l * Bb * MK * Dd);
  }
  cout_kernel<<<(Bb * Dd) / 256, 256, 0, stream>>>(xcat_s + (size_t)CLOFF * Dd, out + CL_OFF);
}

// Round 14
// 687.946 us; speedup vs baseline: 1.5101x; 1.0649x over previous
//
#include <hip/hip_runtime.h>
#include <hip/hip_bf16.h>
#include <cstddef>

#define DEV __device__ __forceinline__

constexpr int Bb  = 4;
constexpr int Nn  = 2048;
constexpr int MK  = 256;
constexpr int Dd  = 512;
constexpr int Hh  = 8;
constexpr int DH  = 64;
constexpr int QLD = 1536;   // qkv row stride (3*512)
constexpr int MLPD = 2048;
constexpr int NTOK = Bb * Nn + Bb * MK + Bb;   // 9220 concatenated rows
constexpr int KXOFF = Bb * Nn;                 // 8192: first kx row
constexpr int CLOFF = Bb * Nn + Bb * MK;       // 9216: first cls row
constexpr float SCALE = 0.125f;   // 64^-0.5
constexpr float NEGV  = -1e9f;

typedef __attribute__((ext_vector_type(8))) short short8;
typedef __attribute__((ext_vector_type(4))) float f32x4;

DEV float4 ldf4(const float* p) { return *reinterpret_cast<const float4*>(p); }

// async global->LDS, 16B per lane, linear LDS dest
DEV void gload16(const short* g, short* l) {
  __builtin_amdgcn_global_load_lds(
      (const __attribute__((address_space(1))) void*)g,
      (__attribute__((address_space(3))) void*)l, 16, 0, 0);
}

DEV float waveMax(float v) {
#pragma unroll
  for (int o = 32; o; o >>= 1) v = fmaxf(v, __shfl_xor(v, o));
  return v;
}
DEV float waveSum(float v) {
#pragma unroll
  for (int o = 32; o; o >>= 1) v += __shfl_xor(v, o);
  return v;
}
DEV float blockMax256(float v, float* red) {
  v = waveMax(v);
  __syncthreads();
  if ((threadIdx.x & 63) == 0) red[threadIdx.x >> 6] = v;
  __syncthreads();
  return fmaxf(fmaxf(red[0], red[1]), fmaxf(red[2], red[3]));
}
DEV float blockSum256(float v, float* red) {
  v = waveSum(v);
  __syncthreads();
  if ((threadIdx.x & 63) == 0) red[threadIdx.x >> 6] = v;
  __syncthreads();
  return red[0] + red[1] + red[2] + red[3];
}
DEV float gelu_f(float x) { return 0.5f * x * (1.f + erff(x * 0.70710678118654752f)); }
// exact: e1^24 (5 multiplies)
DEV float pow24(float e1) {
  float e2 = e1 * e1, e4 = e2 * e2, e8 = e4 * e4, e16 = e8 * e8;
  return e16 * e8;
}

// ---------------- input concat copy: {x, kx, cls} -> xcat_s ----------------
__global__ __launch_bounds__(256)
void copy3_kernel(const float* __restrict__ x, const float* __restrict__ kx,
                  const float* __restrict__ c, float* __restrict__ dst) {
  const int idx = blockIdx.x * 256 + threadIdx.x;   // float4 index
  const int row = idx >> 7;
  float4 v;
  if (row < KXOFF) v = ldf4(x + (size_t)idx * 4);
  else if (row < CLOFF) v = ldf4(kx + (size_t)idx * 4 - (size_t)KXOFF * Dd);
  else v = ldf4(c + (size_t)idx * 4 - (size_t)CLOFF * Dd);
  *reinterpret_cast<float4*>(dst + (size_t)idx * 4) = v;
}

// ---------------- LayerNorm: one wave per 512-float row, bf16 out ----------------
__global__ __launch_bounds__(64)
void ln_kernel(const float* __restrict__ in, const float* __restrict__ gw,
               const float* __restrict__ bw, __hip_bfloat16* __restrict__ outb) {
  const int row = blockIdx.x;
  const int t = threadIdx.x;
  const float* p = in + (size_t)row * Dd + t * 8;
  float4 v0 = ldf4(p), v1 = ldf4(p + 4);
  float s = v0.x + v0.y + v0.z + v0.w + v1.x + v1.y + v1.z + v1.w;
  float q = v0.x*v0.x + v0.y*v0.y + v0.z*v0.z + v0.w*v0.w
          + v1.x*v1.x + v1.y*v1.y + v1.z*v1.z + v1.w*v1.w;
  s = waveSum(s); q = waveSum(q);
  const float mu = s * (1.f / Dd);
  const float rstd = rsqrtf(fmaxf(q * (1.f / Dd) - mu * mu, 0.f) + 1e-5f);
  float4 g0 = ldf4(gw + t * 8), g1 = ldf4(gw + t * 8 + 4);
  float4 b0 = ldf4(bw + t * 8), b1 = ldf4(bw + t * 8 + 4);
  float o[8];
  o[0] = (v0.x - mu) * rstd * g0.x + b0.x;
  o[1] = (v0.y - mu) * rstd * g0.y + b0.y;
  o[2] = (v0.z - mu) * rstd * g0.z + b0.z;
  o[3] = (v0.w - mu) * rstd * g0.w + b0.w;
  o[4] = (v1.x - mu) * rstd * g1.x + b1.x;
  o[5] = (v1.y - mu) * rstd * g1.y + b1.y;
  o[6] = (v1.z - mu) * rstd * g1.z + b1.z;
  o[7] = (v1.w - mu) * rstd * g1.w + b1.w;
  __hip_bfloat16* ob = outb + (size_t)row * Dd + t * 8;
#pragma unroll
  for (int e = 0; e < 8; ++e) ob[e] = __float2bfloat16(o[e]);
}

// ---------------- bf16 MFMA GEMM ----------------
// Single-buffered (32 KB LDS), source-pre-swizzled staging, XCD swizzle.
// EPI: 0 = f32 write; 3 = +bias, gelu, bf16; 4 = bf16;
//      2 = +bias + f32 res, f32 write; 5 = +bias + bf16 res, f32 write.
struct GArgs {
  const short* A;  long asb; int lda;
  const short* Bt; long bsb; int ldb;
  float* C; __hip_bfloat16* Cb;
  long czo, czi; int ldc;
  const float* bias;
  const float* res; const __hip_bfloat16* resb; int ldr;
  int M, N, K;
};

template<int BM, int BN, int EPI>
__global__ __launch_bounds__(256)
void mgemm(GArgs g) {
  constexpr int WMW = (BN >= 128) ? 2 : 4;
  constexpr int WNW = 4 / WMW;
  constexpr int WM = BM / WMW, WN = BN / WNW;
  constexpr int FM = WM / 16, FN = WN / 16;
  __shared__ __align__(16) short As[BM * 64];
  __shared__ __align__(16) short Bs[BN * 64];
  const int tid = threadIdx.x, l = tid & 63, w = tid >> 6;
  const int wm = (WNW == 2) ? (w >> 1) : w;
  const int wn = (WNW == 2) ? (w & 1) : 0;
  int bx = blockIdx.x, by = blockIdx.y;
  {  // bijective XCD swizzle (m204)
    const int gx = gridDim.x, nwg = gx * gridDim.y;
    const int orig = by * gx + bx;
    const int xcd = orig & 7, pos = orig >> 3;
    const int q = nwg >> 3, rmd = nwg & 7;
    const int s = (xcd < rmd ? xcd * (q + 1) : rmd * (q + 1) + (xcd - rmd) * q) + pos;
    bx = s % gx; by = s / gx;
  }
  const int z = blockIdx.z;
  const short* Ab = g.A + (size_t)z * g.asb;
  const short* Bb_ = g.Bt + (size_t)z * g.bsb;
  f32x4 acc[FM][FN] = {};
  const int lr = l & 15, lg = l >> 4;

  for (int k0 = 0; k0 < g.K; k0 += 64) {
    __syncthreads();
#pragma unroll
    for (int it = 0; it < BM / 32; ++it) {
      int idx = tid + it * 256, r = idx >> 3, c = idx & 7;
      int gm = by * BM + r;
      if (gm >= g.M) gm = g.M - 1;   // clamp; rows independent, masked at write
      gload16(Ab + (size_t)gm * g.lda + k0 + ((c ^ (r & 7)) * 8), As + idx * 8);
    }
#pragma unroll
    for (int it = 0; it < BN / 32; ++it) {
      int idx = tid + it * 256, r = idx >> 3, c = idx & 7;
      int gn = bx * BN + r;
      gload16(Bb_ + (size_t)gn * g.ldb + k0 + ((c ^ (r & 7)) * 8), Bs + idx * 8);
    }
    __syncthreads();
#pragma unroll
    for (int ks = 0; ks < 2; ++ks) {
      short8 a[FM], b[FN];
#pragma unroll
      for (int fm = 0; fm < FM; ++fm) {
        int rr = wm * WM + fm * 16 + lr;
        int ch = (ks * 4 + lg) ^ (rr & 7);
        a[fm] = *reinterpret_cast<const short8*>(As + rr * 64 + ch * 8);
      }
#pragma unroll
      for (int fn = 0; fn < FN; ++fn) {
        int rn = wn * WN + fn * 16 + lr;
        int ch = (ks * 4 + lg) ^ (rn & 7);
        b[fn] = *reinterpret_cast<const short8*>(Bs + rn * 64 + ch * 8);
      }
#pragma unroll
      for (int fm = 0; fm < FM; ++fm)
#pragma unroll
        for (int fn = 0; fn < FN; ++fn)
          acc[fm][fn] = __builtin_amdgcn_mfma_f32_16x16x32_bf16(a[fm], b[fn], acc[fm][fn], 0, 0, 0);
    }
  }

  const size_t zoff = (size_t)(z >> 3) * g.czo + (size_t)(z & 7) * g.czi;
#pragma unroll
  for (int fm = 0; fm < FM; ++fm) {
#pragma unroll
    for (int fn = 0; fn < FN; ++fn) {
#pragma unroll
      for (int r = 0; r < 4; ++r) {
        int m = by * BM + wm * WM + fm * 16 + lg * 4 + r;
        int n = bx * BN + wn * WN + fn * 16 + lr;
        if (m >= g.M) continue;
        float v = acc[fm][fn][r];
        size_t coff = zoff + (size_t)m * g.ldc + n;
        if (EPI == 0) {
          g.C[coff] = v;
        } else if (EPI == 2) {
          v += g.bias[n] + g.res[(size_t)m * g.ldr + n];
          g.C[coff] = v;
        } else if (EPI == 5) {
          v += g.bias[n] + __bfloat162float(g.resb[(size_t)m * g.ldr + n]);
          g.C[coff] = v;
        } else if (EPI == 3) {
          v = gelu_f(v + g.bias[n]);
          g.Cb[coff] = __float2bfloat16(v);
        } else {
          g.Cb[coff] = __float2bfloat16(v);
        }
      }
    }
  }
}

template<int BM, int BN, int EPI>
static void launch_mgemm(const GArgs& g, int zdim, hipStream_t s) {
  dim3 grid((g.N + BN - 1) / BN, (g.M + BM - 1) / BM, zdim);
  mgemm<BM, BN, EPI><<<grid, 256, 0, s>>>(g);
}

// ---------------- fused attention prep: splits + v transposes in one launch ----------------
__global__ __launch_bounds__(256)
void prep_attn_kernel(const float* __restrict__ qkv_x, const float* __restrict__ qkv_k,
                      __hip_bfloat16* __restrict__ tq_s, __hip_bfloat16* __restrict__ tk_hi,
                      __hip_bfloat16* __restrict__ kq_hi, __hip_bfloat16* __restrict__ kk_s,
                      __hip_bfloat16* __restrict__ tvT, __hip_bfloat16* __restrict__ kvT) {
  __shared__ float t[64][65];
  const int blk = blockIdx.x, tid = threadIdx.x;
  if (blk < 4096 + 512) {
    const bool isX = blk < 4096;
    const int T = isX ? Nn : MK;
    const float* qkv = isX ? qkv_x : qkv_k;
    const int idx = (isX ? blk : blk - 4096) * 256 + tid;
    const int token = idx >> 7, c8 = (idx & 127) * 8;
    const int b = token / T, i = token - b * T;
    const float* p = qkv + (size_t)token * QLD + c8;
    float v[8];
    float4 a = ldf4(p), c = ldf4(p + 4);
    v[0]=a.x; v[1]=a.y; v[2]=a.z; v[3]=a.w; v[4]=c.x; v[5]=c.y; v[6]=c.z; v[7]=c.w;
    if (c8 < 512) {
      int h = c8 >> 6, d = c8 & 63;
      if (isX) {
        __hip_bfloat16* q = tq_s + ((size_t)((b * 8 + h) * T + i)) * 128 + d;
#pragma unroll
        for (int e = 0; e < 8; ++e) {
          __hip_bfloat16 hi = __float2bfloat16(v[e]);
          q[e] = hi;
          q[64 + e] = __float2bfloat16(v[e] - __bfloat162float(hi));
        }
      } else {
        __hip_bfloat16* q = kq_hi + ((size_t)((b * 8 + h) * T + i)) * 64 + d;
#pragma unroll
        for (int e = 0; e < 8; ++e) q[e] = __float2bfloat16(v[e]);
      }
    } else {
      int cc = c8 - 512, h = cc >> 6, d = cc & 63;
      if (isX) {
        __hip_bfloat16* k = tk_hi + ((size_t)((b * 8 + h) * T + i)) * 64 + d;
#pragma unroll
        for (int e = 0; e < 8; ++e) k[e] = __float2bfloat16(v[e]);
      } else {
        __hip_bfloat16* k = kk_s + ((size_t)((b * 8 + h) * T + i)) * 128 + d;
#pragma unroll
        for (int e = 0; e < 8; ++e) {
          __hip_bfloat16 hi = __float2bfloat16(v[e]);
          k[e] = hi;
          k[64 + e] = __float2bfloat16(v[e] - __bfloat162float(hi));
        }
      }
    }
    return;
  }
  const bool isX = blk < 5632;
  const int r = isX ? blk - 4608 : blk - 5632;
  const int T = isX ? Nn : MK;
  const int tilesPerBh = T / 64;
  const int bh = r / tilesPerBh, i0 = (r % tilesPerBh) * 64;
  const int b = bh >> 3, h = bh & 7;
  const float* qkv = isX ? qkv_x : qkv_k;
  __hip_bfloat16* vT = isX ? tvT : kvT;
#pragma unroll
  for (int it = 0; it < 4; ++it) {
    int idx = tid + it * 256, rr = idx >> 4, f = idx & 15;
    float4 v = ldf4(qkv + (size_t)(b * T + i0 + rr) * QLD + 2 * Dd + h * 64 + f * 4);
    t[rr][f * 4 + 0] = v.x; t[rr][f * 4 + 1] = v.y;
    t[rr][f * 4 + 2] = v.z; t[rr][f * 4 + 3] = v.w;
  }
  __syncthreads();
#pragma unroll
  for (int it = 0; it < 4; ++it) {
    int idx = tid + it * 256, d = idx >> 4, c4 = (idx & 15) * 4;
    __hip_bfloat16* op = vT + (size_t)(bh * 64 + d) * T + i0 + c4;
#pragma unroll
    for (int e = 0; e < 4; ++e) op[e] = __float2bfloat16(t[c4 + e][d]);
  }
}

// ---------------- fused x-path score GEMM + dual softmax + atten transpose ----------------
// grid (Nn/128, 32), 512 threads. Writes P1 bf16 and atten f32 (transposed) directly.
__global__ __launch_bounds__(512)
void score_sx_kernel(const short* __restrict__ Q, const short* __restrict__ Km,
                     const float* __restrict__ mask, const float* __restrict__ kmask,
                     const float* __restrict__ rdT,
                     __hip_bfloat16* __restrict__ P1, float* __restrict__ atten) {
  __shared__ __align__(16) char smem[49152];   // As(16K) | Bs(32K); reused as tb f32[256][33]
  short* As = (short*)smem;
  short* Bs = (short*)(smem + 16384);
  float* tb = (float*)smem;
  __shared__ float red[128 * 2];
  __shared__ float red2[128 * 4];
  const int tid = threadIdx.x, l = tid & 63, w = tid >> 6;
  const int wm = w >> 1, wn = w & 1;
  const int by = blockIdx.x, bh = blockIdx.y;
  const int b = bh >> 3;
  const short* Ab = Q + (size_t)bh * Nn * 128;
  const short* Bb = Km + (size_t)bh * MK * 128;
  const int lr = l & 15, lg = l >> 4;
  f32x4 acc[2][8] = {};

  for (int k0 = 0; k0 < 128; k0 += 64) {
    __syncthreads();
#pragma unroll
    for (int it = 0; it < 2; ++it) {
      int idx = tid + it * 512, r = idx >> 3, c = idx & 7;
      gload16(Ab + (size_t)(by * 128 + r) * 128 + k0 + ((c ^ (r & 7)) * 8), As + idx * 8);
    }
#pragma unroll
    for (int it = 0; it < 4; ++it) {
      int idx = tid + it * 512, r = idx >> 3, c = idx & 7;
      gload16(Bb + (size_t)r * 128 + k0 + ((c ^ (r & 7)) * 8), Bs + idx * 8);
    }
    __syncthreads();
#pragma unroll
    for (int ks = 0; ks < 2; ++ks) {
      short8 a[2], bv[8];
#pragma unroll
      for (int fm = 0; fm < 2; ++fm) {
        int rr = wm * 32 + fm * 16 + lr;
        int ch = (ks * 4 + lg) ^ (rr & 7);
        a[fm] = *reinterpret_cast<const short8*>(As + rr * 64 + ch * 8);
      }
#pragma unroll
      for (int fn = 0; fn < 8; ++fn) {
        int rn = wn * 128 + fn * 16 + lr;
        int ch = (ks * 4 + lg) ^ (rn & 7);
        bv[fn] = *reinterpret_cast<const short8*>(Bs + rn * 64 + ch * 8);
      }
#pragma unroll
      for (int fm = 0; fm < 2; ++fm)
#pragma unroll
        for (int fn = 0; fn < 8; ++fn)
          acc[fm][fn] = __builtin_amdgcn_mfma_f32_16x16x32_bf16(a[fm], bv[fn], acc[fm][fn], 0, 0, 0);
    }
  }
  // mask + scale in place
  {
    float colm[8];
#pragma unroll
    for (int fn = 0; fn < 8; ++fn)
      colm[fn] = kmask[b * MK + wn * 128 + fn * 16 + lr];
#pragma unroll
    for (int fm = 0; fm < 2; ++fm)
#pragma unroll
      for (int r = 0; r < 4; ++r) {
        float rm = mask[(size_t)b * Nn + by * 128 + wm * 32 + fm * 16 + lg * 4 + r];
#pragma unroll
        for (int fn = 0; fn < 8; ++fn)
          acc[fm][fn][r] = (rm * colm[fn] < 0.5f) ? NEGV : acc[fm][fn][r] * SCALE;
      }
  }
  // row max: local frags -> 16-lane shfl -> cross-wave (wn) via LDS red[]
  float mx[2][4];
#pragma unroll
  for (int fm = 0; fm < 2; ++fm)
#pragma unroll
    for (int r = 0; r < 4; ++r) {
      float m = -3.4e38f;
#pragma unroll
      for (int fn = 0; fn < 8; ++fn) m = fmaxf(m, acc[fm][fn][r]);
#pragma unroll
      for (int o = 8; o; o >>= 1) m = fmaxf(m, __shfl_xor(m, o));
      mx[fm][r] = m;
    }
  __syncthreads();
  if (lr == 0) {
#pragma unroll
    for (int fm = 0; fm < 2; ++fm)
#pragma unroll
      for (int r = 0; r < 4; ++r)
        red[(wm * 32 + fm * 16 + lg * 4 + r) * 2 + wn] = mx[fm][r];
  }
  __syncthreads();
#pragma unroll
  for (int fm = 0; fm < 2; ++fm)
#pragma unroll
    for (int r = 0; r < 4; ++r) {
      int row = wm * 32 + fm * 16 + lg * 4 + r;
      mx[fm][r] = fmaxf(red[row * 2], red[row * 2 + 1]);
    }
  // single exp per element: store e1 in acc; e24 via 5 mults
  float s1[2][4], s24[2][4];
#pragma unroll
  for (int fm = 0; fm < 2; ++fm)
#pragma unroll
    for (int r = 0; r < 4; ++r) {
      float a1 = 0.f, a24 = 0.f;
#pragma unroll
      for (int fn = 0; fn < 8; ++fn) {
        float e1 = __expf(acc[fm][fn][r] - mx[fm][r]);
        acc[fm][fn][r] = e1;
        a1 += e1;
        a24 += pow24(e1);
      }
#pragma unroll
      for (int o = 8; o; o >>= 1) { a1 += __shfl_xor(a1, o); a24 += __shfl_xor(a24, o); }
      s1[fm][r] = a1; s24[fm][r] = a24;
    }
  __syncthreads();
  if (lr == 0) {
#pragma unroll
    for (int fm = 0; fm < 2; ++fm)
#pragma unroll
      for (int r = 0; r < 4; ++r) {
        int row = wm * 32 + fm * 16 + lg * 4 + r;
        red2[row * 4 + wn * 2]     = s1[fm][r];
        red2[row * 4 + wn * 2 + 1] = s24[fm][r];
      }
  }
  __syncthreads();
#pragma unroll
  for (int fm = 0; fm < 2; ++fm)
#pragma unroll
    for (int r = 0; r < 4; ++r) {
      int row = wm * 32 + fm * 16 + lg * 4 + r;
      s1[fm][r]  = 1.f / (red2[row * 4] + red2[row * 4 + 2]);
      s24[fm][r] = 1.f / (red2[row * 4 + 1] + red2[row * 4 + 3]);
    }
  // P1 write; convert acc to final atten value e24*rv (registers)
#pragma unroll
  for (int fm = 0; fm < 2; ++fm) {
#pragma unroll
    for (int r = 0; r < 4; ++r) {
      int m = by * 128 + wm * 32 + fm * 16 + lg * 4 + r;
      const float* rp = rdT + ((size_t)b * Nn + m) * MK;
      size_t obase = ((size_t)bh * Nn + m) * MK;
#pragma unroll
      for (int fn = 0; fn < 8; ++fn) {
        int n = wn * 128 + fn * 16 + lr;
        float e1 = acc[fm][fn][r];
        float rv = rp[n];
        P1[obase + n] = __float2bfloat16(e1 * s1[fm][r] * rv);
        acc[fm][fn][r] = pow24(e1) * s24[fm][r] * rv;
      }
    }
  }
  // atten transpose via LDS: 4 chunks of 32 i-rows; tb[256j][33]
  const int jw = tid >> 1, ipw = (tid & 1) * 16;
#pragma unroll
  for (int c = 0; c < 4; ++c) {
    __syncthreads();   // As/Bs dead (reductions synced); chunk c-1 reads done
    if (wm == c) {
#pragma unroll
      for (int fm = 0; fm < 2; ++fm)
#pragma unroll
        for (int r = 0; r < 4; ++r) {
          int mloc = fm * 16 + lg * 4 + r;
#pragma unroll
          for (int fn = 0; fn < 8; ++fn) {
            int n = wn * 128 + fn * 16 + lr;
            tb[n * 33 + mloc] = acc[fm][fn][r];
          }
        }
    }
    __syncthreads();
    // write atten[bh][j][by*128 + c*32 + 0..31]: 512 threads, 16 floats each
    float* op = atten + ((size_t)bh * MK + jw) * Nn + by * 128 + c * 32 + ipw;
    const float* tp = tb + jw * 33 + ipw;
#pragma unroll
    for (int e = 0; e < 4; ++e)
      *reinterpret_cast<float4*>(op + e * 4) =
          make_float4(tp[e * 4], tp[e * 4 + 1], tp[e * 4 + 2], tp[e * 4 + 3]);
  }
}

// ---------------- fused k-path score GEMM + softmax ----------------
__global__ __launch_bounds__(256)
void score_sk_kernel(const short* __restrict__ Qk, const short* __restrict__ Kt,
                     const float* __restrict__ mask, const float* __restrict__ kmask,
                     const float* __restrict__ rd, __hip_bfloat16* __restrict__ P2) {
  __shared__ __align__(16) short As[16 * 64];
  __shared__ __align__(16) short Bs[256 * 64];
  __shared__ float redm[16 * 4];
  __shared__ float reds[16 * 4];
  const int tid = threadIdx.x, l = tid & 63, w = tid >> 6;
  const int lr = l & 15, lg = l >> 4;
  const int bh = blockIdx.x, j0 = blockIdx.y * 16, b = bh >> 3;
  const short* Ab = Qk + ((size_t)bh * MK + j0) * 64;
  const short* Bb = Kt + (size_t)bh * Nn * 64;
  f32x4 acc[32];
#pragma unroll
  for (int q = 0; q < 32; ++q) acc[q] = f32x4{0.f, 0.f, 0.f, 0.f};
  if (tid < 128) {
    int r = tid >> 3, c = tid & 7;
    gload16(Ab + (size_t)r * 64 + ((c ^ (r & 7)) * 8), As + tid * 8);
  }
#pragma unroll
  for (int nc = 0; nc < 8; ++nc) {
    __syncthreads();
#pragma unroll
    for (int it = 0; it < 8; ++it) {
      int idx = tid + it * 256, r = idx >> 3, c = idx & 7;
      gload16(Bb + (size_t)(nc * 256 + r) * 64 + ((c ^ (r & 7)) * 8), Bs + idx * 8);
    }
    __syncthreads();
#pragma unroll
    for (int ks = 0; ks < 2; ++ks) {
      short8 a;
      {
        int ch = (ks * 4 + lg) ^ (lr & 7);
        a = *reinterpret_cast<const short8*>(As + lr * 64 + ch * 8);
      }
#pragma unroll
      for (int fn = 0; fn < 4; ++fn) {
        int rn = w * 64 + fn * 16 + lr;
        int ch = (ks * 4 + lg) ^ (rn & 7);
        short8 bv = *reinterpret_cast<const short8*>(Bs + rn * 64 + ch * 8);
        acc[nc * 4 + fn] =
            __builtin_amdgcn_mfma_f32_16x16x32_bf16(a, bv, acc[nc * 4 + fn], 0, 0, 0);
      }
    }
  }
  float rm[4];
#pragma unroll
  for (int rr = 0; rr < 4; ++rr) rm[rr] = kmask[b * MK + j0 + lg * 4 + rr];
  float mx[4] = {-3.4e38f, -3.4e38f, -3.4e38f, -3.4e38f};
#pragma unroll
  for (int q = 0; q < 32; ++q) {
    int n = (q >> 2) * 256 + w * 64 + (q & 3) * 16 + lr;
    float cm = mask[(size_t)b * Nn + n];
#pragma unroll
    for (int rr = 0; rr < 4; ++rr) {
      float v = (rm[rr] * cm < 0.5f) ? NEGV : acc[q][rr] * SCALE;
      acc[q][rr] = v;
      mx[rr] = fmaxf(mx[rr], v);
    }
  }
#pragma unroll
  for (int o = 8; o; o >>= 1)
#pragma unroll
    for (int rr = 0; rr < 4; ++rr) mx[rr] = fmaxf(mx[rr], __shfl_xor(mx[rr], o));
  __syncthreads();
  if (lr == 0) {
#pragma unroll
    for (int rr = 0; rr < 4; ++rr) redm[(lg * 4 + rr) * 4 + w] = mx[rr];
  }
  __syncthreads();
#pragma unroll
  for (int rr = 0; rr < 4; ++rr) {
    int row = lg * 4 + rr;
    mx[rr] = fmaxf(fmaxf(redm[row * 4], redm[row * 4 + 1]),
                   fmaxf(redm[row * 4 + 2], redm[row * 4 + 3]));
  }
  float sm[4] = {0.f, 0.f, 0.f, 0.f};
#pragma unroll
  for (int q = 0; q < 32; ++q)
#pragma unroll
    for (int rr = 0; rr < 4; ++rr) {
      float e = __expf(acc[q][rr] - mx[rr]);
      acc[q][rr] = e;
      sm[rr] += e;
    }
#pragma unroll
  for (int o = 8; o; o >>= 1)
#pragma unroll
    for (int rr = 0; rr < 4; ++rr) sm[rr] += __shfl_xor(sm[rr], o);
  __syncthreads();
  if (lr == 0) {
#pragma unroll
    for (int rr = 0; rr < 4; ++rr) reds[(lg * 4 + rr) * 4 + w] = sm[rr];
  }
  __syncthreads();
  float inv[4];
#pragma unroll
  for (int rr = 0; rr < 4; ++rr) {
    int row = lg * 4 + rr;
    inv[rr] = 1.f / (reds[row * 4] + reds[row * 4 + 1] + reds[row * 4 + 2] + reds[row * 4 + 3]);
  }
#pragma unroll
  for (int rr = 0; rr < 4; ++rr) {
    int j = j0 + lg * 4 + rr;
    const float* rp = rd + (size_t)(b * MK + j) * Nn;
    __hip_bfloat16* pp = P2 + ((size_t)bh * MK + j) * Nn;
#pragma unroll
    for (int q = 0; q < 32; ++q) {
      int n = (q >> 2) * 256 + w * 64 + (q & 3) * 16 + lr;
      pp[n] = __float2bfloat16(acc[q][rr] * inv[rr] * rp[n]);
    }
  }
}

// ---------------- rd transpose: [b][j][i] -> rdT [b][i][j] (runs once) ----------------
__global__ __launch_bounds__(256)
void rd_tr_kernel(const float* __restrict__ rd, float* __restrict__ rdT) {
  __shared__ float tb[64][65];
  const int b = blockIdx.x;
  const int i0 = blockIdx.y * 64, j0 = blockIdx.z * 64;
  const int tid = threadIdx.x;
#pragma unroll
  for (int it = 0; it < 4; ++it) {
    int idx = tid + it * 256, r = idx >> 4, c4 = (idx & 15) * 4;
    float4 v = ldf4(rd + ((size_t)(b * MK + j0 + r)) * Nn + i0 + c4);
    tb[r][c4 + 0] = v.x; tb[r][c4 + 1] = v.y; tb[r][c4 + 2] = v.z; tb[r][c4 + 3] = v.w;
  }
  __syncthreads();
#pragma unroll
  for (int it = 0; it < 4; ++it) {
    int idx = tid + it * 256, r = idx >> 4, c4 = (idx & 15) * 4;
    float4 o = make_float4(tb[c4 + 0][r], tb[c4 + 1][r], tb[c4 + 2][r], tb[c4 + 3][r]);
    *reinterpret_cast<float4*>(rdT + ((size_t)(b * Nn + i0 + r)) * MK + j0 + c4) = o;
  }
}

// ---------------- batched weight transpose: 8 matrices in one launch ----------------
struct WtArgs {
  const float* W[8];
  __hip_bfloat16* T[8];
  int K[8], N[8];
};
__global__ __launch_bounds__(256)
void wtrans_all_kernel(WtArgs a) {
  __shared__ float t[64][65];
  const int e = blockIdx.z;
  const int K = a.K[e], N = a.N[e];
  const int n0 = blockIdx.x * 64, k0 = blockIdx.y * 64;
  if (n0 >= N || k0 >= K) return;
  const float* W = a.W[e];
  __hip_bfloat16* WT = a.T[e];
  const int tid = threadIdx.x;
#pragma unroll
  for (int it = 0; it < 4; ++it) {
    int idx = tid + it * 256, r = idx >> 4, f = idx & 15;
    float4 v = ldf4(W + (size_t)(k0 + r) * N + n0 + f * 4);
    t[r][f * 4 + 0] = v.x; t[r][f * 4 + 1] = v.y;
    t[r][f * 4 + 2] = v.z; t[r][f * 4 + 3] = v.w;
  }
  __syncthreads();
#pragma unroll
  for (int it = 0; it < 4; ++it) {
    int idx = tid + it * 256, r = idx >> 4, c4 = (idx & 15) * 4;
    __hip_bfloat16* op = WT + (size_t)(n0 + r) * K + k0 + c4;
#pragma unroll
    for (int e2 = 0; e2 < 4; ++e2) op[e2] = __float2bfloat16(t[c4 + e2][r]);
  }
}

// ------------- cls-token attention: grid B*H, block 256, bf16 out -------------
__global__ __launch_bounds__(256)
void attn_c_kernel(const float* __restrict__ cqkv, const float* __restrict__ kqkv,
                   const float* __restrict__ mask, const float* __restrict__ kmask,
                   __hip_bfloat16* __restrict__ c_pre) {
  __shared__ __align__(16) float kv_s[MK][DH];
  __shared__ __align__(16) float q_s[DH];
  __shared__ float pbuf[MK];
  __shared__ float red8[8];
  __shared__ float redpv[4][DH];
  const int tid = threadIdx.x;
  const int bh = blockIdx.x, b = bh >> 3, h = bh & 7;
  const float* vp = kqkv + ((size_t)(b * MK + tid)) * QLD + 2 * Dd + h * DH;
#pragma unroll
  for (int q4 = 0; q4 < 16; ++q4)
    *reinterpret_cast<float4*>(&kv_s[tid][q4 * 4]) = ldf4(vp + q4 * 4);
  if (tid < DH) q_s[tid] = cqkv[(size_t)b * QLD + h * DH + tid];
  __syncthreads();
  const float* kp = kqkv + ((size_t)(b * MK + tid)) * QLD + Dd + h * DH;
  float dot = 0.f;
#pragma unroll
  for (int q4 = 0; q4 < 16; ++q4) {
    float4 kv4 = ldf4(kp + q4 * 4);
    float4 qv = ldf4(&q_s[q4 * 4]);
    dot = fmaf(qv.x, kv4.x, dot);
    dot = fmaf(qv.y, kv4.y, dot);
    dot = fmaf(qv.z, kv4.z, dot);
    dot = fmaf(qv.w, kv4.w, dot);
  }
  const float dm = (mask[(size_t)b * Nn] * kmask[b * MK + tid] < 0.5f) ? NEGV : dot * SCALE;
  const float mx = blockMax256(dm, red8);
  const float e = __expf(dm - mx);
  const float s = blockSum256(e, red8);
  pbuf[tid] = e / s;
  __syncthreads();
  const int d = tid & 63, g = tid >> 6;
  float acc = 0.f;
#pragma unroll 8
  for (int jj = 0; jj < 64; ++jj)
    acc = fmaf(pbuf[g * 64 + jj], kv_s[g * 64 + jj][d], acc);
  redpv[g][d] = acc;
  __syncthreads();
  if (tid < DH)
    c_pre[(size_t)b * Dd + h * DH + tid] = __float2bfloat16(
        redpv[0][tid] + redpv[1][tid] + redpv[2][tid] + redpv[3][tid]);
}

// ------------- output writers (float32 outputs) -------------
__global__ void kreps_kernel(const float* __restrict__ kx, const float* __restrict__ kmask,
                             float* __restrict__ o) {
  const int idx = blockIdx.x * 256 + threadIdx.x;
  const int bj = idx >> 9;
  const float keep = (kmask[bj] >= 0.5f) ? 1.f : 0.f;
  o[idx] = kx[idx] * keep;
}
__global__ void cout_kernel(const float* __restrict__ c_s, float* __restrict__ o) {
  const int idx = blockIdx.x * 256 + threadIdx.x;
  o[idx] = c_s[idx];
}

static GArgs ga_base() { GArgs g = {}; return g; }

extern "C" void kernel_launch(void* const* d_in, const int* in_sizes, int n_in,
                              void* d_out, int out_size, void* d_ws, size_t ws_size,
                              hipStream_t stream) {
  (void)in_sizes; (void)n_in; (void)out_size; (void)ws_size;
  const float* x_in  = (const float*)d_in[0];
  const float* kx_in = (const float*)d_in[1];
  const float* rd    = (const float*)d_in[2];
  const float* c_in  = (const float*)d_in[3];
  const float* mask  = (const float*)d_in[4];
  const float* kmask = (const float*)d_in[5];
  const float* ln1g  = (const float*)d_in[6];
  const float* ln1b  = (const float*)d_in[7];
  const float* Wqkv  = (const float*)d_in[8];
  const float* Woutw = (const float*)d_in[9];
  const float* boutw = (const float*)d_in[10];
  const float* ln2g  = (const float*)d_in[11];
  const float* ln2b  = (const float*)d_in[12];
  const float* W1    = (const float*)d_in[13];
  const float* b1    = (const float*)d_in[14];
  const float* W2    = (const float*)d_in[15];
  const float* b2    = (const float*)d_in[16];
  float* out = (float*)d_out;

  float* ws = (float*)d_ws;
  size_t off = 0;
  auto alloc = [&](size_t n) { float* p = ws + off; off += (n + 15) & ~(size_t)15; return p; };
  float* xcat_s    = alloc((size_t)NTOK * Dd);
  float* xcat_nb_f = alloc((size_t)NTOK * Dd / 2);
  float* pre_cat_f = alloc((size_t)NTOK * Dd / 2);
  float* qkv       = alloc((size_t)NTOK * QLD);     // hosts hid after attention
  float* P1_f      = alloc((size_t)32 * Nn * MK / 2);
  float* P2_f      = alloc((size_t)32 * MK * Nn / 2);
  float* tq_s_f    = alloc((size_t)32 * Nn * 128 / 2);
  float* kk_s_f    = alloc((size_t)32 * MK * 128 / 2);
  float* tk_hi_f   = alloc((size_t)32 * Nn * 64 / 2);
  float* kq_hi_f   = alloc((size_t)32 * MK * 64 / 2);
  float* tvT_f     = alloc((size_t)32 * 64 * Nn / 2);
  float* kvT_f     = alloc((size_t)32 * 64 * MK / 2);
  float* rdT       = alloc((size_t)Bb * Nn * MK);
  float* WqkvT_f   = alloc((size_t)2 * QLD * Dd / 2);
  float* WoutT_f   = alloc((size_t)2 * Dd * Dd / 2);
  float* W1T_f     = alloc((size_t)2 * MLPD * Dd / 2);
  float* W2T_f     = alloc((size_t)2 * Dd * MLPD / 2);

  __hip_bfloat16* xcat_nb = (__hip_bfloat16*)xcat_nb_f;
  __hip_bfloat16* pre_cat = (__hip_bfloat16*)pre_cat_f;
  __hip_bfloat16* P1b     = (__hip_bfloat16*)P1_f;
  __hip_bfloat16* P2b     = (__hip_bfloat16*)P2_f;
  __hip_bfloat16* tq_s    = (__hip_bfloat16*)tq_s_f;
  __hip_bfloat16* kk_s    = (__hip_bfloat16*)kk_s_f;
  __hip_bfloat16* tk_hi   = (__hip_bfloat16*)tk_hi_f;
  __hip_bfloat16* kq_hi   = (__hip_bfloat16*)kq_hi_f;
  __hip_bfloat16* tvT     = (__hip_bfloat16*)tvT_f;
  __hip_bfloat16* kvT     = (__hip_bfloat16*)kvT_f;
  __hip_bfloat16* WqkvT   = (__hip_bfloat16*)WqkvT_f;
  __hip_bfloat16* WoutT   = (__hip_bfloat16*)WoutT_f;
  __hip_bfloat16* W1T     = (__hip_bfloat16*)W1T_f;
  __hip_bfloat16* W2T     = (__hip_bfloat16*)W2T_f;
  __hip_bfloat16* hid     = (__hip_bfloat16*)qkv;   // FF hidden overlay

  const size_t CL_OFF = (size_t)2 * Bb * MK * Dd;
  const size_t AT_OFF = CL_OFF + (size_t)Bb * Dd;

  // ---- upfront: input concat, rd transpose, all weight transposes ----
  copy3_kernel<<<(NTOK * 128) / 256, 256, 0, stream>>>(x_in, kx_in, c_in, xcat_s);
  rd_tr_kernel<<<dim3(Bb, Nn / 64, MK / 64), 256, 0, stream>>>(rd, rdT);
  {
    WtArgs a;
    for (int l = 0; l < 2; ++l) {
      a.W[l * 4 + 0] = Wqkv + (size_t)l * Dd * QLD;  a.T[l * 4 + 0] = WqkvT + (size_t)l * QLD * Dd;
      a.K[l * 4 + 0] = Dd;   a.N[l * 4 + 0] = QLD;
      a.W[l * 4 + 1] = Woutw + (size_t)l * Dd * Dd;  a.T[l * 4 + 1] = WoutT + (size_t)l * Dd * Dd;
      a.K[l * 4 + 1] = Dd;   a.N[l * 4 + 1] = Dd;
      a.W[l * 4 + 2] = W1 + (size_t)l * Dd * MLPD;   a.T[l * 4 + 2] = W1T + (size_t)l * MLPD * Dd;
      a.K[l * 4 + 2] = Dd;   a.N[l * 4 + 2] = MLPD;
      a.W[l * 4 + 3] = W2 + (size_t)l * MLPD * Dd;   a.T[l * 4 + 3] = W2T + (size_t)l * Dd * MLPD;
      a.K[l * 4 + 3] = MLPD; a.N[l * 4 + 3] = Dd;
    }
    wtrans_all_kernel<<<dim3(32, 32, 8), 256, 0, stream>>>(a);
  }

  for (int l = 0; l < 2; ++l) {
    const float* bo  = boutw + (size_t)l * Dd;
    const float* b1l = b1 + (size_t)l * MLPD;
    const float* b2l = b2 + (size_t)l * Dd;
    __hip_bfloat16* WqkvTl = WqkvT + (size_t)l * QLD * Dd;
    __hip_bfloat16* WoutTl = WoutT + (size_t)l * Dd * Dd;
    __hip_bfloat16* W1Tl   = W1T + (size_t)l * MLPD * Dd;
    __hip_bfloat16* W2Tl   = W2T + (size_t)l * Dd * MLPD;

    ln_kernel<<<NTOK, 64, 0, stream>>>(xcat_s, ln1g + l * Dd, ln1b + l * Dd, xcat_nb);

    // QKV: one GEMM over all 9220 rows
    {
      GArgs g = ga_base();
      g.A = (const short*)xcat_nb; g.lda = Dd;
      g.Bt = (const short*)WqkvTl; g.ldb = Dd;
      g.C = qkv; g.ldc = QLD;
      g.M = NTOK; g.N = QLD; g.K = Dd;
      launch_mgemm<128, 128, 0>(g, 1, stream);
    }

    prep_attn_kernel<<<5760, 256, 0, stream>>>(
        qkv, qkv + (size_t)KXOFF * QLD, tq_s, tk_hi, kq_hi, kk_s, tvT, kvT);

    attn_c_kernel<<<Bb * Hh, 256, 0, stream>>>(qkv + (size_t)CLOFF * QLD,
                                               qkv + (size_t)KXOFF * QLD, mask, kmask,
                                               pre_cat + (size_t)CLOFF * Dd);

    // ---- x-path: fused score+softmax+atten-transpose -> PV ----
    score_sx_kernel<<<dim3(Nn / 128, 32), 512, 0, stream>>>(
        (const short*)tq_s, (const short*)kk_s, mask, kmask, rdT, P1b,
        out + AT_OFF + (size_t)l * 32 * MK * Nn);
    {
      GArgs g = ga_base();
      g.A = (const short*)P1b; g.asb = (long)Nn * MK; g.lda = MK;
      g.Bt = (const short*)kvT; g.bsb = (long)64 * MK; g.ldb = MK;
      g.Cb = pre_cat; g.czo = (long)Nn * Dd; g.czi = 64; g.ldc = Dd;
      g.M = Nn; g.N = 64; g.K = MK;
      launch_mgemm<128, 64, 4>(g, 32, stream);
    }
    // ---- k-path: fused score+softmax -> PV ----
    score_sk_kernel<<<dim3(32, MK / 16), 256, 0, stream>>>(
        (const short*)kq_hi, (const short*)tk_hi, mask, kmask, rd, P2b);
    {
      GArgs g = ga_base();
      g.A = (const short*)P2b; g.asb = (long)MK * Nn; g.lda = Nn;
      g.Bt = (const short*)tvT; g.bsb = (long)64 * Nn; g.ldb = Nn;
      g.Cb = pre_cat + (size_t)KXOFF * Dd; g.czo = (long)MK * Dd; g.czi = 64; g.ldc = Dd;
      g.M = MK; g.N = 64; g.K = Nn;
      launch_mgemm<64, 64, 4>(g, 32, stream);
    }

    // ---- Wout + bf16 residual over all rows ----
    {
      GArgs g = ga_base();
      g.A = (const short*)pre_cat; g.lda = Dd;
      g.Bt = (const short*)WoutTl; g.ldb = Dd;
      g.C = xcat_s; g.ldc = Dd; g.bias = bo; g.resb = xcat_nb; g.ldr = Dd;
      g.M = NTOK; g.N = Dd; g.K = Dd;
      launch_mgemm<128, 64, 5>(g, 1, stream);
    }

    // ---- FF over all rows ----
    ln_kernel<<<NTOK, 64, 0, stream>>>(xcat_s, ln2g + l * Dd, ln2b + l * Dd, xcat_nb);
    {
      GArgs g = ga_base();
      g.A = (const short*)xcat_nb; g.lda = Dd;
      g.Bt = (const short*)W1Tl; g.ldb = Dd;
      g.Cb = hid; g.ldc = MLPD; g.bias = b1l;
      g.M = NTOK; g.N = MLPD; g.K = Dd;
      launch_mgemm<128, 128, 3>(g, 1, stream);
      GArgs h = ga_base();
      h.A = (const short*)hid; h.lda = MLPD;
      h.Bt = (const short*)W2Tl; h.ldb = MLPD;
      h.C = xcat_s; h.ldc = Dd; h.bias = b2l; h.res = xcat_s; h.ldr = Dd;
      h.M = NTOK; h.N = Dd; h.K = MLPD;
      launch_mgemm<128, 64, 2>(h, 1, stream);
    }

    kreps_kernel<<<(Bb * MK * Dd) / 256, 256, 0, stream>>>(
        xcat_s + (size_t)KXOFF * Dd, kmask, out + (size_t)l * Bb * MK * Dd);
  }
  cout_kernel<<<(Bb * Dd) / 256, 256, 0, stream>>>(xcat_s + (size_t)CLOFF * Dd, out + CL_OFF);
}

// Round 16
// 650.689 us; speedup vs baseline: 1.5966x; 1.0573x over previous
//
#include <hip/hip_runtime.h>
#include <hip/hip_bf16.h>
#include <cstddef>

#define DEV __device__ __forceinline__

constexpr int Bb  = 4;
constexpr int Nn  = 2048;
constexpr int MK  = 256;
constexpr int Dd  = 512;
constexpr int Hh  = 8;
constexpr int DH  = 64;
constexpr int QLD = 1536;   // qkv row stride (3*512)
constexpr int MLPD = 2048;
constexpr int NTOK = Bb * Nn + Bb * MK + Bb;   // 9220 concatenated rows
constexpr int KXOFF = Bb * Nn;                 // 8192: first kx row
constexpr int CLOFF = Bb * Nn + Bb * MK;       // 9216: first cls row
constexpr float SCALE = 0.125f;   // 64^-0.5
constexpr float NEGV  = -1e9f;

typedef __attribute__((ext_vector_type(8))) short short8;
typedef __attribute__((ext_vector_type(4))) float f32x4;

DEV float4 ldf4(const float* p) { return *reinterpret_cast<const float4*>(p); }

// async global->LDS, 16B per lane, linear LDS dest
DEV void gload16(const short* g, short* l) {
  __builtin_amdgcn_global_load_lds(
      (const __attribute__((address_space(1))) void*)g,
      (__attribute__((address_space(3))) void*)l, 16, 0, 0);
}

DEV float waveMax(float v) {
#pragma unroll
  for (int o = 32; o; o >>= 1) v = fmaxf(v, __shfl_xor(v, o));
  return v;
}
DEV float waveSum(float v) {
#pragma unroll
  for (int o = 32; o; o >>= 1) v += __shfl_xor(v, o);
  return v;
}
DEV float blockMax256(float v, float* red) {
  v = waveMax(v);
  __syncthreads();
  if ((threadIdx.x & 63) == 0) red[threadIdx.x >> 6] = v;
  __syncthreads();
  return fmaxf(fmaxf(red[0], red[1]), fmaxf(red[2], red[3]));
}
DEV float blockSum256(float v, float* red) {
  v = waveSum(v);
  __syncthreads();
  if ((threadIdx.x & 63) == 0) red[threadIdx.x >> 6] = v;
  __syncthreads();
  return red[0] + red[1] + red[2] + red[3];
}
DEV float gelu_f(float x) { return 0.5f * x * (1.f + erff(x * 0.70710678118654752f)); }
// exact: e1^24 (5 multiplies)
DEV float pow24(float e1) {
  float e2 = e1 * e1, e4 = e2 * e2, e8 = e4 * e4, e16 = e8 * e8;
  return e16 * e8;
}
DEV short bf16bits(float v) {
  __hip_bfloat16 h = __float2bfloat16(v);
  return *reinterpret_cast<short*>(&h);
}

// ---------------- input concat copy: {x, kx, cls} -> xcat_s ----------------
__global__ __launch_bounds__(256)
void copy3_kernel(const float* __restrict__ x, const float* __restrict__ kx,
                  const float* __restrict__ c, float* __restrict__ dst) {
  const int idx = blockIdx.x * 256 + threadIdx.x;   // float4 index
  const int row = idx >> 7;
  float4 v;
  if (row < KXOFF) v = ldf4(x + (size_t)idx * 4);
  else if (row < CLOFF) v = ldf4(kx + (size_t)idx * 4 - (size_t)KXOFF * Dd);
  else v = ldf4(c + (size_t)idx * 4 - (size_t)CLOFF * Dd);
  *reinterpret_cast<float4*>(dst + (size_t)idx * 4) = v;
}

// ---------------- LayerNorm: one wave per 512-float row, bf16 out ----------------
__global__ __launch_bounds__(64)
void ln_kernel(const float* __restrict__ in, const float* __restrict__ gw,
               const float* __restrict__ bw, __hip_bfloat16* __restrict__ outb) {
  const int row = blockIdx.x;
  const int t = threadIdx.x;
  const float* p = in + (size_t)row * Dd + t * 8;
  float4 v0 = ldf4(p), v1 = ldf4(p + 4);
  float s = v0.x + v0.y + v0.z + v0.w + v1.x + v1.y + v1.z + v1.w;
  float q = v0.x*v0.x + v0.y*v0.y + v0.z*v0.z + v0.w*v0.w
          + v1.x*v1.x + v1.y*v1.y + v1.z*v1.z + v1.w*v1.w;
  s = waveSum(s); q = waveSum(q);
  const float mu = s * (1.f / Dd);
  const float rstd = rsqrtf(fmaxf(q * (1.f / Dd) - mu * mu, 0.f) + 1e-5f);
  float4 g0 = ldf4(gw + t * 8), g1 = ldf4(gw + t * 8 + 4);
  float4 b0 = ldf4(bw + t * 8), b1 = ldf4(bw + t * 8 + 4);
  float o[8];
  o[0] = (v0.x - mu) * rstd * g0.x + b0.x;
  o[1] = (v0.y - mu) * rstd * g0.y + b0.y;
  o[2] = (v0.z - mu) * rstd * g0.z + b0.z;
  o[3] = (v0.w - mu) * rstd * g0.w + b0.w;
  o[4] = (v1.x - mu) * rstd * g1.x + b1.x;
  o[5] = (v1.y - mu) * rstd * g1.y + b1.y;
  o[6] = (v1.z - mu) * rstd * g1.z + b1.z;
  o[7] = (v1.w - mu) * rstd * g1.w + b1.w;
  __hip_bfloat16* ob = outb + (size_t)row * Dd + t * 8;
#pragma unroll
  for (int e = 0; e < 8; ++e) ob[e] = __float2bfloat16(o[e]);
}

// ---------------- bf16 MFMA GEMM ----------------
// Single-buffered (32 KB LDS), source-pre-swizzled staging, XCD swizzle.
// EPI: 0 = f32; 3 = +bias gelu bf16; 4 = bf16; 2 = +bias +f32 res f32;
//      5 = +bias +bf16 res f32; 6 = EPI2 + masked kreps output for kx rows.
struct GArgs {
  const short* A;  long asb; int lda;
  const short* Bt; long bsb; int ldb;
  float* C; __hip_bfloat16* Cb;
  long czo, czi; int ldc;
  const float* bias;
  const float* res; const __hip_bfloat16* resb; int ldr;
  float* out2; const float* km2;
  int M, N, K;
};

template<int BM, int BN, int EPI>
__global__ __launch_bounds__(256)
void mgemm(GArgs g) {
  constexpr int WMW = (BN >= 128) ? 2 : 4;
  constexpr int WNW = 4 / WMW;
  constexpr int WM = BM / WMW, WN = BN / WNW;
  constexpr int FM = WM / 16, FN = WN / 16;
  __shared__ __align__(16) short As[BM * 64];
  __shared__ __align__(16) short Bs[BN * 64];
  const int tid = threadIdx.x, l = tid & 63, w = tid >> 6;
  const int wm = (WNW == 2) ? (w >> 1) : w;
  const int wn = (WNW == 2) ? (w & 1) : 0;
  int bx = blockIdx.x, by = blockIdx.y;
  {  // bijective XCD swizzle (m204)
    const int gx = gridDim.x, nwg = gx * gridDim.y;
    const int orig = by * gx + bx;
    const int xcd = orig & 7, pos = orig >> 3;
    const int q = nwg >> 3, rmd = nwg & 7;
    const int s = (xcd < rmd ? xcd * (q + 1) : rmd * (q + 1) + (xcd - rmd) * q) + pos;
    bx = s % gx; by = s / gx;
  }
  const int z = blockIdx.z;
  const short* Ab = g.A + (size_t)z * g.asb;
  const short* Bb_ = g.Bt + (size_t)z * g.bsb;
  f32x4 acc[FM][FN] = {};
  const int lr = l & 15, lg = l >> 4;

  for (int k0 = 0; k0 < g.K; k0 += 64) {
    __syncthreads();
#pragma unroll
    for (int it = 0; it < BM / 32; ++it) {
      int idx = tid + it * 256, r = idx >> 3, c = idx & 7;
      int gm = by * BM + r;
      if (gm >= g.M) gm = g.M - 1;   // clamp; rows independent, masked at write
      gload16(Ab + (size_t)gm * g.lda + k0 + ((c ^ (r & 7)) * 8), As + idx * 8);
    }
#pragma unroll
    for (int it = 0; it < BN / 32; ++it) {
      int idx = tid + it * 256, r = idx >> 3, c = idx & 7;
      int gn = bx * BN + r;
      gload16(Bb_ + (size_t)gn * g.ldb + k0 + ((c ^ (r & 7)) * 8), Bs + idx * 8);
    }
    __syncthreads();
#pragma unroll
    for (int ks = 0; ks < 2; ++ks) {
      short8 a[FM], b[FN];
#pragma unroll
      for (int fm = 0; fm < FM; ++fm) {
        int rr = wm * WM + fm * 16 + lr;
        int ch = (ks * 4 + lg) ^ (rr & 7);
        a[fm] = *reinterpret_cast<const short8*>(As + rr * 64 + ch * 8);
      }
#pragma unroll
      for (int fn = 0; fn < FN; ++fn) {
        int rn = wn * WN + fn * 16 + lr;
        int ch = (ks * 4 + lg) ^ (rn & 7);
        b[fn] = *reinterpret_cast<const short8*>(Bs + rn * 64 + ch * 8);
      }
#pragma unroll
      for (int fm = 0; fm < FM; ++fm)
#pragma unroll
        for (int fn = 0; fn < FN; ++fn)
          acc[fm][fn] = __builtin_amdgcn_mfma_f32_16x16x32_bf16(a[fm], b[fn], acc[fm][fn], 0, 0, 0);
    }
  }

  const size_t zoff = (size_t)(z >> 3) * g.czo + (size_t)(z & 7) * g.czi;
#pragma unroll
  for (int fm = 0; fm < FM; ++fm) {
#pragma unroll
    for (int fn = 0; fn < FN; ++fn) {
#pragma unroll
      for (int r = 0; r < 4; ++r) {
        int m = by * BM + wm * WM + fm * 16 + lg * 4 + r;
        int n = bx * BN + wn * WN + fn * 16 + lr;
        if (m >= g.M) continue;
        float v = acc[fm][fn][r];
        size_t coff = zoff + (size_t)m * g.ldc + n;
        if (EPI == 0) {
          g.C[coff] = v;
        } else if (EPI == 2) {
          v += g.bias[n] + g.res[(size_t)m * g.ldr + n];
          g.C[coff] = v;
        } else if (EPI == 5) {
          v += g.bias[n] + __bfloat162float(g.resb[(size_t)m * g.ldr + n]);
          g.C[coff] = v;
        } else if (EPI == 6) {
          v += g.bias[n] + g.res[(size_t)m * g.ldr + n];
          g.C[coff] = v;
          if (m >= KXOFF && m < CLOFF) {
            int t = m - KXOFF;
            float keep = (g.km2[t] >= 0.5f) ? 1.f : 0.f;
            g.out2[(size_t)t * Dd + n] = v * keep;
          }
        } else if (EPI == 3) {
          v = gelu_f(v + g.bias[n]);
          g.Cb[coff] = __float2bfloat16(v);
        } else {
          g.Cb[coff] = __float2bfloat16(v);
        }
      }
    }
  }
}

template<int BM, int BN, int EPI>
static void launch_mgemm(const GArgs& g, int zdim, hipStream_t s) {
  dim3 grid((g.N + BN - 1) / BN, (g.M + BM - 1) / BM, zdim);
  mgemm<BM, BN, EPI><<<grid, 256, 0, s>>>(g);
}

// ---------------- QKV GEMM with fused split/transpose epilogue ----------------
// BM=128, BN=128 over [NTOK x 1536]. bx 0-3: q, 4-7: k, 8-11: v.
// by 0-63: x tokens, 64-71: kx tokens, 72: cls.
struct QArgs {
  const short* A; int lda;
  const short* Bt; int ldb;
  __hip_bfloat16 *tq, *tk, *kq, *kk, *tvT, *kvT;
  float* cq;
  int M, K;
};

__global__ __launch_bounds__(256)
void qkv_gemm(QArgs g) {
  __shared__ __align__(16) char smem[34816];   // As 16K | Bs 16K; v-path: tb[128][136] bf16
  short* As = (short*)smem;
  short* Bs = (short*)(smem + 16384);
  short* tb = (short*)smem;
  const int tid = threadIdx.x, l = tid & 63, w = tid >> 6;
  const int wm = w >> 1, wn = w & 1;
  int bx = blockIdx.x, by = blockIdx.y;
  {  // bijective XCD swizzle
    const int gx = gridDim.x, nwg = gx * gridDim.y;
    const int orig = by * gx + bx;
    const int xcd = orig & 7, pos = orig >> 3;
    const int q = nwg >> 3, rmd = nwg & 7;
    const int s = (xcd < rmd ? xcd * (q + 1) : rmd * (q + 1) + (xcd - rmd) * q) + pos;
    bx = s % gx; by = s / gx;
  }
  f32x4 acc[4][4] = {};
  const int lr = l & 15, lg = l >> 4;

  for (int k0 = 0; k0 < g.K; k0 += 64) {
    __syncthreads();
#pragma unroll
    for (int it = 0; it < 4; ++it) {
      int idx = tid + it * 256, r = idx >> 3, c = idx & 7;
      int gm = by * 128 + r;
      if (gm >= g.M) gm = g.M - 1;
      gload16(g.A + (size_t)gm * g.lda + k0 + ((c ^ (r & 7)) * 8), As + idx * 8);
    }
#pragma unroll
    for (int it = 0; it < 4; ++it) {
      int idx = tid + it * 256, r = idx >> 3, c = idx & 7;
      int gn = bx * 128 + r;
      gload16(g.Bt + (size_t)gn * g.ldb + k0 + ((c ^ (r & 7)) * 8), Bs + idx * 8);
    }
    __syncthreads();
#pragma unroll
    for (int ks = 0; ks < 2; ++ks) {
      short8 a[4], b[4];
#pragma unroll
      for (int fm = 0; fm < 4; ++fm) {
        int rr = wm * 64 + fm * 16 + lr;
        int ch = (ks * 4 + lg) ^ (rr & 7);
        a[fm] = *reinterpret_cast<const short8*>(As + rr * 64 + ch * 8);
      }
#pragma unroll
      for (int fn = 0; fn < 4; ++fn) {
        int rn = wn * 64 + fn * 16 + lr;
        int ch = (ks * 4 + lg) ^ (rn & 7);
        b[fn] = *reinterpret_cast<const short8*>(Bs + rn * 64 + ch * 8);
      }
#pragma unroll
      for (int fm = 0; fm < 4; ++fm)
#pragma unroll
        for (int fn = 0; fn < 4; ++fn)
          acc[fm][fn] = __builtin_amdgcn_mfma_f32_16x16x32_bf16(a[fm], b[fn], acc[fm][fn], 0, 0, 0);
    }
  }

  const int sec = bx >> 2;                         // 0 q, 1 k, 2 v
  const int region = (by < 64) ? 0 : (by < 72 ? 1 : 2);

  if (sec == 2) {
    // ---- v: LDS transpose -> coalesced bf16 writes into tvT/kvT ----
    if (region == 2) return;                       // cls v unused
    __syncthreads();                               // all As/Bs reads done
#pragma unroll
    for (int fm = 0; fm < 4; ++fm)
#pragma unroll
      for (int fn = 0; fn < 4; ++fn)
#pragma unroll
        for (int r = 0; r < 4; ++r) {
          int mloc = wm * 64 + fm * 16 + lg * 4 + r;
          int nloc = wn * 64 + fn * 16 + lr;
          tb[nloc * 136 + mloc] = bf16bits(acc[fm][fn][r]);
        }
    __syncthreads();
    const int nloc = tid >> 1, mh = (tid & 1) * 64;
    const int nv = (bx - 8) * 128 + nloc;          // 0..511
    const int h = nv >> 6, d = nv & 63;
    int T, b, ibase;
    __hip_bfloat16* vT;
    if (region == 0) {
      T = Nn; b = by >> 4; ibase = (by & 15) * 128 + mh; vT = g.tvT;
    } else {
      T = MK; int t0 = (by - 64) * 128 + mh; b = t0 >> 8; ibase = t0 & 255; vT = g.kvT;
    }
    short* dst = (short*)vT + ((size_t)(b * 8 + h) * 64 + d) * T + ibase;
    const short* src = tb + nloc * 136 + mh;
#pragma unroll
    for (int e = 0; e < 8; ++e)
      *reinterpret_cast<short8*>(dst + e * 8) = *reinterpret_cast<const short8*>(src + e * 8);
    return;
  }

  if (region == 2) {
    // ---- cls q -> f32 cq; cls k unused ----
    if (sec == 0) {
#pragma unroll
      for (int fm = 0; fm < 4; ++fm)
#pragma unroll
        for (int fn = 0; fn < 4; ++fn)
#pragma unroll
          for (int r = 0; r < 4; ++r) {
            int m = by * 128 + wm * 64 + fm * 16 + lg * 4 + r;
            if (m >= g.M) continue;
            int n = bx * 128 + wn * 64 + fn * 16 + lr;
            g.cq[(size_t)(m - CLOFF) * Dd + n] = acc[fm][fn][r];
          }
    }
    return;
  }

  // ---- q/k scatter for x and kx regions ----
  const int T = region ? MK : Nn;
#pragma unroll
  for (int fm = 0; fm < 4; ++fm) {
#pragma unroll
    for (int fn = 0; fn < 4; ++fn) {
#pragma unroll
      for (int r = 0; r < 4; ++r) {
        int m = by * 128 + wm * 64 + fm * 16 + lg * 4 + r;
        int n = bx * 128 + wn * 64 + fn * 16 + lr;
        float v = acc[fm][fn][r];
        int t = region ? m - KXOFF : m;
        int b = region ? (t >> 8) : (t >> 11);
        int i = region ? (t & 255) : (t & 2047);
        int h = (n >> 6) & 7, d = n & 63;
        size_t tok = (size_t)(b * 8 + h) * T + i;
        if (sec == 0) {
          if (region == 0) {     // x q: hi/lo
            __hip_bfloat16 hi = __float2bfloat16(v);
            g.tq[tok * 128 + d] = hi;
            g.tq[tok * 128 + 64 + d] = __float2bfloat16(v - __bfloat162float(hi));
          } else {               // kx q: hi
            g.kq[tok * 64 + d] = __float2bfloat16(v);
          }
        } else {
          if (region == 0) {     // x k: hi
            g.tk[tok * 64 + d] = __float2bfloat16(v);
          } else {               // kx k: hi/lo
            __hip_bfloat16 hi = __float2bfloat16(v);
            g.kk[tok * 128 + d] = hi;
            g.kk[tok * 128 + 64 + d] = __float2bfloat16(v - __bfloat162float(hi));
          }
        }
      }
    }
  }
}

// ---------------- fused x-path score GEMM + dual softmax + atten transpose ----------------
// grid (Nn/128, 32), 512 threads. Writes P1 bf16 and atten f32 (transposed) directly.
__global__ __launch_bounds__(512)
void score_sx_kernel(const short* __restrict__ Q, const short* __restrict__ Km,
                     const float* __restrict__ mask, const float* __restrict__ kmask,
                     const float* __restrict__ rdT,
                     __hip_bfloat16* __restrict__ P1, float* __restrict__ atten) {
  __shared__ __align__(16) char smem[49152];   // As(16K) | Bs(32K); reused as tb f32[256][33]
  short* As = (short*)smem;
  short* Bs = (short*)(smem + 16384);
  float* tb = (float*)smem;
  __shared__ float red[128 * 2];
  __shared__ float red2[128 * 4];
  const int tid = threadIdx.x, l = tid & 63, w = tid >> 6;
  const int wm = w >> 1, wn = w & 1;
  const int by = blockIdx.x, bh = blockIdx.y;
  const int b = bh >> 3;
  const short* Ab = Q + (size_t)bh * Nn * 128;
  const short* Bb = Km + (size_t)bh * MK * 128;
  const int lr = l & 15, lg = l >> 4;
  f32x4 acc[2][8] = {};

  for (int k0 = 0; k0 < 128; k0 += 64) {
    __syncthreads();
#pragma unroll
    for (int it = 0; it < 2; ++it) {
      int idx = tid + it * 512, r = idx >> 3, c = idx & 7;
      gload16(Ab + (size_t)(by * 128 + r) * 128 + k0 + ((c ^ (r & 7)) * 8), As + idx * 8);
    }
#pragma unroll
    for (int it = 0; it < 4; ++it) {
      int idx = tid + it * 512, r = idx >> 3, c = idx & 7;
      gload16(Bb + (size_t)r * 128 + k0 + ((c ^ (r & 7)) * 8), Bs + idx * 8);
    }
    __syncthreads();
#pragma unroll
    for (int ks = 0; ks < 2; ++ks) {
      short8 a[2], bv[8];
#pragma unroll
      for (int fm = 0; fm < 2; ++fm) {
        int rr = wm * 32 + fm * 16 + lr;
        int ch = (ks * 4 + lg) ^ (rr & 7);
        a[fm] = *reinterpret_cast<const short8*>(As + rr * 64 + ch * 8);
      }
#pragma unroll
      for (int fn = 0; fn < 8; ++fn) {
        int rn = wn * 128 + fn * 16 + lr;
        int ch = (ks * 4 + lg) ^ (rn & 7);
        bv[fn] = *reinterpret_cast<const short8*>(Bs + rn * 64 + ch * 8);
      }
#pragma unroll
      for (int fm = 0; fm < 2; ++fm)
#pragma unroll
        for (int fn = 0; fn < 8; ++fn)
          acc[fm][fn] = __builtin_amdgcn_mfma_f32_16x16x32_bf16(a[fm], bv[fn], acc[fm][fn], 0, 0, 0);
    }
  }
  // mask + scale in place
  {
    float colm[8];
#pragma unroll
    for (int fn = 0; fn < 8; ++fn)
      colm[fn] = kmask[b * MK + wn * 128 + fn * 16 + lr];
#pragma unroll
    for (int fm = 0; fm < 2; ++fm)
#pragma unroll
      for (int r = 0; r < 4; ++r) {
        float rm = mask[(size_t)b * Nn + by * 128 + wm * 32 + fm * 16 + lg * 4 + r];
#pragma unroll
        for (int fn = 0; fn < 8; ++fn)
          acc[fm][fn][r] = (rm * colm[fn] < 0.5f) ? NEGV : acc[fm][fn][r] * SCALE;
      }
  }
  // row max
  float mx[2][4];
#pragma unroll
  for (int fm = 0; fm < 2; ++fm)
#pragma unroll
    for (int r = 0; r < 4; ++r) {
      float m = -3.4e38f;
#pragma unroll
      for (int fn = 0; fn < 8; ++fn) m = fmaxf(m, acc[fm][fn][r]);
#pragma unroll
      for (int o = 8; o; o >>= 1) m = fmaxf(m, __shfl_xor(m, o));
      mx[fm][r] = m;
    }
  __syncthreads();
  if (lr == 0) {
#pragma unroll
    for (int fm = 0; fm < 2; ++fm)
#pragma unroll
      for (int r = 0; r < 4; ++r)
        red[(wm * 32 + fm * 16 + lg * 4 + r) * 2 + wn] = mx[fm][r];
  }
  __syncthreads();
#pragma unroll
  for (int fm = 0; fm < 2; ++fm)
#pragma unroll
    for (int r = 0; r < 4; ++r) {
      int row = wm * 32 + fm * 16 + lg * 4 + r;
      mx[fm][r] = fmaxf(red[row * 2], red[row * 2 + 1]);
    }
  // single exp per element: store e1 in acc; e24 via 5 mults
  float s1[2][4], s24[2][4];
#pragma unroll
  for (int fm = 0; fm < 2; ++fm)
#pragma unroll
    for (int r = 0; r < 4; ++r) {
      float a1 = 0.f, a24 = 0.f;
#pragma unroll
      for (int fn = 0; fn < 8; ++fn) {
        float e1 = __expf(acc[fm][fn][r] - mx[fm][r]);
        acc[fm][fn][r] = e1;
        a1 += e1;
        a24 += pow24(e1);
      }
#pragma unroll
      for (int o = 8; o; o >>= 1) { a1 += __shfl_xor(a1, o); a24 += __shfl_xor(a24, o); }
      s1[fm][r] = a1; s24[fm][r] = a24;
    }
  __syncthreads();
  if (lr == 0) {
#pragma unroll
    for (int fm = 0; fm < 2; ++fm)
#pragma unroll
      for (int r = 0; r < 4; ++r) {
        int row = wm * 32 + fm * 16 + lg * 4 + r;
        red2[row * 4 + wn * 2]     = s1[fm][r];
        red2[row * 4 + wn * 2 + 1] = s24[fm][r];
      }
  }
  __syncthreads();
#pragma unroll
  for (int fm = 0; fm < 2; ++fm)
#pragma unroll
    for (int r = 0; r < 4; ++r) {
      int row = wm * 32 + fm * 16 + lg * 4 + r;
      s1[fm][r]  = 1.f / (red2[row * 4] + red2[row * 4 + 2]);
      s24[fm][r] = 1.f / (red2[row * 4 + 1] + red2[row * 4 + 3]);
    }
  // P1 write; convert acc to final atten value e24*rv
#pragma unroll
  for (int fm = 0; fm < 2; ++fm) {
#pragma unroll
    for (int r = 0; r < 4; ++r) {
      int m = by * 128 + wm * 32 + fm * 16 + lg * 4 + r;
      const float* rp = rdT + ((size_t)b * Nn + m) * MK;
      size_t obase = ((size_t)bh * Nn + m) * MK;
#pragma unroll
      for (int fn = 0; fn < 8; ++fn) {
        int n = wn * 128 + fn * 16 + lr;
        float e1 = acc[fm][fn][r];
        float rv = rp[n];
        P1[obase + n] = __float2bfloat16(e1 * s1[fm][r] * rv);
        acc[fm][fn][r] = pow24(e1) * s24[fm][r] * rv;
      }
    }
  }
  // atten transpose via LDS: 4 chunks of 32 i-rows; tb[256j][33]
  const int jw = tid >> 1, ipw = (tid & 1) * 16;
#pragma unroll
  for (int c = 0; c < 4; ++c) {
    __syncthreads();
    if (wm == c) {
#pragma unroll
      for (int fm = 0; fm < 2; ++fm)
#pragma unroll
        for (int r = 0; r < 4; ++r) {
          int mloc = fm * 16 + lg * 4 + r;
#pragma unroll
          for (int fn = 0; fn < 8; ++fn) {
            int n = wn * 128 + fn * 16 + lr;
            tb[n * 33 + mloc] = acc[fm][fn][r];
          }
        }
    }
    __syncthreads();
    float* op = atten + ((size_t)bh * MK + jw) * Nn + by * 128 + c * 32 + ipw;
    const float* tp = tb + jw * 33 + ipw;
#pragma unroll
    for (int e = 0; e < 4; ++e)
      *reinterpret_cast<float4*>(op + e * 4) =
          make_float4(tp[e * 4], tp[e * 4 + 1], tp[e * 4 + 2], tp[e * 4 + 3]);
  }
}

// ---------------- fused k-path score GEMM + softmax ----------------
__global__ __launch_bounds__(256)
void score_sk_kernel(const short* __restrict__ Qk, const short* __restrict__ Kt,
                     const float* __restrict__ mask, const float* __restrict__ kmask,
                     const float* __restrict__ rd, __hip_bfloat16* __restrict__ P2) {
  __shared__ __align__(16) short As[16 * 64];
  __shared__ __align__(16) short Bs[256 * 64];
  __shared__ float redm[16 * 4];
  __shared__ float reds[16 * 4];
  const int tid = threadIdx.x, l = tid & 63, w = tid >> 6;
  const int lr = l & 15, lg = l >> 4;
  const int bh = blockIdx.x, j0 = blockIdx.y * 16, b = bh >> 3;
  const short* Ab = Qk + ((size_t)bh * MK + j0) * 64;
  const short* Bb = Kt + (size_t)bh * Nn * 64;
  f32x4 acc[32];
#pragma unroll
  for (int q = 0; q < 32; ++q) acc[q] = f32x4{0.f, 0.f, 0.f, 0.f};
  if (tid < 128) {
    int r = tid >> 3, c = tid & 7;
    gload16(Ab + (size_t)r * 64 + ((c ^ (r & 7)) * 8), As + tid * 8);
  }
#pragma unroll
  for (int nc = 0; nc < 8; ++nc) {
    __syncthreads();
#pragma unroll
    for (int it = 0; it < 8; ++it) {
      int idx = tid + it * 256, r = idx >> 3, c = idx & 7;
      gload16(Bb + (size_t)(nc * 256 + r) * 64 + ((c ^ (r & 7)) * 8), Bs + idx * 8);
    }
    __syncthreads();
#pragma unroll
    for (int ks = 0; ks < 2; ++ks) {
      short8 a;
      {
        int ch = (ks * 4 + lg) ^ (lr & 7);
        a = *reinterpret_cast<const short8*>(As + lr * 64 + ch * 8);
      }
#pragma unroll
      for (int fn = 0; fn < 4; ++fn) {
        int rn = w * 64 + fn * 16 + lr;
        int ch = (ks * 4 + lg) ^ (rn & 7);
        short8 bv = *reinterpret_cast<const short8*>(Bs + rn * 64 + ch * 8);
        acc[nc * 4 + fn] =
            __builtin_amdgcn_mfma_f32_16x16x32_bf16(a, bv, acc[nc * 4 + fn], 0, 0, 0);
      }
    }
  }
  float rm[4];
#pragma unroll
  for (int rr = 0; rr < 4; ++rr) rm[rr] = kmask[b * MK + j0 + lg * 4 + rr];
  float mx[4] = {-3.4e38f, -3.4e38f, -3.4e38f, -3.4e38f};
#pragma unroll
  for (int q = 0; q < 32; ++q) {
    int n = (q >> 2) * 256 + w * 64 + (q & 3) * 16 + lr;
    float cm = mask[(size_t)b * Nn + n];
#pragma unroll
    for (int rr = 0; rr < 4; ++rr) {
      float v = (rm[rr] * cm < 0.5f) ? NEGV : acc[q][rr] * SCALE;
      acc[q][rr] = v;
      mx[rr] = fmaxf(mx[rr], v);
    }
  }
#pragma unroll
  for (int o = 8; o; o >>= 1)
#pragma unroll
    for (int rr = 0; rr < 4; ++rr) mx[rr] = fmaxf(mx[rr], __shfl_xor(mx[rr], o));
  __syncthreads();
  if (lr == 0) {
#pragma unroll
    for (int rr = 0; rr < 4; ++rr) redm[(lg * 4 + rr) * 4 + w] = mx[rr];
  }
  __syncthreads();
#pragma unroll
  for (int rr = 0; rr < 4; ++rr) {
    int row = lg * 4 + rr;
    mx[rr] = fmaxf(fmaxf(redm[row * 4], redm[row * 4 + 1]),
                   fmaxf(redm[row * 4 + 2], redm[row * 4 + 3]));
  }
  float sm[4] = {0.f, 0.f, 0.f, 0.f};
#pragma unroll
  for (int q = 0; q < 32; ++q)
#pragma unroll
    for (int rr = 0; rr < 4; ++rr) {
      float e = __expf(acc[q][rr] - mx[rr]);
      acc[q][rr] = e;
      sm[rr] += e;
    }
#pragma unroll
  for (int o = 8; o; o >>= 1)
#pragma unroll
    for (int rr = 0; rr < 4; ++rr) sm[rr] += __shfl_xor(sm[rr], o);
  __syncthreads();
  if (lr == 0) {
#pragma unroll
    for (int rr = 0; rr < 4; ++rr) reds[(lg * 4 + rr) * 4 + w] = sm[rr];
  }
  __syncthreads();
  float inv[4];
#pragma unroll
  for (int rr = 0; rr < 4; ++rr) {
    int row = lg * 4 + rr;
    inv[rr] = 1.f / (reds[row * 4] + reds[row * 4 + 1] + reds[row * 4 + 2] + reds[row * 4 + 3]);
  }
#pragma unroll
  for (int rr = 0; rr < 4; ++rr) {
    int j = j0 + lg * 4 + rr;
    const float* rp = rd + (size_t)(b * MK + j) * Nn;
    __hip_bfloat16* pp = P2 + ((size_t)bh * MK + j) * Nn;
#pragma unroll
    for (int q = 0; q < 32; ++q) {
      int n = (q >> 2) * 256 + w * 64 + (q & 3) * 16 + lr;
      pp[n] = __float2bfloat16(acc[q][rr] * inv[rr] * rp[n]);
    }
  }
}

// ---------------- rd transpose: [b][j][i] -> rdT [b][i][j] (runs once) ----------------
__global__ __launch_bounds__(256)
void rd_tr_kernel(const float* __restrict__ rd, float* __restrict__ rdT) {
  __shared__ float tb[64][65];
  const int b = blockIdx.x;
  const int i0 = blockIdx.y * 64, j0 = blockIdx.z * 64;
  const int tid = threadIdx.x;
#pragma unroll
  for (int it = 0; it < 4; ++it) {
    int idx = tid + it * 256, r = idx >> 4, c4 = (idx & 15) * 4;
    float4 v = ldf4(rd + ((size_t)(b * MK + j0 + r)) * Nn + i0 + c4);
    tb[r][c4 + 0] = v.x; tb[r][c4 + 1] = v.y; tb[r][c4 + 2] = v.z; tb[r][c4 + 3] = v.w;
  }
  __syncthreads();
#pragma unroll
  for (int it = 0; it < 4; ++it) {
    int idx = tid + it * 256, r = idx >> 4, c4 = (idx & 15) * 4;
    float4 o = make_float4(tb[c4 + 0][r], tb[c4 + 1][r], tb[c4 + 2][r], tb[c4 + 3][r]);
    *reinterpret_cast<float4*>(rdT + ((size_t)(b * Nn + i0 + r)) * MK + j0 + c4) = o;
  }
}

// ---------------- batched weight transpose: 8 matrices in one launch ----------------
struct WtArgs {
  const float* W[8];
  __hip_bfloat16* T[8];
  int K[8], N[8];
};
__global__ __launch_bounds__(256)
void wtrans_all_kernel(WtArgs a) {
  __shared__ float t[64][65];
  const int e = blockIdx.z;
  const int K = a.K[e], N = a.N[e];
  const int n0 = blockIdx.x * 64, k0 = blockIdx.y * 64;
  if (n0 >= N || k0 >= K) return;
  const float* W = a.W[e];
  __hip_bfloat16* WT = a.T[e];
  const int tid = threadIdx.x;
#pragma unroll
  for (int it = 0; it < 4; ++it) {
    int idx = tid + it * 256, r = idx >> 4, f = idx & 15;
    float4 v = ldf4(W + (size_t)(k0 + r) * N + n0 + f * 4);
    t[r][f * 4 + 0] = v.x; t[r][f * 4 + 1] = v.y;
    t[r][f * 4 + 2] = v.z; t[r][f * 4 + 3] = v.w;
  }
  __syncthreads();
#pragma unroll
  for (int it = 0; it < 4; ++it) {
    int idx = tid + it * 256, r = idx >> 4, c4 = (idx & 15) * 4;
    __hip_bfloat16* op = WT + (size_t)(n0 + r) * K + k0 + c4;
#pragma unroll
    for (int e2 = 0; e2 < 4; ++e2) op[e2] = __float2bfloat16(t[c4 + e2][r]);
  }
}

// ------------- cls-token attention: reads cq f32, kk hi/lo bf16, kvT bf16 -------------
__global__ __launch_bounds__(256)
void attn_c_kernel(const float* __restrict__ cq, const __hip_bfloat16* __restrict__ kk,
                   const __hip_bfloat16* __restrict__ kvT,
                   const float* __restrict__ mask, const float* __restrict__ kmask,
                   __hip_bfloat16* __restrict__ c_pre) {
  __shared__ __align__(16) float kv_s[MK][DH];
  __shared__ __align__(16) float q_s[DH];
  __shared__ float pbuf[MK];
  __shared__ float red8[8];
  __shared__ float redpv[4][DH];
  const int tid = threadIdx.x;
  const int bh = blockIdx.x, b = bh >> 3, h = bh & 7;
  // v: from transposed kvT [bh*64+d][token]
#pragma unroll
  for (int d = 0; d < DH; ++d)
    kv_s[tid][d] = __bfloat162float(kvT[((size_t)(b * 8 + h) * 64 + d) * MK + tid]);
  if (tid < DH) q_s[tid] = cq[(size_t)b * Dd + h * DH + tid];
  __syncthreads();
  // k: hi+lo reconstruction
  const __hip_bfloat16* kp = kk + ((size_t)((b * 8 + h) * MK + tid)) * 128;
  float dot = 0.f;
#pragma unroll
  for (int d = 0; d < DH; ++d) {
    float kd = __bfloat162float(kp[d]) + __bfloat162float(kp[64 + d]);
    dot = fmaf(q_s[d], kd, dot);
  }
  const float dm = (mask[(size_t)b * Nn] * kmask[b * MK + tid] < 0.5f) ? NEGV : dot * SCALE;
  const float mx = blockMax256(dm, red8);
  const float e = __expf(dm - mx);
  const float s = blockSum256(e, red8);
  pbuf[tid] = e / s;
  __syncthreads();
  const int d = tid & 63, g = tid >> 6;
  float acc = 0.f;
#pragma unroll 8
  for (int jj = 0; jj < 64; ++jj)
    acc = fmaf(pbuf[g * 64 + jj], kv_s[g * 64 + jj][d], acc);
  redpv[g][d] = acc;
  __syncthreads();
  if (tid < DH)
    c_pre[(size_t)b * Dd + h * DH + tid] = __float2bfloat16(
        redpv[0][tid] + redpv[1][tid] + redpv[2][tid] + redpv[3][tid]);
}

// ------------- output writer (cls f32) -------------
__global__ void cout_kernel(const float* __restrict__ c_s, float* __restrict__ o) {
  const int idx = blockIdx.x * 256 + threadIdx.x;
  o[idx] = c_s[idx];
}

static GArgs ga_base() { GArgs g = {}; return g; }

extern "C" void kernel_launch(void* const* d_in, const int* in_sizes, int n_in,
                              void* d_out, int out_size, void* d_ws, size_t ws_size,
                              hipStream_t stream) {
  (void)in_sizes; (void)n_in; (void)out_size; (void)ws_size;
  const float* x_in  = (const float*)d_in[0];
  const float* kx_in = (const float*)d_in[1];
  const float* rd    = (const float*)d_in[2];
  const float* c_in  = (const float*)d_in[3];
  const float* mask  = (const float*)d_in[4];
  const float* kmask = (const float*)d_in[5];
  const float* ln1g  = (const float*)d_in[6];
  const float* ln1b  = (const float*)d_in[7];
  const float* Wqkv  = (const float*)d_in[8];
  const float* Woutw = (const float*)d_in[9];
  const float* boutw = (const float*)d_in[10];
  const float* ln2g  = (const float*)d_in[11];
  const float* ln2b  = (const float*)d_in[12];
  const float* W1    = (const float*)d_in[13];
  const float* b1    = (const float*)d_in[14];
  const float* W2    = (const float*)d_in[15];
  const float* b2    = (const float*)d_in[16];
  float* out = (float*)d_out;

  float* ws = (float*)d_ws;
  size_t off = 0;
  auto alloc = [&](size_t n) { float* p = ws + off; off += (n + 15) & ~(size_t)15; return p; };
  float* xcat_s    = alloc((size_t)NTOK * Dd);
  float* xcat_nb_f = alloc((size_t)NTOK * Dd / 2);
  float* pre_cat_f = alloc((size_t)NTOK * Dd / 2);
  float* hid_f     = alloc((size_t)NTOK * MLPD / 2);
  float* cq        = alloc((size_t)Bb * Dd);
  float* P1_f      = alloc((size_t)32 * Nn * MK / 2);
  float* P2_f      = alloc((size_t)32 * MK * Nn / 2);
  float* tq_s_f    = alloc((size_t)32 * Nn * 128 / 2);
  float* kk_s_f    = alloc((size_t)32 * MK * 128 / 2);
  float* tk_hi_f   = alloc((size_t)32 * Nn * 64 / 2);
  float* kq_hi_f   = alloc((size_t)32 * MK * 64 / 2);
  float* tvT_f     = alloc((size_t)32 * 64 * Nn / 2);
  float* kvT_f     = alloc((size_t)32 * 64 * MK / 2);
  float* rdT       = alloc((size_t)Bb * Nn * MK);
  float* WqkvT_f   = alloc((size_t)2 * QLD * Dd / 2);
  float* WoutT_f   = alloc((size_t)2 * Dd * Dd / 2);
  float* W1T_f     = alloc((size_t)2 * MLPD * Dd / 2);
  float* W2T_f     = alloc((size_t)2 * Dd * MLPD / 2);

  __hip_bfloat16* xcat_nb = (__hip_bfloat16*)xcat_nb_f;
  __hip_bfloat16* pre_cat = (__hip_bfloat16*)pre_cat_f;
  __hip_bfloat16* hid     = (__hip_bfloat16*)hid_f;
  __hip_bfloat16* P1b     = (__hip_bfloat16*)P1_f;
  __hip_bfloat16* P2b     = (__hip_bfloat16*)P2_f;
  __hip_bfloat16* tq_s    = (__hip_bfloat16*)tq_s_f;
  __hip_bfloat16* kk_s    = (__hip_bfloat16*)kk_s_f;
  __hip_bfloat16* tk_hi   = (__hip_bfloat16*)tk_hi_f;
  __hip_bfloat16* kq_hi   = (__hip_bfloat16*)kq_hi_f;
  __hip_bfloat16* tvT     = (__hip_bfloat16*)tvT_f;
  __hip_bfloat16* kvT     = (__hip_bfloat16*)kvT_f;
  __hip_bfloat16* WqkvT   = (__hip_bfloat16*)WqkvT_f;
  __hip_bfloat16* WoutT   = (__hip_bfloat16*)WoutT_f;
  __hip_bfloat16* W1T     = (__hip_bfloat16*)W1T_f;
  __hip_bfloat16* W2T     = (__hip_bfloat16*)W2T_f;

  const size_t CL_OFF = (size_t)2 * Bb * MK * Dd;
  const size_t AT_OFF = CL_OFF + (size_t)Bb * Dd;

  // ---- upfront: input concat, rd transpose, all weight transposes ----
  copy3_kernel<<<(NTOK * 128) / 256, 256, 0, stream>>>(x_in, kx_in, c_in, xcat_s);
  rd_tr_kernel<<<dim3(Bb, Nn / 64, MK / 64), 256, 0, stream>>>(rd, rdT);
  {
    WtArgs a;
    for (int l = 0; l < 2; ++l) {
      a.W[l * 4 + 0] = Wqkv + (size_t)l * Dd * QLD;  a.T[l * 4 + 0] = WqkvT + (size_t)l * QLD * Dd;
      a.K[l * 4 + 0] = Dd;   a.N[l * 4 + 0] = QLD;
      a.W[l * 4 + 1] = Woutw + (size_t)l * Dd * Dd;  a.T[l * 4 + 1] = WoutT + (size_t)l * Dd * Dd;
      a.K[l * 4 + 1] = Dd;   a.N[l * 4 + 1] = Dd;
      a.W[l * 4 + 2] = W1 + (size_t)l * Dd * MLPD;   a.T[l * 4 + 2] = W1T + (size_t)l * MLPD * Dd;
      a.K[l * 4 + 2] = Dd;   a.N[l * 4 + 2] = MLPD;
      a.W[l * 4 + 3] = W2 + (size_t)l * MLPD * Dd;   a.T[l * 4 + 3] = W2T + (size_t)l * Dd * MLPD;
      a.K[l * 4 + 3] = MLPD; a.N[l * 4 + 3] = Dd;
    }
    wtrans_all_kernel<<<dim3(32, 32, 8), 256, 0, stream>>>(a);
  }

  for (int l = 0; l < 2; ++l) {
    const float* bo  = boutw + (size_t)l * Dd;
    const float* b1l = b1 + (size_t)l * MLPD;
    const float* b2l = b2 + (size_t)l * Dd;
    __hip_bfloat16* WqkvTl = WqkvT + (size_t)l * QLD * Dd;
    __hip_bfloat16* WoutTl = WoutT + (size_t)l * Dd * Dd;
    __hip_bfloat16* W1Tl   = W1T + (size_t)l * MLPD * Dd;
    __hip_bfloat16* W2Tl   = W2T + (size_t)l * Dd * MLPD;

    ln_kernel<<<NTOK, 64, 0, stream>>>(xcat_s, ln1g + l * Dd, ln1b + l * Dd, xcat_nb);

    // QKV GEMM with fused split/hi-lo/v-transpose epilogue
    {
      QArgs q = {};
      q.A = (const short*)xcat_nb; q.lda = Dd;
      q.Bt = (const short*)WqkvTl; q.ldb = Dd;
      q.tq = tq_s; q.tk = tk_hi; q.kq = kq_hi; q.kk = kk_s;
      q.tvT = tvT; q.kvT = kvT; q.cq = cq;
      q.M = NTOK; q.K = Dd;
      qkv_gemm<<<dim3(QLD / 128, (NTOK + 127) / 128, 1), 256, 0, stream>>>(q);
    }

    attn_c_kernel<<<Bb * Hh, 256, 0, stream>>>(cq, kk_s, kvT, mask, kmask,
                                               pre_cat + (size_t)CLOFF * Dd);

    // ---- x-path: fused score+softmax+atten-transpose -> PV ----
    score_sx_kernel<<<dim3(Nn / 128, 32), 512, 0, stream>>>(
        (const short*)tq_s, (const short*)kk_s, mask, kmask, rdT, P1b,
        out + AT_OFF + (size_t)l * 32 * MK * Nn);
    {
      GArgs g = ga_base();
      g.A = (const short*)P1b; g.asb = (long)Nn * MK; g.lda = MK;
      g.Bt = (const short*)kvT; g.bsb = (long)64 * MK; g.ldb = MK;
      g.Cb = pre_cat; g.czo = (long)Nn * Dd; g.czi = 64; g.ldc = Dd;
      g.M = Nn; g.N = 64; g.K = MK;
      launch_mgemm<128, 64, 4>(g, 32, stream);
    }
    // ---- k-path: fused score+softmax -> PV ----
    score_sk_kernel<<<dim3(32, MK / 16), 256, 0, stream>>>(
        (const short*)kq_hi, (const short*)tk_hi, mask, kmask, rd, P2b);
    {
      GArgs g = ga_base();
      g.A = (const short*)P2b; g.asb = (long)MK * Nn; g.lda = Nn;
      g.Bt = (const short*)tvT; g.bsb = (long)64 * Nn; g.ldb = Nn;
      g.Cb = pre_cat + (size_t)KXOFF * Dd; g.czo = (long)MK * Dd; g.czi = 64; g.ldc = Dd;
      g.M = MK; g.N = 64; g.K = Nn;
      launch_mgemm<64, 64, 4>(g, 32, stream);
    }

    // ---- Wout + bf16 residual over all rows ----
    {
      GArgs g = ga_base();
      g.A = (const short*)pre_cat; g.lda = Dd;
      g.Bt = (const short*)WoutTl; g.ldb = Dd;
      g.C = xcat_s; g.ldc = Dd; g.bias = bo; g.resb = xcat_nb; g.ldr = Dd;
      g.M = NTOK; g.N = Dd; g.K = Dd;
      launch_mgemm<128, 64, 5>(g, 1, stream);
    }

    // ---- FF over all rows; FF2 fuses kreps output ----
    ln_kernel<<<NTOK, 64, 0, stream>>>(xcat_s, ln2g + l * Dd, ln2b + l * Dd, xcat_nb);
    {
      GArgs g = ga_base();
      g.A = (const short*)xcat_nb; g.lda = Dd;
      g.Bt = (const short*)W1Tl; g.ldb = Dd;
      g.Cb = hid; g.ldc = MLPD; g.bias = b1l;
      g.M = NTOK; g.N = MLPD; g.K = Dd;
      launch_mgemm<128, 128, 3>(g, 1, stream);
      GArgs h = ga_base();
      h.A = (const short*)hid; h.lda = MLPD;
      h.Bt = (const short*)W2Tl; h.ldb = MLPD;
      h.C = xcat_s; h.ldc = Dd; h.bias = b2l; h.res = xcat_s; h.ldr = Dd;
      h.out2 = out + (size_t)l * Bb * MK * Dd; h.km2 = kmask;
      h.M = NTOK; h.N = Dd; h.K = MLPD;
      launch_mgemm<128, 64, 6>(h, 1, stream);
    }
  }
  cout_kernel<<<(Bb * Dd) / 256, 256, 0, stream>>>(xcat_s + (size_t)CLOFF * Dd, out + CL_OFF);
}